// Round 6
// baseline (2811.524 us; speedup 1.0000x reference)
//
#include <hip/hip_runtime.h>
#include <stdint.h>

// ---------------- dims ----------------
constexpr int L = 2, Bb = 2, S = 1024, H = 768, NHd = 12, HD = 64;
constexpr int E = 8, F = 3072, V = 50257;
constexpr int NTOK = Bb * S;        // 2048
constexpr int NSLOT = NTOK * 2;     // 4096 (top-2)
constexpr float EPSLN = 1e-5f;

typedef __attribute__((ext_vector_type(4))) float f32x4;
typedef __attribute__((ext_vector_type(8))) short s16x8;

#define DEVI __device__ __forceinline__

DEVI float bf2f(short u) {
  union { float f; uint32_t i; } c; c.i = ((uint32_t)(uint16_t)u) << 16; return c.f;
}
DEVI short f2bf(float f) {
  union { float f; uint32_t i; } c; c.f = f;
  uint32_t x = c.i;
  uint32_t r = (x + 0x7fffu + ((x >> 16) & 1u)) >> 16;  // RNE
  return (short)r;
}

DEVI void gload16(const void* g, void* l) {
  __builtin_amdgcn_global_load_lds(g, l, 16, 0, 0);
}

DEVI float gelu1(float g) { return 0.5f * g * (1.f + erff(g * 0.70710678118f)); }

// ---------------- small kernels ----------------
__global__ void k_f32_to_bf16(const float* __restrict__ in, short* __restrict__ out, long n4) {
  long i = (long)blockIdx.x * blockDim.x + threadIdx.x;
  if (i >= n4) return;
  long base = i * 4;
  f32x4 v = *(const f32x4*)(in + base);
  short4 o;
  o.x = f2bf(v.x); o.y = f2bf(v.y); o.z = f2bf(v.z); o.w = f2bf(v.w);
  *(short4*)(out + base) = o;
}

// in  f32 [batch][R][C]  ->  out bf16 [batch][C][R]
__global__ void k_transpose_bf16(const float* __restrict__ in, short* __restrict__ out,
                                 int R, int C, long inBS, long outBS) {
  __shared__ float tile[32][33];
  const float* src = in + (size_t)blockIdx.z * inBS;
  short* dst = out + (size_t)blockIdx.z * outBS;
  int r0 = blockIdx.y * 32, c0 = blockIdx.x * 32;
  int tx = threadIdx.x, ty = threadIdx.y;
#pragma unroll
  for (int i = 0; i < 32; i += 8) {
    int r = r0 + ty + i, c = c0 + tx;
    if (r < R && c < C) tile[ty + i][tx] = src[(size_t)r * C + c];
  }
  __syncthreads();
#pragma unroll
  for (int i = 0; i < 32; i += 8) {
    int c = c0 + ty + i, r = r0 + tx;
    if (r < R && c < C) dst[(size_t)c * R + r] = f2bf(tile[tx][ty + i]);
  }
}

__global__ void k_bqkv(const float* __restrict__ bq, const float* __restrict__ bk,
                       const float* __restrict__ bv, float* __restrict__ bqkv) {
  int i = blockIdx.x * blockDim.x + threadIdx.x;
  if (i >= L * 3 * H) return;
  int l = i / (3 * H), j = i % (3 * H);
  float v = (j < H) ? bq[l * H + j] : (j < 2 * H) ? bk[l * H + j - H] : bv[l * H + j - 2 * H];
  bqkv[i] = v;
}

// concat Wq|Wk|Wv of layer l into [768][2304] ([k][n])
__global__ void k_wcat(const float* __restrict__ Wq, const float* __restrict__ Wk,
                       const float* __restrict__ Wv, float* __restrict__ out) {
  int i = blockIdx.x * blockDim.x + threadIdx.x;  // H*H
  if (i >= H * H) return;
  int k = i / H, n = i % H;
  out[(size_t)k * 3 * H + n] = Wq[i];
  out[(size_t)k * 3 * H + H + n] = Wk[i];
  out[(size_t)k * 3 * H + 2 * H + n] = Wv[i];
}

__global__ void k_ropetab(float* __restrict__ cosT, float* __restrict__ sinT) {
  int i = blockIdx.x * blockDim.x + threadIdx.x;
  if (i >= S * (HD / 2)) return;
  int s = i / 32, d = i % 32;
  float invf = powf(10000.f, -(2.f * d) / (float)HD);
  float ang = (float)s * invf;
  cosT[i] = cosf(ang);
  sinT[i] = sinf(ang);
}

__global__ void k_embed(const int* __restrict__ ids, const float* __restrict__ emb,
                        float* __restrict__ x) {
  int idx = blockIdx.x * blockDim.x + threadIdx.x;  // NTOK*(H/4)
  int row = idx / (H / 4), c4 = idx % (H / 4);
  if (row >= NTOK) return;
  int t = ids[row];
  ((f32x4*)(x + (size_t)row * H))[c4] = ((const f32x4*)(emb + (size_t)t * H))[c4];
}

// ---------------- layernorm (f32 in, f32 or bf16 out) ----------------
template <bool BF>
__global__ void k_layernorm(const float* __restrict__ x, const float* __restrict__ w,
                            const float* __restrict__ b, void* __restrict__ outp) {
  int row = blockIdx.x * (blockDim.x >> 6) + (threadIdx.x >> 6);
  int lane = threadIdx.x & 63;
  if (row >= NTOK) return;
  const float* xr = x + (size_t)row * H;
  float v[12], s = 0.f, s2 = 0.f;
#pragma unroll
  for (int j = 0; j < 12; j++) { float t = xr[lane + j * 64]; v[j] = t; s += t; s2 += t * t; }
#pragma unroll
  for (int off = 32; off; off >>= 1) { s += __shfl_xor(s, off); s2 += __shfl_xor(s2, off); }
  float m = s / (float)H;
  float var = s2 / (float)H - m * m;
  float rs = 1.f / sqrtf(var + EPSLN);
#pragma unroll
  for (int j = 0; j < 12; j++) {
    int c = lane + j * 64;
    float val = (v[j] - m) * rs * w[c] + b[c];
    if (BF) ((short*)outp)[(size_t)row * H + c] = f2bf(val);
    else    ((float*)outp)[(size_t)row * H + c] = val;
  }
}

// ---------------- rope (all f32; adds QKV bias pre-rotation) ----------------
__global__ void k_rope(const float* __restrict__ qkv, const float* __restrict__ bqkv,
                       const float* __restrict__ cosT, const float* __restrict__ sinT,
                       float* __restrict__ qf, float* __restrict__ kT,
                       float* __restrict__ vf) {
  int idx = blockIdx.x * blockDim.x + threadIdx.x;  // B*S*NH*32
  if (idx >= Bb * S * NHd * 32) return;
  int d = idx & 31;
  int h = (idx >> 5) % NHd;
  int t = idx / (32 * NHd);  // token = b*S+s
  int s = t % S, b = t / S;
  const float* base = qkv + (size_t)t * (3 * H) + h * HD;
  const float* bb = bqkv + h * HD;
  float c = cosT[s * 32 + d], sn = sinT[s * 32 + d];
  float q1 = base[d] + bb[d],               q2 = base[d + 32] + bb[d + 32];
  float k1 = base[H + d] + bb[H + d],       k2 = base[H + d + 32] + bb[H + d + 32];
  float v1 = base[2 * H + d] + bb[2 * H + d], v2 = base[2 * H + d + 32] + bb[2 * H + d + 32];
  size_t z = (size_t)(b * NHd + h);
  size_t qk = (z * S + s) * HD;
  qf[qk + d]      = q1 * c - q2 * sn;
  qf[qk + d + 32] = q2 * c + q1 * sn;
  kT[z * HD * S + (size_t)d * S + s]        = k1 * c - k2 * sn;
  kT[z * HD * S + (size_t)(d + 32) * S + s] = k2 * c + k1 * sn;
  vf[qk + d]      = v1;
  vf[qk + d + 32] = v2;
}

// ---------------- softmax (f32 in place) ----------------
__global__ void k_softmax(float* __restrict__ att) {
  int row = blockIdx.x * (blockDim.x >> 6) + (threadIdx.x >> 6);  // B*NH*S rows
  int lane = threadIdx.x & 63;
  if (row >= Bb * NHd * S) return;
  float* pr = att + (size_t)row * S;
  float v[16], mx = -3e38f;
#pragma unroll
  for (int j = 0; j < 16; j++) { v[j] = pr[lane + j * 64]; mx = fmaxf(mx, v[j]); }
#pragma unroll
  for (int off = 32; off; off >>= 1) mx = fmaxf(mx, __shfl_xor(mx, off));
  float sum = 0.f;
#pragma unroll
  for (int j = 0; j < 16; j++) { v[j] = expf(v[j] - mx); sum += v[j]; }
#pragma unroll
  for (int off = 32; off; off >>= 1) sum += __shfl_xor(sum, off);
  float inv = 1.f / sum;
#pragma unroll
  for (int j = 0; j < 16; j++) pr[lane + j * 64] = v[j] * inv;
}

// x += tmp + bias(col)
__global__ void k_addres(float* __restrict__ x, const float* __restrict__ tmp,
                         const float* __restrict__ bo) {
  int idx = blockIdx.x * blockDim.x + threadIdx.x;  // NTOK*(H/4)
  if (idx >= NTOK * (H / 4)) return;
  int c4 = idx % (H / 4);
  f32x4 t = ((const f32x4*)tmp)[idx];
  f32x4 b = *(const f32x4*)(bo + c4 * 4);
  f32x4* xp = (f32x4*)x + idx;
  *xp = *xp + t + b;
}

// ---------------- router (f32 h input -> exact top-2) ----------------
__global__ void k_router(const float* __restrict__ h, const float* __restrict__ Wr,
                         const float* __restrict__ br, float* __restrict__ sel_w,
                         int* __restrict__ sel_e, int* __restrict__ counts) {
  int tok = blockIdx.x * (blockDim.x >> 6) + (threadIdx.x >> 6);
  int lane = threadIdx.x & 63;
  if (tok >= NTOK) return;
  const float* hr = h + (size_t)tok * H;
  float acc[8] = {0, 0, 0, 0, 0, 0, 0, 0};
  for (int i = lane; i < H; i += 64) {
    float hv = hr[i];
    const f32x4* w4 = (const f32x4*)(Wr + (size_t)i * E);
    f32x4 a = w4[0], b = w4[1];
    acc[0] += hv * a.x; acc[1] += hv * a.y; acc[2] += hv * a.z; acc[3] += hv * a.w;
    acc[4] += hv * b.x; acc[5] += hv * b.y; acc[6] += hv * b.z; acc[7] += hv * b.w;
  }
#pragma unroll
  for (int off = 32; off; off >>= 1)
#pragma unroll
    for (int e = 0; e < 8; e++) acc[e] += __shfl_xor(acc[e], off);
  if (lane == 0) {
    float lg[8], m = -3e38f;
#pragma unroll
    for (int e = 0; e < 8; e++) { lg[e] = acc[e] + br[e]; m = fmaxf(m, lg[e]); }
    float sum = 0.f;
#pragma unroll
    for (int e = 0; e < 8; e++) { lg[e] = expf(lg[e] - m); sum += lg[e]; }
    float inv = 1.f / sum;
#pragma unroll
    for (int e = 0; e < 8; e++) lg[e] *= inv;
    int i1 = 0;
#pragma unroll
    for (int e = 1; e < 8; e++) if (lg[e] > lg[i1]) i1 = e;
    int i2 = (i1 == 0) ? 1 : 0;
#pragma unroll
    for (int e = 0; e < 8; e++) if (e != i1 && lg[e] > lg[i2]) i2 = e;
    float p1 = lg[i1], p2 = lg[i2];
    float ws = p1 + p2 + 1e-9f;
    sel_e[tok * 2] = i1; sel_e[tok * 2 + 1] = i2;
    sel_w[tok * 2] = p1 / ws; sel_w[tok * 2 + 1] = p2 / ws;
    atomicAdd(counts + i1, 1);
    atomicAdd(counts + i2, 1);
  }
}

__global__ void k_offsets(const int* __restrict__ counts, int* __restrict__ offs) {
  if (threadIdx.x == 0) {
    int a = 0;
    for (int e = 0; e < E; e++) { offs[e] = a; a += counts[e]; }
    offs[E] = a;
  }
}

__global__ void k_scatter(const int* __restrict__ sel_e, const int* __restrict__ offs,
                          int* __restrict__ cursor, int* __restrict__ tok_list,
                          int* __restrict__ slot_of) {
  int tok = blockIdx.x * blockDim.x + threadIdx.x;
  if (tok >= NTOK) return;
  for (int k = 0; k < 2; k++) {
    int e = sel_e[tok * 2 + k];
    int pos = atomicAdd(cursor + e, 1);
    int g = offs[e] + pos;
    tok_list[g] = tok;
    slot_of[tok * 2 + k] = g;
  }
}

// ff = sum_k w_k * (oe[slot_k] + b2[e_k]); x += ff
__global__ void k_combine(const float* __restrict__ oe, const float* __restrict__ sel_w,
                          const int* __restrict__ slot_of, const int* __restrict__ sel_e,
                          const float* __restrict__ b2, float* __restrict__ x) {
  int idx = blockIdx.x * blockDim.x + threadIdx.x;  // NTOK*(H/4)
  if (idx >= NTOK * (H / 4)) return;
  int tok = idx / (H / 4), c4 = idx % (H / 4);
  float w0 = sel_w[tok * 2], w1 = sel_w[tok * 2 + 1];
  int s0 = slot_of[tok * 2], s1 = slot_of[tok * 2 + 1];
  int e0 = sel_e[tok * 2], e1 = sel_e[tok * 2 + 1];
  f32x4 a = ((const f32x4*)(oe + (size_t)s0 * H))[c4];
  f32x4 b = ((const f32x4*)(oe + (size_t)s1 * H))[c4];
  f32x4 ba = ((const f32x4*)(b2 + (size_t)e0 * H))[c4];
  f32x4 bb = ((const f32x4*)(b2 + (size_t)e1 * H))[c4];
  f32x4* xp = (f32x4*)(x + (size_t)tok * H) + c4;
  *xp = *xp + w0 * (a + ba) + w1 * (b + bb);
}

// ---------------- f32 SGEMM, 128x128 tile, 8x8 micro, K-step 8, split-K ------
// C[z][m][n] = sum_k A[z][row(m)][k] * B[z][k][n]    (all f32)
// Requires N % 128 == 0 and (K/KSPLIT) % 8 == 0.
// MODE 0: +bias(opt)  2: acc*alpha + causal  4: gelu(acc+bias)  5: atomicAdd
// Accumulators: f32x4 accA[8] (cols tx*4..+3), accB[8] (cols 64+tx*4..+3),
// rows ty*8+i. ALL indices compile-time static (rule #20: no scratch demotion).
template <int MODE, bool GATHER, int KSPLIT>
__global__ __launch_bounds__(256, 2) void k_sgemm128(
    const float* __restrict__ A, long sAz, int lda,
    const float* __restrict__ B, long sBz, int ldb,
    float* __restrict__ C, int zdiv, long sChi, long sClo, int ldc,
    const float* __restrict__ bias, long sBias,
    int M, int N, int K,
    const int* __restrict__ cnts, const int* __restrict__ offs,
    const int* __restrict__ gidx, float alpha) {
  const int z = blockIdx.z / KSPLIT;
  const int ks = blockIdx.z % KSPLIT;
  const int Kc = K / KSPLIT;
  const int Meff = cnts ? cnts[z] : M;
  const int tm = blockIdx.y;
  if (tm * 128 >= Meff) return;
  const int tn = blockIdx.x;
  const int row_base = offs ? offs[z] : 0;

  __shared__ float As[8][128];
  __shared__ float Bs[8][132];

  const int tid = threadIdx.x;

  // A staging: thread t -> row t>>1, k-quad (t&1)*4
  int arow = tm * 128 + (tid >> 1);
  if (arow > Meff - 1) arow = Meff - 1;
  int agr = row_base + arow;
  if (GATHER) agr = gidx[agr];
  const int am = tid >> 1, ak = (tid & 1) * 4;
  const float* aP = A + (size_t)z * sAz + (size_t)agr * lda + ks * Kc + ak;

  // B staging: thread t -> k-row t>>5, col-quad (t&31)*4
  const int bk = tid >> 5, bn4 = (tid & 31) * 4;
  const float* bP = B + (size_t)z * sBz + (size_t)(ks * Kc + bk) * ldb + tn * 128 + bn4;

  f32x4 accA[8], accB[8];
#pragma unroll
  for (int i = 0; i < 8; ++i) {
    accA[i] = {0.f, 0.f, 0.f, 0.f};
    accB[i] = {0.f, 0.f, 0.f, 0.f};
  }
  const int ty = tid >> 4, tx = tid & 15;

  for (int k0 = 0; k0 < Kc; k0 += 8) {
    f32x4 av = *(const f32x4*)aP;
    f32x4 bv = *(const f32x4*)bP;
    __syncthreads();
    As[ak + 0][am] = av.x; As[ak + 1][am] = av.y;
    As[ak + 2][am] = av.z; As[ak + 3][am] = av.w;
    *(f32x4*)&Bs[bk][bn4] = bv;
    __syncthreads();
#pragma unroll
    for (int kk = 0; kk < 8; ++kk) {
      const f32x4 a0 = *(const f32x4*)&As[kk][ty * 8];
      const f32x4 a1 = *(const f32x4*)&As[kk][ty * 8 + 4];
      const f32x4 b0 = *(const f32x4*)&Bs[kk][tx * 4];
      const f32x4 b1 = *(const f32x4*)&Bs[kk][64 + tx * 4];
      accA[0] += a0.x * b0; accB[0] += a0.x * b1;
      accA[1] += a0.y * b0; accB[1] += a0.y * b1;
      accA[2] += a0.z * b0; accB[2] += a0.z * b1;
      accA[3] += a0.w * b0; accB[3] += a0.w * b1;
      accA[4] += a1.x * b0; accB[4] += a1.x * b1;
      accA[5] += a1.y * b0; accB[5] += a1.y * b1;
      accA[6] += a1.z * b0; accB[6] += a1.z * b1;
      accA[7] += a1.w * b0; accB[7] += a1.w * b1;
    }
    aP += 8;
    bP += (size_t)8 * ldb;
  }

  const long out_off = (long)(z / zdiv) * sChi + (long)(z % zdiv) * sClo;
  const float* bz = bias ? bias + (size_t)z * sBias : nullptr;
  const int gc0 = tn * 128 + tx * 4;        // cols gc0..gc0+3 and gc0+64..gc0+67
  f32x4 bva = {0.f, 0.f, 0.f, 0.f}, bvb = {0.f, 0.f, 0.f, 0.f};
  if ((MODE == 0 || MODE == 4) && bz) {
    bva = *(const f32x4*)&bz[gc0];
    bvb = *(const f32x4*)&bz[gc0 + 64];
  }
#pragma unroll
  for (int i = 0; i < 8; ++i) {
    const int lrow = tm * 128 + ty * 8 + i;
    if (lrow >= Meff) continue;
    const long orow = row_base + lrow;
    const long idx = out_off + orow * (long)ldc + gc0;
    if (MODE == 5) {
      atomicAdd(&C[idx + 0], accA[i].x);
      atomicAdd(&C[idx + 1], accA[i].y);
      atomicAdd(&C[idx + 2], accA[i].z);
      atomicAdd(&C[idx + 3], accA[i].w);
      atomicAdd(&C[idx + 64], accB[i].x);
      atomicAdd(&C[idx + 65], accB[i].y);
      atomicAdd(&C[idx + 66], accB[i].z);
      atomicAdd(&C[idx + 67], accB[i].w);
      continue;
    }
    f32x4 v0, v1;
    if (MODE == 0) {
      v0 = accA[i] + bva;
      v1 = accB[i] + bvb;
    } else if (MODE == 2) {
      v0.x = accA[i].x * alpha + ((gc0 + 0 > lrow) ? -1e9f : 0.f);
      v0.y = accA[i].y * alpha + ((gc0 + 1 > lrow) ? -1e9f : 0.f);
      v0.z = accA[i].z * alpha + ((gc0 + 2 > lrow) ? -1e9f : 0.f);
      v0.w = accA[i].w * alpha + ((gc0 + 3 > lrow) ? -1e9f : 0.f);
      v1.x = accB[i].x * alpha + ((gc0 + 64 > lrow) ? -1e9f : 0.f);
      v1.y = accB[i].y * alpha + ((gc0 + 65 > lrow) ? -1e9f : 0.f);
      v1.z = accB[i].z * alpha + ((gc0 + 66 > lrow) ? -1e9f : 0.f);
      v1.w = accB[i].w * alpha + ((gc0 + 67 > lrow) ? -1e9f : 0.f);
    } else if (MODE == 4) {
      v0.x = gelu1(accA[i].x + bva.x);
      v0.y = gelu1(accA[i].y + bva.y);
      v0.z = gelu1(accA[i].z + bva.z);
      v0.w = gelu1(accA[i].w + bva.w);
      v1.x = gelu1(accB[i].x + bvb.x);
      v1.y = gelu1(accB[i].y + bvb.y);
      v1.z = gelu1(accB[i].z + bvb.z);
      v1.w = gelu1(accB[i].w + bvb.w);
    }
    *(f32x4*)&C[idx] = v0;
    *(f32x4*)&C[idx + 64] = v1;
  }
}

template <int MODE, bool GATHER, int KSPLIT>
static void sgemm128(hipStream_t st, const float* A, long sAz, int lda, const float* B,
                     long sBz, int ldb, float* C, int zdiv, long sChi, long sClo, int ldc,
                     const float* bias, long sBias, int M, int N, int K, int nz,
                     const int* cnts, const int* offs_, const int* gat, float alpha) {
  dim3 g(N / 128, (M + 127) / 128, nz * KSPLIT);
  k_sgemm128<MODE, GATHER, KSPLIT><<<g, 256, 0, st>>>(A, sAz, lda, B, sBz, ldb, C, zdiv, sChi,
                                                      sClo, ldc, bias, sBias, M, N, K, cnts,
                                                      offs_, gat, alpha);
}

// ---------------- f32 SGEMM 64x64 (for PV: N=64) ----------------
// MODE 5 only in practice: atomicAdd accumulate.
template <int MODE, bool GATHER, int KSPLIT>
__global__ __launch_bounds__(256, 4) void k_sgemm64(
    const float* __restrict__ A, long sAz, int lda,
    const float* __restrict__ B, long sBz, int ldb,
    float* __restrict__ C, int zdiv, long sChi, long sClo, int ldc,
    int M, int N, int K,
    const int* __restrict__ cnts, const int* __restrict__ offs,
    const int* __restrict__ gidx) {
  const int z = blockIdx.z / KSPLIT;
  const int ks = blockIdx.z % KSPLIT;
  const int Kc = K / KSPLIT;
  const int Meff = cnts ? cnts[z] : M;
  const int tm = blockIdx.y;
  if (tm * 64 >= Meff) return;
  const int tn = blockIdx.x;
  const int row_base = offs ? offs[z] : 0;

  __shared__ float As[16][64];
  __shared__ float Bs[16][68];

  const int tid = threadIdx.x;
  int arow = tm * 64 + (tid >> 2);
  if (arow > Meff - 1) arow = Meff - 1;
  int agr = row_base + arow;
  if (GATHER) agr = gidx[agr];
  const int am = tid >> 2, ak = (tid & 3) * 4;
  const float* aP = A + (size_t)z * sAz + (size_t)agr * lda + ks * Kc + ak;
  const int bk = tid >> 4, bn4 = (tid & 15) * 4;
  const float* bP = B + (size_t)z * sBz + (size_t)(ks * Kc + bk) * ldb + tn * 64 + bn4;

  f32x4 acc4[4];
#pragma unroll
  for (int i = 0; i < 4; ++i) acc4[i] = {0.f, 0.f, 0.f, 0.f};
  const int ty = tid >> 4, tx = tid & 15;

  for (int k0 = 0; k0 < Kc; k0 += 16) {
    f32x4 av = *(const f32x4*)aP;
    f32x4 bv = *(const f32x4*)bP;
    __syncthreads();
    As[ak + 0][am] = av.x; As[ak + 1][am] = av.y;
    As[ak + 2][am] = av.z; As[ak + 3][am] = av.w;
    *(f32x4*)&Bs[bk][bn4] = bv;
    __syncthreads();
#pragma unroll
    for (int kk = 0; kk < 16; ++kk) {
      const f32x4 a4 = *(const f32x4*)&As[kk][ty * 4];
      const f32x4 b4 = *(const f32x4*)&Bs[kk][tx * 4];
      acc4[0] += a4.x * b4;
      acc4[1] += a4.y * b4;
      acc4[2] += a4.z * b4;
      acc4[3] += a4.w * b4;
    }
    aP += 16;
    bP += (size_t)16 * ldb;
  }

  const long out_off = (long)(z / zdiv) * sChi + (long)(z % zdiv) * sClo;
  const int gc0 = tn * 64 + tx * 4;
#pragma unroll
  for (int i = 0; i < 4; ++i) {
    const int lrow = tm * 64 + ty * 4 + i;
    if (lrow >= Meff) continue;
    const long orow = row_base + lrow;
    const long idx = out_off + orow * (long)ldc + gc0;
    atomicAdd(&C[idx + 0], acc4[i].x);
    atomicAdd(&C[idx + 1], acc4[i].y);
    atomicAdd(&C[idx + 2], acc4[i].z);
    atomicAdd(&C[idx + 3], acc4[i].w);
  }
}

// ---------------- bf16 MFMA GEMM ----------------
// C[z][m][n] = sum_k A[z][row(m)][k] * Bt[z][n][k]   (A,Bt bf16; acc f32)
// MODE 0: f32 out (+bias opt)   4: bf16 out = gelu(acc + bias)
// NSWZ: remap grid so consecutive blocks share the same N-tile (B-locality).
template <int MODE, bool GATHER, bool NSWZ>
__global__ __launch_bounds__(256, 2) void k_bgemm(
    const short* __restrict__ A, long sAz, int lda,
    const short* __restrict__ Bt, long sBz, int ldb,
    void* __restrict__ Cp, int zdiv, long sChi, long sClo, int ldc,
    const float* __restrict__ bias, long sBias,
    int M, int N, int K,
    const int* __restrict__ d_counts, const int* __restrict__ d_offs,
    const int* __restrict__ gidx) {
  const int z = blockIdx.z;
  const int Meff = d_counts ? d_counts[z] : M;
  int tm, tn;
  if (NSWZ) {
    const int bid = blockIdx.y * gridDim.x + blockIdx.x;
    tn = bid / gridDim.y;
    tm = bid % gridDim.y;
  } else {
    tm = blockIdx.y;
    tn = blockIdx.x;
  }
  if (tm * 128 >= Meff) return;
  const int row_base = d_offs ? d_offs[z] : 0;

  __shared__ short Abuf[128 * 32];
  __shared__ short Bbuf[128 * 32];

  const int tid = threadIdx.x;
  const int lane = tid & 63;
  const int w = tid >> 6;

  const short* Az = A + (size_t)z * sAz;
  const short* Bz = Bt + (size_t)z * sBz;

  const short* aSrc[2];
  const short* bSrc[2];
#pragma unroll
  for (int i = 0; i < 2; ++i) {
    const int srow = i * 64 + (tid >> 2);
    const int kb = (tid & 3) ^ (srow & 3);  // XOR swizzle (both-sides involution)
    int lrow = tm * 128 + srow;
    if (lrow > Meff - 1) lrow = Meff - 1;
    int ar = row_base + lrow;
    if (GATHER) ar = gidx[ar];
    aSrc[i] = Az + (size_t)ar * lda + kb * 8;
    int bcol = tn * 128 + srow;
    if (bcol > N - 1) bcol = N - 1;
    bSrc[i] = Bz + (size_t)bcol * ldb + kb * 8;
  }

  f32x4 acc[4][4];
#pragma unroll
  for (int a = 0; a < 4; ++a)
#pragma unroll
    for (int b = 0; b < 4; ++b) acc[a][b] = {0.f, 0.f, 0.f, 0.f};

  const int wr = (w >> 1) * 64;
  const int wc = (w & 1) * 64;
  const int r16 = lane & 15;
  const int kb4 = lane >> 4;
  const int swz = (kb4 ^ (r16 & 3)) * 8;
  int aoff[4], boff[4];
#pragma unroll
  for (int i = 0; i < 4; ++i) {
    aoff[i] = (wr + i * 16 + r16) * 32 + swz;
    boff[i] = (wc + i * 16 + r16) * 32 + swz;
  }
  char* const ldsA0 = (char*)Abuf + w * 1024;
  char* const ldsA1 = (char*)Abuf + 4096 + w * 1024;
  char* const ldsB0 = (char*)Bbuf + w * 1024;
  char* const ldsB1 = (char*)Bbuf + 4096 + w * 1024;

  for (int k0 = 0; k0 < K; k0 += 32) {
    gload16(aSrc[0], ldsA0);
    gload16(aSrc[1], ldsA1);
    gload16(bSrc[0], ldsB0);
    gload16(bSrc[1], ldsB1);
    aSrc[0] += 32; aSrc[1] += 32; bSrc[0] += 32; bSrc[1] += 32;
    __syncthreads();
    s16x8 af[4], bf[4];
#pragma unroll
    for (int i = 0; i < 4; ++i) {
      af[i] = *(const s16x8*)(Abuf + aoff[i]);
      bf[i] = *(const s16x8*)(Bbuf + boff[i]);
    }
#pragma unroll
    for (int mi = 0; mi < 4; ++mi)
#pragma unroll
      for (int ni = 0; ni < 4; ++ni)
        acc[mi][ni] =
            __builtin_amdgcn_mfma_f32_16x16x32_bf16(af[mi], bf[ni], acc[mi][ni], 0, 0, 0);
    __syncthreads();
  }

  const long out_off = (long)(z / zdiv) * sChi + (long)(z % zdiv) * sClo;
  const float* bz = bias ? (bias + (size_t)z * sBias) : nullptr;
  const int q4 = lane >> 4;
  float bvv[4];
  int gco[4];
#pragma unroll
  for (int ni = 0; ni < 4; ++ni) {
    gco[ni] = tn * 128 + wc + ni * 16 + r16;
    bvv[ni] = (bz && gco[ni] < N) ? bz[gco[ni]] : 0.f;
  }
#pragma unroll
  for (int mi = 0; mi < 4; ++mi) {
#pragma unroll
    for (int j = 0; j < 4; ++j) {
      const int lrow = tm * 128 + wr + mi * 16 + q4 * 4 + j;
      if (lrow >= Meff) continue;
      const long rbase = out_off + (row_base + lrow) * (long)ldc;
#pragma unroll
      for (int ni = 0; ni < 4; ++ni) {
        if (gco[ni] >= N) continue;
        const float v = acc[mi][ni][j];
        if (MODE == 0) {
          ((float*)Cp)[rbase + gco[ni]] = v + bvv[ni];
        } else if (MODE == 4) {
          float g = v + bvv[ni];
          ((short*)Cp)[rbase + gco[ni]] = f2bf(gelu1(g));
        }
      }
    }
  }
}

template <int MODE, bool GATHER, bool NSWZ>
static void bgemm(hipStream_t st, const short* A, long sAz, int lda, const short* Bt, long sBz,
                  int ldb, void* C, int zdiv, long sChi, long sClo, int ldc, const float* bias,
                  long sBias, int M, int N, int K, int nz, const int* cnts, const int* offs_,
                  const int* gat) {
  dim3 g((N + 127) / 128, (M + 127) / 128, nz);
  k_bgemm<MODE, GATHER, NSWZ><<<g, 256, 0, st>>>(A, sAz, lda, Bt, sBz, ldb, C, zdiv, sChi,
                                                 sClo, ldc, bias, sBias, M, N, K, cnts, offs_,
                                                 gat);
}

// ---------------- launch ----------------
extern "C" void kernel_launch(void* const* d_in, const int* in_sizes, int n_in, void* d_out,
                              int out_size, void* d_ws, size_t ws_size, hipStream_t stream) {
  (void)in_sizes; (void)n_in; (void)out_size; (void)ws_size;
  const int*   ids  = (const int*)d_in[0];
  const float* emb  = (const float*)d_in[1];
  const float* ln1w = (const float*)d_in[2];
  const float* ln1b = (const float*)d_in[3];
  const float* ln2w = (const float*)d_in[4];
  const float* ln2b = (const float*)d_in[5];
  const float* lnfw = (const float*)d_in[6];
  const float* lnfb = (const float*)d_in[7];
  const float* Wq = (const float*)d_in[8];
  const float* bq = (const float*)d_in[9];
  const float* Wk = (const float*)d_in[10];
  const float* bk = (const float*)d_in[11];
  const float* Wv = (const float*)d_in[12];
  const float* bv = (const float*)d_in[13];
  const float* Wo = (const float*)d_in[14];
  const float* bo = (const float*)d_in[15];
  const float* Wr = (const float*)d_in[16];
  const float* br = (const float*)d_in[17];
  const float* W1 = (const float*)d_in[18];
  const float* b1 = (const float*)d_in[19];
  const float* W2 = (const float*)d_in[20];
  const float* b2 = (const float*)d_in[21];
  float* out = (float*)d_out;

  char* p = (char*)d_ws;
  auto alloc = [&](size_t bytes) {
    char* r = p;
    p += (bytes + 255) & ~(size_t)255;
    return r;
  };
  short* embB = (short*)alloc((size_t)V * H * 2);          // 77.2 MB
  short* W1T  = (short*)alloc((size_t)E * F * H * 2);      // 37.7 MB (layer 1, [E][F][H])
  short* W2T  = (short*)alloc((size_t)E * H * F * 2);      // 37.7 MB (layer 1, [E][H][F])
  float* bqkv = (float*)alloc((size_t)L * 3 * H * 4);
  float* Wcat = (float*)alloc((size_t)3 * H * H * 4);      // 7.1 MB (per-layer reuse)
  float* cosT = (float*)alloc((size_t)S * 32 * 4);
  float* sinT = (float*)alloc((size_t)S * 32 * 4);
  float* x    = (float*)alloc((size_t)NTOK * H * 4);
  float* hbuf = (float*)alloc((size_t)NTOK * H * 4);
  float* qf   = (float*)alloc((size_t)NTOK * H * 4);       // also reused as Wo split-K tmp
  float* kT   = (float*)alloc((size_t)NTOK * H * 4);
  float* vf   = (float*)alloc((size_t)NTOK * H * 4);
  float* o    = (float*)alloc((size_t)NTOK * H * 4);
  short* xb   = (short*)alloc((size_t)NTOK * H * 2);
  short* xb2  = (short*)alloc((size_t)NTOK * H * 2);
  // union region: qkvl (18.9MB) | att f32 (100.7MB) | act f32 (50.3) / act bf16 (25.2) + oe
  char* uni = alloc((size_t)Bb * NHd * S * S * 4);         // 100.7 MB
  float* qkvl  = (float*)uni;
  float* att   = (float*)uni;
  float* act_f = (float*)uni;
  short* act_b = (short*)uni;
  float* oe    = (float*)(uni + (size_t)NSLOT * F * 4);
  int* counts  = (int*)alloc(2 * E * 4);
  int* cursor  = counts + E;
  int* offs    = (int*)alloc((E + 1) * 4);
  int* sel_e   = (int*)alloc((size_t)NTOK * 2 * 4);
  float* sel_w = (float*)alloc((size_t)NTOK * 2 * 4);
  int* slot_of = (int*)alloc((size_t)NTOK * 2 * 4);
  int* tok_lst = (int*)alloc((size_t)NSLOT * 4);

  // ---- prologue ----
  long nEmb4 = (long)V * H / 4;
  k_f32_to_bf16<<<(nEmb4 + 255) / 256, 256, 0, stream>>>(emb, embB, nEmb4);
  k_bqkv<<<(L * 3 * H + 255) / 256, 256, 0, stream>>>(bq, bk, bv, bqkv);
  k_ropetab<<<(S * 32 + 255) / 256, 256, 0, stream>>>(cosT, sinT);
  k_embed<<<(NTOK * (H / 4) + 255) / 256, 256, 0, stream>>>(ids, emb, x);
  // layer-1 expert weights -> transposed bf16 (downstream of all routers)
  dim3 tb(32, 8);
  k_transpose_bf16<<<dim3(F / 32, H / 32, E), tb, 0, stream>>>(
      W1 + (size_t)1 * E * H * F, W1T, H, F, (long)H * F, (long)F * H);
  k_transpose_bf16<<<dim3(H / 32, F / 32, E), tb, 0, stream>>>(
      W2 + (size_t)1 * E * F * H, W2T, F, H, (long)F * H, (long)H * F);

  for (int l = 0; l < L; l++) {
    // --- attention (f32; upstream of routers) ---
    k_layernorm<false><<<NTOK / 4, 256, 0, stream>>>(x, ln1w + l * H, ln1b + l * H, hbuf);
    k_wcat<<<(H * H + 255) / 256, 256, 0, stream>>>(Wq + (size_t)l * H * H,
                                                    Wk + (size_t)l * H * H,
                                                    Wv + (size_t)l * H * H, Wcat);
    // QKV: split-K x2, accumulate into zeroed qkvl; bias applied in k_rope
    hipMemsetAsync(qkvl, 0, (size_t)NTOK * 3 * H * 4, stream);
    sgemm128<5, false, 2>(stream, hbuf, 0, H, Wcat, 0, 3 * H, qkvl, 1, 0, 0, 3 * H, nullptr, 0,
                          NTOK, 3 * H, H, 1, nullptr, nullptr, nullptr, 1.f);
    k_rope<<<(Bb * S * NHd * 32 + 255) / 256, 256, 0, stream>>>(qkvl, bqkv + l * 3 * H, cosT,
                                                                sinT, qf, kT, vf);
    // QK^T: 128-tile, causal + scale
    sgemm128<2, false, 1>(stream, qf, (long)S * HD, HD, kT, (long)HD * S, S, att, 1,
                          (long)S * S, 0, S, nullptr, 0, S, S, HD, Bb * NHd, nullptr, nullptr,
                          nullptr, 0.125f);
    k_softmax<<<(Bb * NHd * S) / 4, 256, 0, stream>>>(att);
    // PV: 64-tile split-K x4 into zeroed o
    hipMemsetAsync(o, 0, (size_t)NTOK * H * 4, stream);
    {
      dim3 g(1, S / 64, Bb * NHd * 4);
      k_sgemm64<5, false, 4><<<g, 256, 0, stream>>>(att, (long)S * S, S, vf, (long)S * HD, HD,
                                                    o, NHd, (long)S * H, HD, H, S, HD, S,
                                                    nullptr, nullptr, nullptr);
    }
    // Wo: split-K x8 into zeroed tmp (=qf), then x += tmp + bo
    hipMemsetAsync(qf, 0, (size_t)NTOK * H * 4, stream);
    sgemm128<5, false, 8>(stream, o, 0, H, Wo + (size_t)l * H * H, 0, H, qf, 1, 0, 0, H,
                          nullptr, 0, NTOK, H, H, 1, nullptr, nullptr, nullptr, 1.f);
    k_addres<<<(NTOK * (H / 4) + 255) / 256, 256, 0, stream>>>(x, qf, bo + l * H);

    // --- MoE ---
    k_layernorm<false><<<NTOK / 4, 256, 0, stream>>>(x, ln2w + l * H, ln2b + l * H, hbuf);
    hipMemsetAsync(counts, 0, 2 * E * sizeof(int), stream);
    k_router<<<NTOK / 4, 256, 0, stream>>>(hbuf, Wr + (size_t)l * H * E, br + l * E, sel_w,
                                           sel_e, counts);
    k_offsets<<<1, 64, 0, stream>>>(counts, offs);
    k_scatter<<<(NTOK + 255) / 256, 256, 0, stream>>>(sel_e, offs, cursor, tok_lst, slot_of);
    if (l == 0) {
      // upstream of router 1: experts in f32
      sgemm128<4, true, 1>(stream, hbuf, 0, H, W1 + (size_t)l * E * H * F, (long)H * F, F,
                           act_f, 1, 0, 0, F, b1 + (size_t)l * E * F, F, NSLOT, F, H, E,
                           counts, offs, tok_lst, 1.f);
      // W2: split-K x2, accumulate into zeroed oe; b2 bias applied in k_combine
      hipMemsetAsync(oe, 0, (size_t)NSLOT * H * 4, stream);
      sgemm128<5, false, 2>(stream, act_f, 0, F, W2 + (size_t)l * E * F * H, (long)F * H, H,
                            oe, 1, 0, 0, H, nullptr, 0, NSLOT, H, F, E, counts, offs, nullptr,
                            1.f);
    } else {
      // downstream of all routers: bf16 MFMA experts
      k_f32_to_bf16<<<(NTOK * H / 4 + 255) / 256, 256, 0, stream>>>(hbuf, xb2,
                                                                    (long)NTOK * H / 4);
      bgemm<4, true, false>(stream, xb2, 0, H, W1T, (long)F * H, H, act_b, 1, 0, 0, F,
                            b1 + (size_t)l * E * F, F, NSLOT, F, H, E, counts, offs, tok_lst);
      bgemm<0, false, false>(stream, act_b, 0, F, W2T, (long)H * F, F, oe, 1, 0, 0, H, nullptr,
                             0, NSLOT, H, F, E, counts, offs, nullptr);
    }
    k_combine<<<(NTOK * (H / 4) + 255) / 256, 256, 0, stream>>>(oe, sel_w, slot_of, sel_e,
                                                                b2 + (size_t)l * E * H, x);
  }

  // --- final LN + tied logits (bf16 MFMA, N-major swizzle for B-locality) ---
  k_layernorm<true><<<NTOK / 4, 256, 0, stream>>>(x, lnfw, lnfb, xb);
  bgemm<0, false, true>(stream, xb, 0, H, embB, 0, H, out, 1, 0, 0, V, nullptr, 0, NTOK, V, H,
                        1, nullptr, nullptr, nullptr);
}

// Round 7
// 2695.462 us; speedup vs baseline: 1.0431x; 1.0431x over previous
//
#include <hip/hip_runtime.h>
#include <stdint.h>

// ---------------- dims ----------------
constexpr int L = 2, Bb = 2, S = 1024, H = 768, NHd = 12, HD = 64;
constexpr int E = 8, F = 3072, V = 50257;
constexpr int NTOK = Bb * S;        // 2048
constexpr int NSLOT = NTOK * 2;     // 4096 (top-2)
constexpr float EPSLN = 1e-5f;

typedef __attribute__((ext_vector_type(4))) float f32x4;
typedef __attribute__((ext_vector_type(8))) short s16x8;

#define DEVI __device__ __forceinline__

DEVI float bf2f(short u) {
  union { float f; uint32_t i; } c; c.i = ((uint32_t)(uint16_t)u) << 16; return c.f;
}
DEVI short f2bf(float f) {
  union { float f; uint32_t i; } c; c.f = f;
  uint32_t x = c.i;
  uint32_t r = (x + 0x7fffu + ((x >> 16) & 1u)) >> 16;  // RNE
  return (short)r;
}

DEVI void gload16(const void* g, void* l) {
  __builtin_amdgcn_global_load_lds(g, l, 16, 0, 0);
}

DEVI float gelu1(float g) { return 0.5f * g * (1.f + erff(g * 0.70710678118f)); }

// ---------------- small kernels ----------------
__global__ void k_f32_to_bf16(const float* __restrict__ in, short* __restrict__ out, long n4) {
  long i = (long)blockIdx.x * blockDim.x + threadIdx.x;
  if (i >= n4) return;
  long base = i * 4;
  f32x4 v = *(const f32x4*)(in + base);
  short4 o;
  o.x = f2bf(v.x); o.y = f2bf(v.y); o.z = f2bf(v.z); o.w = f2bf(v.w);
  *(short4*)(out + base) = o;
}

// in  f32 [batch][R][C]  ->  out bf16 [batch][C][R]
__global__ void k_transpose_bf16(const float* __restrict__ in, short* __restrict__ out,
                                 int R, int C, long inBS, long outBS) {
  __shared__ float tile[32][33];
  const float* src = in + (size_t)blockIdx.z * inBS;
  short* dst = out + (size_t)blockIdx.z * outBS;
  int r0 = blockIdx.y * 32, c0 = blockIdx.x * 32;
  int tx = threadIdx.x, ty = threadIdx.y;
#pragma unroll
  for (int i = 0; i < 32; i += 8) {
    int r = r0 + ty + i, c = c0 + tx;
    if (r < R && c < C) tile[ty + i][tx] = src[(size_t)r * C + c];
  }
  __syncthreads();
#pragma unroll
  for (int i = 0; i < 32; i += 8) {
    int c = c0 + ty + i, r = r0 + tx;
    if (r < R && c < C) dst[(size_t)c * R + r] = f2bf(tile[tx][ty + i]);
  }
}

__global__ void k_bqkv(const float* __restrict__ bq, const float* __restrict__ bk,
                       const float* __restrict__ bv, float* __restrict__ bqkv) {
  int i = blockIdx.x * blockDim.x + threadIdx.x;
  if (i >= L * 3 * H) return;
  int l = i / (3 * H), j = i % (3 * H);
  float v = (j < H) ? bq[l * H + j] : (j < 2 * H) ? bk[l * H + j - H] : bv[l * H + j - 2 * H];
  bqkv[i] = v;
}

// concat Wq|Wk|Wv of layer l into [768][2304] ([k][n])
__global__ void k_wcat(const float* __restrict__ Wq, const float* __restrict__ Wk,
                       const float* __restrict__ Wv, float* __restrict__ out) {
  int i = blockIdx.x * blockDim.x + threadIdx.x;  // H*H
  if (i >= H * H) return;
  int k = i / H, n = i % H;
  out[(size_t)k * 3 * H + n] = Wq[i];
  out[(size_t)k * 3 * H + H + n] = Wk[i];
  out[(size_t)k * 3 * H + 2 * H + n] = Wv[i];
}

__global__ void k_ropetab(float* __restrict__ cosT, float* __restrict__ sinT) {
  int i = blockIdx.x * blockDim.x + threadIdx.x;
  if (i >= S * (HD / 2)) return;
  int s = i / 32, d = i % 32;
  float invf = powf(10000.f, -(2.f * d) / (float)HD);
  float ang = (float)s * invf;
  cosT[i] = cosf(ang);
  sinT[i] = sinf(ang);
}

__global__ void k_embed(const int* __restrict__ ids, const float* __restrict__ emb,
                        float* __restrict__ x) {
  int idx = blockIdx.x * blockDim.x + threadIdx.x;  // NTOK*(H/4)
  int row = idx / (H / 4), c4 = idx % (H / 4);
  if (row >= NTOK) return;
  int t = ids[row];
  ((f32x4*)(x + (size_t)row * H))[c4] = ((const f32x4*)(emb + (size_t)t * H))[c4];
}

// ---------------- layernorm (f32 in, f32 or bf16 out) ----------------
template <bool BF>
__global__ void k_layernorm(const float* __restrict__ x, const float* __restrict__ w,
                            const float* __restrict__ b, void* __restrict__ outp) {
  int row = blockIdx.x * (blockDim.x >> 6) + (threadIdx.x >> 6);
  int lane = threadIdx.x & 63;
  if (row >= NTOK) return;
  const float* xr = x + (size_t)row * H;
  float v[12], s = 0.f, s2 = 0.f;
#pragma unroll
  for (int j = 0; j < 12; j++) { float t = xr[lane + j * 64]; v[j] = t; s += t; s2 += t * t; }
#pragma unroll
  for (int off = 32; off; off >>= 1) { s += __shfl_xor(s, off); s2 += __shfl_xor(s2, off); }
  float m = s / (float)H;
  float var = s2 / (float)H - m * m;
  float rs = 1.f / sqrtf(var + EPSLN);
#pragma unroll
  for (int j = 0; j < 12; j++) {
    int c = lane + j * 64;
    float val = (v[j] - m) * rs * w[c] + b[c];
    if (BF) ((short*)outp)[(size_t)row * H + c] = f2bf(val);
    else    ((float*)outp)[(size_t)row * H + c] = val;
  }
}

// ---------------- rope (all f32; adds QKV bias pre-rotation) ----------------
__global__ void k_rope(const float* __restrict__ qkv, const float* __restrict__ bqkv,
                       const float* __restrict__ cosT, const float* __restrict__ sinT,
                       float* __restrict__ qf, float* __restrict__ kT,
                       float* __restrict__ vf) {
  int idx = blockIdx.x * blockDim.x + threadIdx.x;  // B*S*NH*32
  if (idx >= Bb * S * NHd * 32) return;
  int d = idx & 31;
  int h = (idx >> 5) % NHd;
  int t = idx / (32 * NHd);  // token = b*S+s
  int s = t % S, b = t / S;
  const float* base = qkv + (size_t)t * (3 * H) + h * HD;
  const float* bb = bqkv + h * HD;
  float c = cosT[s * 32 + d], sn = sinT[s * 32 + d];
  float q1 = base[d] + bb[d],               q2 = base[d + 32] + bb[d + 32];
  float k1 = base[H + d] + bb[H + d],       k2 = base[H + d + 32] + bb[H + d + 32];
  float v1 = base[2 * H + d] + bb[2 * H + d], v2 = base[2 * H + d + 32] + bb[2 * H + d + 32];
  size_t z = (size_t)(b * NHd + h);
  size_t qk = (z * S + s) * HD;
  qf[qk + d]      = q1 * c - q2 * sn;
  qf[qk + d + 32] = q2 * c + q1 * sn;
  kT[z * HD * S + (size_t)d * S + s]        = k1 * c - k2 * sn;
  kT[z * HD * S + (size_t)(d + 32) * S + s] = k2 * c + k1 * sn;
  vf[qk + d]      = v1;
  vf[qk + d + 32] = v2;
}

// ---------------- softmax (f32 in place) ----------------
__global__ void k_softmax(float* __restrict__ att) {
  int row = blockIdx.x * (blockDim.x >> 6) + (threadIdx.x >> 6);  // B*NH*S rows
  int lane = threadIdx.x & 63;
  if (row >= Bb * NHd * S) return;
  float* pr = att + (size_t)row * S;
  float v[16], mx = -3e38f;
#pragma unroll
  for (int j = 0; j < 16; j++) { v[j] = pr[lane + j * 64]; mx = fmaxf(mx, v[j]); }
#pragma unroll
  for (int off = 32; off; off >>= 1) mx = fmaxf(mx, __shfl_xor(mx, off));
  float sum = 0.f;
#pragma unroll
  for (int j = 0; j < 16; j++) { v[j] = expf(v[j] - mx); sum += v[j]; }
#pragma unroll
  for (int off = 32; off; off >>= 1) sum += __shfl_xor(sum, off);
  float inv = 1.f / sum;
#pragma unroll
  for (int j = 0; j < 16; j++) pr[lane + j * 64] = v[j] * inv;
}

// x += tmp + bias(col)
__global__ void k_addres(float* __restrict__ x, const float* __restrict__ tmp,
                         const float* __restrict__ bo) {
  int idx = blockIdx.x * blockDim.x + threadIdx.x;  // NTOK*(H/4)
  if (idx >= NTOK * (H / 4)) return;
  int c4 = idx % (H / 4);
  f32x4 t = ((const f32x4*)tmp)[idx];
  f32x4 b = *(const f32x4*)(bo + c4 * 4);
  f32x4* xp = (f32x4*)x + idx;
  *xp = *xp + t + b;
}

// ---------------- router (f32 h input -> exact top-2) ----------------
__global__ void k_router(const float* __restrict__ h, const float* __restrict__ Wr,
                         const float* __restrict__ br, float* __restrict__ sel_w,
                         int* __restrict__ sel_e, int* __restrict__ counts) {
  int tok = blockIdx.x * (blockDim.x >> 6) + (threadIdx.x >> 6);
  int lane = threadIdx.x & 63;
  if (tok >= NTOK) return;
  const float* hr = h + (size_t)tok * H;
  float acc[8] = {0, 0, 0, 0, 0, 0, 0, 0};
  for (int i = lane; i < H; i += 64) {
    float hv = hr[i];
    const f32x4* w4 = (const f32x4*)(Wr + (size_t)i * E);
    f32x4 a = w4[0], b = w4[1];
    acc[0] += hv * a.x; acc[1] += hv * a.y; acc[2] += hv * a.z; acc[3] += hv * a.w;
    acc[4] += hv * b.x; acc[5] += hv * b.y; acc[6] += hv * b.z; acc[7] += hv * b.w;
  }
#pragma unroll
  for (int off = 32; off; off >>= 1)
#pragma unroll
    for (int e = 0; e < 8; e++) acc[e] += __shfl_xor(acc[e], off);
  if (lane == 0) {
    float lg[8], m = -3e38f;
#pragma unroll
    for (int e = 0; e < 8; e++) { lg[e] = acc[e] + br[e]; m = fmaxf(m, lg[e]); }
    float sum = 0.f;
#pragma unroll
    for (int e = 0; e < 8; e++) { lg[e] = expf(lg[e] - m); sum += lg[e]; }
    float inv = 1.f / sum;
#pragma unroll
    for (int e = 0; e < 8; e++) lg[e] *= inv;
    int i1 = 0;
#pragma unroll
    for (int e = 1; e < 8; e++) if (lg[e] > lg[i1]) i1 = e;
    int i2 = (i1 == 0) ? 1 : 0;
#pragma unroll
    for (int e = 0; e < 8; e++) if (e != i1 && lg[e] > lg[i2]) i2 = e;
    float p1 = lg[i1], p2 = lg[i2];
    float ws = p1 + p2 + 1e-9f;
    sel_e[tok * 2] = i1; sel_e[tok * 2 + 1] = i2;
    sel_w[tok * 2] = p1 / ws; sel_w[tok * 2 + 1] = p2 / ws;
    atomicAdd(counts + i1, 1);
    atomicAdd(counts + i2, 1);
  }
}

__global__ void k_offsets(const int* __restrict__ counts, int* __restrict__ offs) {
  if (threadIdx.x == 0) {
    int a = 0;
    for (int e = 0; e < E; e++) { offs[e] = a; a += counts[e]; }
    offs[E] = a;
  }
}

__global__ void k_scatter(const int* __restrict__ sel_e, const int* __restrict__ offs,
                          int* __restrict__ cursor, int* __restrict__ tok_list,
                          int* __restrict__ slot_of) {
  int tok = blockIdx.x * blockDim.x + threadIdx.x;
  if (tok >= NTOK) return;
  for (int k = 0; k < 2; k++) {
    int e = sel_e[tok * 2 + k];
    int pos = atomicAdd(cursor + e, 1);
    int g = offs[e] + pos;
    tok_list[g] = tok;
    slot_of[tok * 2 + k] = g;
  }
}

// ff = sum_k w_k * (oe[slot_k] + b2[e_k]); x += ff
__global__ void k_combine(const float* __restrict__ oe, const float* __restrict__ sel_w,
                          const int* __restrict__ slot_of, const int* __restrict__ sel_e,
                          const float* __restrict__ b2, float* __restrict__ x) {
  int idx = blockIdx.x * blockDim.x + threadIdx.x;  // NTOK*(H/4)
  if (idx >= NTOK * (H / 4)) return;
  int tok = idx / (H / 4), c4 = idx % (H / 4);
  float w0 = sel_w[tok * 2], w1 = sel_w[tok * 2 + 1];
  int s0 = slot_of[tok * 2], s1 = slot_of[tok * 2 + 1];
  int e0 = sel_e[tok * 2], e1 = sel_e[tok * 2 + 1];
  f32x4 a = ((const f32x4*)(oe + (size_t)s0 * H))[c4];
  f32x4 b = ((const f32x4*)(oe + (size_t)s1 * H))[c4];
  f32x4 ba = ((const f32x4*)(b2 + (size_t)e0 * H))[c4];
  f32x4 bb = ((const f32x4*)(b2 + (size_t)e1 * H))[c4];
  f32x4* xp = (f32x4*)(x + (size_t)tok * H) + c4;
  *xp = *xp + w0 * (a + ba) + w1 * (b + bb);
}

// ---------------- f32 SGEMM, 128x128 tile, 8x8 micro, K-step 8, split-K ------
// C[z][m][n] = sum_k A[z][row(m)][k] * B[z][k][n]    (all f32)
// Requires N % 128 == 0 and (K/KSPLIT) % 8 == 0.
// MODE 0: +bias(opt)  2: acc*alpha + causal  4: gelu(acc+bias)  5: atomicAdd
// Register-prefetch pipeline: tile t+1's global loads are issued right after
// the LDS-write barrier, so their ~600cy latency hides under tile t's 8x64 FMAs.
template <int MODE, bool GATHER, int KSPLIT>
__global__ __launch_bounds__(256, 2) void k_sgemm128(
    const float* __restrict__ A, long sAz, int lda,
    const float* __restrict__ B, long sBz, int ldb,
    float* __restrict__ C, int zdiv, long sChi, long sClo, int ldc,
    const float* __restrict__ bias, long sBias,
    int M, int N, int K,
    const int* __restrict__ cnts, const int* __restrict__ offs,
    const int* __restrict__ gidx, float alpha) {
  const int z = blockIdx.z / KSPLIT;
  const int ks = blockIdx.z % KSPLIT;
  const int Kc = K / KSPLIT;
  const int Meff = cnts ? cnts[z] : M;
  const int tm = blockIdx.y;
  if (tm * 128 >= Meff) return;
  const int tn = blockIdx.x;
  const int row_base = offs ? offs[z] : 0;

  __shared__ float As[8][128];
  __shared__ float Bs[8][132];

  const int tid = threadIdx.x;

  // A staging: thread t -> row t>>1, k-quad (t&1)*4
  int arow = tm * 128 + (tid >> 1);
  if (arow > Meff - 1) arow = Meff - 1;
  int agr = row_base + arow;
  if (GATHER) agr = gidx[agr];
  const int am = tid >> 1, ak = (tid & 1) * 4;
  const float* aP = A + (size_t)z * sAz + (size_t)agr * lda + ks * Kc + ak;

  // B staging: thread t -> k-row t>>5, col-quad (t&31)*4
  const int bk = tid >> 5, bn4 = (tid & 31) * 4;
  const float* bP = B + (size_t)z * sBz + (size_t)(ks * Kc + bk) * ldb + tn * 128 + bn4;

  f32x4 accA[8], accB[8];
#pragma unroll
  for (int i = 0; i < 8; ++i) {
    accA[i] = {0.f, 0.f, 0.f, 0.f};
    accB[i] = {0.f, 0.f, 0.f, 0.f};
  }
  const int ty = tid >> 4, tx = tid & 15;

  // prologue: load tile 0
  f32x4 av = *(const f32x4*)aP;
  f32x4 bv = *(const f32x4*)bP;

  for (int k0 = 0; k0 < Kc; k0 += 8) {
    __syncthreads();  // previous compute done; LDS safe to overwrite
    As[ak + 0][am] = av.x; As[ak + 1][am] = av.y;
    As[ak + 2][am] = av.z; As[ak + 3][am] = av.w;
    *(f32x4*)&Bs[bk][bn4] = bv;
    __syncthreads();
    // issue next tile's loads NOW; they fly under the FMA block below
    if (k0 + 8 < Kc) {
      aP += 8;
      bP += (size_t)8 * ldb;
      av = *(const f32x4*)aP;
      bv = *(const f32x4*)bP;
    }
#pragma unroll
    for (int kk = 0; kk < 8; ++kk) {
      const f32x4 a0 = *(const f32x4*)&As[kk][ty * 8];
      const f32x4 a1 = *(const f32x4*)&As[kk][ty * 8 + 4];
      const f32x4 b0 = *(const f32x4*)&Bs[kk][tx * 4];
      const f32x4 b1 = *(const f32x4*)&Bs[kk][64 + tx * 4];
      accA[0] += a0.x * b0; accB[0] += a0.x * b1;
      accA[1] += a0.y * b0; accB[1] += a0.y * b1;
      accA[2] += a0.z * b0; accB[2] += a0.z * b1;
      accA[3] += a0.w * b0; accB[3] += a0.w * b1;
      accA[4] += a1.x * b0; accB[4] += a1.x * b1;
      accA[5] += a1.y * b0; accB[5] += a1.y * b1;
      accA[6] += a1.z * b0; accB[6] += a1.z * b1;
      accA[7] += a1.w * b0; accB[7] += a1.w * b1;
    }
  }

  const long out_off = (long)(z / zdiv) * sChi + (long)(z % zdiv) * sClo;
  const float* bz = bias ? bias + (size_t)z * sBias : nullptr;
  const int gc0 = tn * 128 + tx * 4;        // cols gc0..gc0+3 and gc0+64..gc0+67
  f32x4 bva = {0.f, 0.f, 0.f, 0.f}, bvb = {0.f, 0.f, 0.f, 0.f};
  if ((MODE == 0 || MODE == 4) && bz) {
    bva = *(const f32x4*)&bz[gc0];
    bvb = *(const f32x4*)&bz[gc0 + 64];
  }
#pragma unroll
  for (int i = 0; i < 8; ++i) {
    const int lrow = tm * 128 + ty * 8 + i;
    if (lrow >= Meff) continue;
    const long orow = row_base + lrow;
    const long idx = out_off + orow * (long)ldc + gc0;
    if (MODE == 5) {
      atomicAdd(&C[idx + 0], accA[i].x);
      atomicAdd(&C[idx + 1], accA[i].y);
      atomicAdd(&C[idx + 2], accA[i].z);
      atomicAdd(&C[idx + 3], accA[i].w);
      atomicAdd(&C[idx + 64], accB[i].x);
      atomicAdd(&C[idx + 65], accB[i].y);
      atomicAdd(&C[idx + 66], accB[i].z);
      atomicAdd(&C[idx + 67], accB[i].w);
      continue;
    }
    f32x4 v0, v1;
    if (MODE == 0) {
      v0 = accA[i] + bva;
      v1 = accB[i] + bvb;
    } else if (MODE == 2) {
      v0.x = accA[i].x * alpha + ((gc0 + 0 > lrow) ? -1e9f : 0.f);
      v0.y = accA[i].y * alpha + ((gc0 + 1 > lrow) ? -1e9f : 0.f);
      v0.z = accA[i].z * alpha + ((gc0 + 2 > lrow) ? -1e9f : 0.f);
      v0.w = accA[i].w * alpha + ((gc0 + 3 > lrow) ? -1e9f : 0.f);
      v1.x = accB[i].x * alpha + ((gc0 + 64 > lrow) ? -1e9f : 0.f);
      v1.y = accB[i].y * alpha + ((gc0 + 65 > lrow) ? -1e9f : 0.f);
      v1.z = accB[i].z * alpha + ((gc0 + 66 > lrow) ? -1e9f : 0.f);
      v1.w = accB[i].w * alpha + ((gc0 + 67 > lrow) ? -1e9f : 0.f);
    } else if (MODE == 4) {
      v0.x = gelu1(accA[i].x + bva.x);
      v0.y = gelu1(accA[i].y + bva.y);
      v0.z = gelu1(accA[i].z + bva.z);
      v0.w = gelu1(accA[i].w + bva.w);
      v1.x = gelu1(accB[i].x + bvb.x);
      v1.y = gelu1(accB[i].y + bvb.y);
      v1.z = gelu1(accB[i].z + bvb.z);
      v1.w = gelu1(accB[i].w + bvb.w);
    }
    *(f32x4*)&C[idx] = v0;
    *(f32x4*)&C[idx + 64] = v1;
  }
}

template <int MODE, bool GATHER, int KSPLIT>
static void sgemm128(hipStream_t st, const float* A, long sAz, int lda, const float* B,
                     long sBz, int ldb, float* C, int zdiv, long sChi, long sClo, int ldc,
                     const float* bias, long sBias, int M, int N, int K, int nz,
                     const int* cnts, const int* offs_, const int* gat, float alpha) {
  dim3 g(N / 128, (M + 127) / 128, nz * KSPLIT);
  k_sgemm128<MODE, GATHER, KSPLIT><<<g, 256, 0, st>>>(A, sAz, lda, B, sBz, ldb, C, zdiv, sChi,
                                                      sClo, ldc, bias, sBias, M, N, K, cnts,
                                                      offs_, gat, alpha);
}

// ---------------- f32 SGEMM 64x64 (for PV: N=64), register-prefetch ----------
// MODE 5 only in practice: atomicAdd accumulate.
template <int MODE, bool GATHER, int KSPLIT>
__global__ __launch_bounds__(256, 4) void k_sgemm64(
    const float* __restrict__ A, long sAz, int lda,
    const float* __restrict__ B, long sBz, int ldb,
    float* __restrict__ C, int zdiv, long sChi, long sClo, int ldc,
    int M, int N, int K,
    const int* __restrict__ cnts, const int* __restrict__ offs,
    const int* __restrict__ gidx) {
  const int z = blockIdx.z / KSPLIT;
  const int ks = blockIdx.z % KSPLIT;
  const int Kc = K / KSPLIT;
  const int Meff = cnts ? cnts[z] : M;
  const int tm = blockIdx.y;
  if (tm * 64 >= Meff) return;
  const int tn = blockIdx.x;
  const int row_base = offs ? offs[z] : 0;

  __shared__ float As[16][64];
  __shared__ float Bs[16][68];

  const int tid = threadIdx.x;
  int arow = tm * 64 + (tid >> 2);
  if (arow > Meff - 1) arow = Meff - 1;
  int agr = row_base + arow;
  if (GATHER) agr = gidx[agr];
  const int am = tid >> 2, ak = (tid & 3) * 4;
  const float* aP = A + (size_t)z * sAz + (size_t)agr * lda + ks * Kc + ak;
  const int bk = tid >> 4, bn4 = (tid & 15) * 4;
  const float* bP = B + (size_t)z * sBz + (size_t)(ks * Kc + bk) * ldb + tn * 64 + bn4;

  f32x4 acc4[4];
#pragma unroll
  for (int i = 0; i < 4; ++i) acc4[i] = {0.f, 0.f, 0.f, 0.f};
  const int ty = tid >> 4, tx = tid & 15;

  f32x4 av = *(const f32x4*)aP;
  f32x4 bv = *(const f32x4*)bP;

  for (int k0 = 0; k0 < Kc; k0 += 16) {
    __syncthreads();
    As[ak + 0][am] = av.x; As[ak + 1][am] = av.y;
    As[ak + 2][am] = av.z; As[ak + 3][am] = av.w;
    *(f32x4*)&Bs[bk][bn4] = bv;
    __syncthreads();
    if (k0 + 16 < Kc) {
      aP += 16;
      bP += (size_t)16 * ldb;
      av = *(const f32x4*)aP;
      bv = *(const f32x4*)bP;
    }
#pragma unroll
    for (int kk = 0; kk < 16; ++kk) {
      const f32x4 a4 = *(const f32x4*)&As[kk][ty * 4];
      const f32x4 b4 = *(const f32x4*)&Bs[kk][tx * 4];
      acc4[0] += a4.x * b4;
      acc4[1] += a4.y * b4;
      acc4[2] += a4.z * b4;
      acc4[3] += a4.w * b4;
    }
  }

  const long out_off = (long)(z / zdiv) * sChi + (long)(z % zdiv) * sClo;
  const int gc0 = tn * 64 + tx * 4;
#pragma unroll
  for (int i = 0; i < 4; ++i) {
    const int lrow = tm * 64 + ty * 4 + i;
    if (lrow >= Meff) continue;
    const long orow = row_base + lrow;
    const long idx = out_off + orow * (long)ldc + gc0;
    atomicAdd(&C[idx + 0], acc4[i].x);
    atomicAdd(&C[idx + 1], acc4[i].y);
    atomicAdd(&C[idx + 2], acc4[i].z);
    atomicAdd(&C[idx + 3], acc4[i].w);
  }
}

// ---------------- bf16 MFMA GEMM ----------------
// C[z][m][n] = sum_k A[z][row(m)][k] * Bt[z][n][k]   (A,Bt bf16; acc f32)
// MODE 0: f32 out (+bias opt)   4: bf16 out = gelu(acc + bias)
// NSWZ: remap grid so consecutive blocks share the same N-tile (B-locality).
template <int MODE, bool GATHER, bool NSWZ>
__global__ __launch_bounds__(256, 2) void k_bgemm(
    const short* __restrict__ A, long sAz, int lda,
    const short* __restrict__ Bt, long sBz, int ldb,
    void* __restrict__ Cp, int zdiv, long sChi, long sClo, int ldc,
    const float* __restrict__ bias, long sBias,
    int M, int N, int K,
    const int* __restrict__ d_counts, const int* __restrict__ d_offs,
    const int* __restrict__ gidx) {
  const int z = blockIdx.z;
  const int Meff = d_counts ? d_counts[z] : M;
  int tm, tn;
  if (NSWZ) {
    const int bid = blockIdx.y * gridDim.x + blockIdx.x;
    tn = bid / gridDim.y;
    tm = bid % gridDim.y;
  } else {
    tm = blockIdx.y;
    tn = blockIdx.x;
  }
  if (tm * 128 >= Meff) return;
  const int row_base = d_offs ? d_offs[z] : 0;

  __shared__ short Abuf[128 * 32];
  __shared__ short Bbuf[128 * 32];

  const int tid = threadIdx.x;
  const int lane = tid & 63;
  const int w = tid >> 6;

  const short* Az = A + (size_t)z * sAz;
  const short* Bz = Bt + (size_t)z * sBz;

  const short* aSrc[2];
  const short* bSrc[2];
#pragma unroll
  for (int i = 0; i < 2; ++i) {
    const int srow = i * 64 + (tid >> 2);
    const int kb = (tid & 3) ^ (srow & 3);  // XOR swizzle (both-sides involution)
    int lrow = tm * 128 + srow;
    if (lrow > Meff - 1) lrow = Meff - 1;
    int ar = row_base + lrow;
    if (GATHER) ar = gidx[ar];
    aSrc[i] = Az + (size_t)ar * lda + kb * 8;
    int bcol = tn * 128 + srow;
    if (bcol > N - 1) bcol = N - 1;
    bSrc[i] = Bz + (size_t)bcol * ldb + kb * 8;
  }

  f32x4 acc[4][4];
#pragma unroll
  for (int a = 0; a < 4; ++a)
#pragma unroll
    for (int b = 0; b < 4; ++b) acc[a][b] = {0.f, 0.f, 0.f, 0.f};

  const int wr = (w >> 1) * 64;
  const int wc = (w & 1) * 64;
  const int r16 = lane & 15;
  const int kb4 = lane >> 4;
  const int swz = (kb4 ^ (r16 & 3)) * 8;
  int aoff[4], boff[4];
#pragma unroll
  for (int i = 0; i < 4; ++i) {
    aoff[i] = (wr + i * 16 + r16) * 32 + swz;
    boff[i] = (wc + i * 16 + r16) * 32 + swz;
  }
  char* const ldsA0 = (char*)Abuf + w * 1024;
  char* const ldsA1 = (char*)Abuf + 4096 + w * 1024;
  char* const ldsB0 = (char*)Bbuf + w * 1024;
  char* const ldsB1 = (char*)Bbuf + 4096 + w * 1024;

  for (int k0 = 0; k0 < K; k0 += 32) {
    gload16(aSrc[0], ldsA0);
    gload16(aSrc[1], ldsA1);
    gload16(bSrc[0], ldsB0);
    gload16(bSrc[1], ldsB1);
    aSrc[0] += 32; aSrc[1] += 32; bSrc[0] += 32; bSrc[1] += 32;
    __syncthreads();
    s16x8 af[4], bf[4];
#pragma unroll
    for (int i = 0; i < 4; ++i) {
      af[i] = *(const s16x8*)(Abuf + aoff[i]);
      bf[i] = *(const s16x8*)(Bbuf + boff[i]);
    }
#pragma unroll
    for (int mi = 0; mi < 4; ++mi)
#pragma unroll
      for (int ni = 0; ni < 4; ++ni)
        acc[mi][ni] =
            __builtin_amdgcn_mfma_f32_16x16x32_bf16(af[mi], bf[ni], acc[mi][ni], 0, 0, 0);
    __syncthreads();
  }

  const long out_off = (long)(z / zdiv) * sChi + (long)(z % zdiv) * sClo;
  const float* bz = bias ? (bias + (size_t)z * sBias) : nullptr;
  const int q4 = lane >> 4;
  float bvv[4];
  int gco[4];
#pragma unroll
  for (int ni = 0; ni < 4; ++ni) {
    gco[ni] = tn * 128 + wc + ni * 16 + r16;
    bvv[ni] = (bz && gco[ni] < N) ? bz[gco[ni]] : 0.f;
  }
#pragma unroll
  for (int mi = 0; mi < 4; ++mi) {
#pragma unroll
    for (int j = 0; j < 4; ++j) {
      const int lrow = tm * 128 + wr + mi * 16 + q4 * 4 + j;
      if (lrow >= Meff) continue;
      const long rbase = out_off + (row_base + lrow) * (long)ldc;
#pragma unroll
      for (int ni = 0; ni < 4; ++ni) {
        if (gco[ni] >= N) continue;
        const float v = acc[mi][ni][j];
        if (MODE == 0) {
          ((float*)Cp)[rbase + gco[ni]] = v + bvv[ni];
        } else if (MODE == 4) {
          float g = v + bvv[ni];
          ((short*)Cp)[rbase + gco[ni]] = f2bf(gelu1(g));
        }
      }
    }
  }
}

template <int MODE, bool GATHER, bool NSWZ>
static void bgemm(hipStream_t st, const short* A, long sAz, int lda, const short* Bt, long sBz,
                  int ldb, void* C, int zdiv, long sChi, long sClo, int ldc, const float* bias,
                  long sBias, int M, int N, int K, int nz, const int* cnts, const int* offs_,
                  const int* gat) {
  dim3 g((N + 127) / 128, (M + 127) / 128, nz);
  k_bgemm<MODE, GATHER, NSWZ><<<g, 256, 0, st>>>(A, sAz, lda, Bt, sBz, ldb, C, zdiv, sChi,
                                                 sClo, ldc, bias, sBias, M, N, K, cnts, offs_,
                                                 gat);
}

// ---------------- launch ----------------
extern "C" void kernel_launch(void* const* d_in, const int* in_sizes, int n_in, void* d_out,
                              int out_size, void* d_ws, size_t ws_size, hipStream_t stream) {
  (void)in_sizes; (void)n_in; (void)out_size; (void)ws_size;
  const int*   ids  = (const int*)d_in[0];
  const float* emb  = (const float*)d_in[1];
  const float* ln1w = (const float*)d_in[2];
  const float* ln1b = (const float*)d_in[3];
  const float* ln2w = (const float*)d_in[4];
  const float* ln2b = (const float*)d_in[5];
  const float* lnfw = (const float*)d_in[6];
  const float* lnfb = (const float*)d_in[7];
  const float* Wq = (const float*)d_in[8];
  const float* bq = (const float*)d_in[9];
  const float* Wk = (const float*)d_in[10];
  const float* bk = (const float*)d_in[11];
  const float* Wv = (const float*)d_in[12];
  const float* bv = (const float*)d_in[13];
  const float* Wo = (const float*)d_in[14];
  const float* bo = (const float*)d_in[15];
  const float* Wr = (const float*)d_in[16];
  const float* br = (const float*)d_in[17];
  const float* W1 = (const float*)d_in[18];
  const float* b1 = (const float*)d_in[19];
  const float* W2 = (const float*)d_in[20];
  const float* b2 = (const float*)d_in[21];
  float* out = (float*)d_out;

  char* p = (char*)d_ws;
  auto alloc = [&](size_t bytes) {
    char* r = p;
    p += (bytes + 255) & ~(size_t)255;
    return r;
  };
  short* embB = (short*)alloc((size_t)V * H * 2);          // 77.2 MB
  short* W1T  = (short*)alloc((size_t)E * F * H * 2);      // 37.7 MB (layer 1, [E][F][H])
  short* W2T  = (short*)alloc((size_t)E * H * F * 2);      // 37.7 MB (layer 1, [E][H][F])
  float* bqkv = (float*)alloc((size_t)L * 3 * H * 4);
  float* Wcat = (float*)alloc((size_t)3 * H * H * 4);      // 7.1 MB (per-layer reuse)
  float* cosT = (float*)alloc((size_t)S * 32 * 4);
  float* sinT = (float*)alloc((size_t)S * 32 * 4);
  float* x    = (float*)alloc((size_t)NTOK * H * 4);
  float* hbuf = (float*)alloc((size_t)NTOK * H * 4);
  float* qf   = (float*)alloc((size_t)NTOK * H * 4);       // also reused as Wo split-K tmp
  float* kT   = (float*)alloc((size_t)NTOK * H * 4);
  float* vf   = (float*)alloc((size_t)NTOK * H * 4);
  float* o    = (float*)alloc((size_t)NTOK * H * 4);
  short* xb   = (short*)alloc((size_t)NTOK * H * 2);
  short* xb2  = (short*)alloc((size_t)NTOK * H * 2);
  // union region: qkvl (18.9MB) | att f32 (100.7MB) | act f32 (50.3) / act bf16 (25.2) + oe
  char* uni = alloc((size_t)Bb * NHd * S * S * 4);         // 100.7 MB
  float* qkvl  = (float*)uni;
  float* att   = (float*)uni;
  float* act_f = (float*)uni;
  short* act_b = (short*)uni;
  float* oe    = (float*)(uni + (size_t)NSLOT * F * 4);
  int* counts  = (int*)alloc(2 * E * 4);
  int* cursor  = counts + E;
  int* offs    = (int*)alloc((E + 1) * 4);
  int* sel_e   = (int*)alloc((size_t)NTOK * 2 * 4);
  float* sel_w = (float*)alloc((size_t)NTOK * 2 * 4);
  int* slot_of = (int*)alloc((size_t)NTOK * 2 * 4);
  int* tok_lst = (int*)alloc((size_t)NSLOT * 4);

  // ---- prologue ----
  long nEmb4 = (long)V * H / 4;
  k_f32_to_bf16<<<(nEmb4 + 255) / 256, 256, 0, stream>>>(emb, embB, nEmb4);
  k_bqkv<<<(L * 3 * H + 255) / 256, 256, 0, stream>>>(bq, bk, bv, bqkv);
  k_ropetab<<<(S * 32 + 255) / 256, 256, 0, stream>>>(cosT, sinT);
  k_embed<<<(NTOK * (H / 4) + 255) / 256, 256, 0, stream>>>(ids, emb, x);
  // layer-1 expert weights -> transposed bf16 (downstream of all routers)
  dim3 tb(32, 8);
  k_transpose_bf16<<<dim3(F / 32, H / 32, E), tb, 0, stream>>>(
      W1 + (size_t)1 * E * H * F, W1T, H, F, (long)H * F, (long)F * H);
  k_transpose_bf16<<<dim3(H / 32, F / 32, E), tb, 0, stream>>>(
      W2 + (size_t)1 * E * F * H, W2T, F, H, (long)F * H, (long)H * F);

  for (int l = 0; l < L; l++) {
    // --- attention (f32; upstream of routers) ---
    k_layernorm<false><<<NTOK / 4, 256, 0, stream>>>(x, ln1w + l * H, ln1b + l * H, hbuf);
    k_wcat<<<(H * H + 255) / 256, 256, 0, stream>>>(Wq + (size_t)l * H * H,
                                                    Wk + (size_t)l * H * H,
                                                    Wv + (size_t)l * H * H, Wcat);
    // QKV: split-K x2, accumulate into zeroed qkvl; bias applied in k_rope
    hipMemsetAsync(qkvl, 0, (size_t)NTOK * 3 * H * 4, stream);
    sgemm128<5, false, 2>(stream, hbuf, 0, H, Wcat, 0, 3 * H, qkvl, 1, 0, 0, 3 * H, nullptr, 0,
                          NTOK, 3 * H, H, 1, nullptr, nullptr, nullptr, 1.f);
    k_rope<<<(Bb * S * NHd * 32 + 255) / 256, 256, 0, stream>>>(qkvl, bqkv + l * 3 * H, cosT,
                                                                sinT, qf, kT, vf);
    // QK^T: 128-tile, causal + scale
    sgemm128<2, false, 1>(stream, qf, (long)S * HD, HD, kT, (long)HD * S, S, att, 1,
                          (long)S * S, 0, S, nullptr, 0, S, S, HD, Bb * NHd, nullptr, nullptr,
                          nullptr, 0.125f);
    k_softmax<<<(Bb * NHd * S) / 4, 256, 0, stream>>>(att);
    // PV: 64-tile split-K x4 into zeroed o
    hipMemsetAsync(o, 0, (size_t)NTOK * H * 4, stream);
    {
      dim3 g(1, S / 64, Bb * NHd * 4);
      k_sgemm64<5, false, 4><<<g, 256, 0, stream>>>(att, (long)S * S, S, vf, (long)S * HD, HD,
                                                    o, NHd, (long)S * H, HD, H, S, HD, S,
                                                    nullptr, nullptr, nullptr);
    }
    // Wo: split-K x8 into zeroed tmp (=qf), then x += tmp + bo
    hipMemsetAsync(qf, 0, (size_t)NTOK * H * 4, stream);
    sgemm128<5, false, 8>(stream, o, 0, H, Wo + (size_t)l * H * H, 0, H, qf, 1, 0, 0, H,
                          nullptr, 0, NTOK, H, H, 1, nullptr, nullptr, nullptr, 1.f);
    k_addres<<<(NTOK * (H / 4) + 255) / 256, 256, 0, stream>>>(x, qf, bo + l * H);

    // --- MoE ---
    k_layernorm<false><<<NTOK / 4, 256, 0, stream>>>(x, ln2w + l * H, ln2b + l * H, hbuf);
    hipMemsetAsync(counts, 0, 2 * E * sizeof(int), stream);
    k_router<<<NTOK / 4, 256, 0, stream>>>(hbuf, Wr + (size_t)l * H * E, br + l * E, sel_w,
                                           sel_e, counts);
    k_offsets<<<1, 64, 0, stream>>>(counts, offs);
    k_scatter<<<(NTOK + 255) / 256, 256, 0, stream>>>(sel_e, offs, cursor, tok_lst, slot_of);
    if (l == 0) {
      // upstream of router 1: experts in f32
      sgemm128<4, true, 1>(stream, hbuf, 0, H, W1 + (size_t)l * E * H * F, (long)H * F, F,
                           act_f, 1, 0, 0, F, b1 + (size_t)l * E * F, F, NSLOT, F, H, E,
                           counts, offs, tok_lst, 1.f);
      // W2: split-K x4, accumulate into zeroed oe; b2 bias applied in k_combine
      hipMemsetAsync(oe, 0, (size_t)NSLOT * H * 4, stream);
      sgemm128<5, false, 4>(stream, act_f, 0, F, W2 + (size_t)l * E * F * H, (long)F * H, H,
                            oe, 1, 0, 0, H, nullptr, 0, NSLOT, H, F, E, counts, offs, nullptr,
                            1.f);
    } else {
      // downstream of all routers: bf16 MFMA experts
      k_f32_to_bf16<<<(NTOK * H / 4 + 255) / 256, 256, 0, stream>>>(hbuf, xb2,
                                                                    (long)NTOK * H / 4);
      bgemm<4, true, false>(stream, xb2, 0, H, W1T, (long)F * H, H, act_b, 1, 0, 0, F,
                            b1 + (size_t)l * E * F, F, NSLOT, F, H, E, counts, offs, tok_lst);
      bgemm<0, false, false>(stream, act_b, 0, F, W2T, (long)H * F, F, oe, 1, 0, 0, H, nullptr,
                             0, NSLOT, H, F, E, counts, offs, nullptr);
    }
    k_combine<<<(NTOK * (H / 4) + 255) / 256, 256, 0, stream>>>(oe, sel_w, slot_of, sel_e,
                                                                b2 + (size_t)l * E * H, x);
  }

  // --- final LN + tied logits (bf16 MFMA, N-major swizzle for B-locality) ---
  k_layernorm<true><<<NTOK / 4, 256, 0, stream>>>(x, lnfw, lnfb, xb);
  bgemm<0, false, true>(stream, xb, 0, H, embB, 0, H, out, 1, 0, 0, V, nullptr, 0, NTOK, V, H,
                        1, nullptr, nullptr, nullptr);
}

// Round 8
// 2386.771 us; speedup vs baseline: 1.1780x; 1.1293x over previous
//
#include <hip/hip_runtime.h>
#include <stdint.h>

// ---------------- dims ----------------
constexpr int L = 2, Bb = 2, S = 1024, H = 768, NHd = 12, HD = 64;
constexpr int E = 8, F = 3072, V = 50257;
constexpr int NTOK = Bb * S;        // 2048
constexpr int NSLOT = NTOK * 2;     // 4096 (top-2)
constexpr float EPSLN = 1e-5f;

typedef __attribute__((ext_vector_type(4))) float f32x4;
typedef __attribute__((ext_vector_type(8))) short s16x8;

#define DEVI __device__ __forceinline__

DEVI float bf2f(short u) {
  union { float f; uint32_t i; } c; c.i = ((uint32_t)(uint16_t)u) << 16; return c.f;
}
DEVI short f2bf(float f) {
  union { float f; uint32_t i; } c; c.f = f;
  uint32_t x = c.i;
  uint32_t r = (x + 0x7fffu + ((x >> 16) & 1u)) >> 16;  // RNE
  return (short)r;
}

DEVI void gload16(const void* g, void* l) {
  __builtin_amdgcn_global_load_lds(g, l, 16, 0, 0);
}

DEVI float gelu1(float g) { return 0.5f * g * (1.f + erff(g * 0.70710678118f)); }

// ---------------- small kernels ----------------
__global__ void k_f32_to_bf16(const float* __restrict__ in, short* __restrict__ out, long n4) {
  long i = (long)blockIdx.x * blockDim.x + threadIdx.x;
  if (i >= n4) return;
  long base = i * 4;
  f32x4 v = *(const f32x4*)(in + base);
  short4 o;
  o.x = f2bf(v.x); o.y = f2bf(v.y); o.z = f2bf(v.z); o.w = f2bf(v.w);
  *(short4*)(out + base) = o;
}

// f32 -> (hi, lo) double-bf16 split, elementwise x4
__global__ void k_split(const float* __restrict__ in, short* __restrict__ oh,
                        short* __restrict__ ol, long n4) {
  long i = (long)blockIdx.x * blockDim.x + threadIdx.x;
  if (i >= n4) return;
  long base = i * 4;
  f32x4 v = *(const f32x4*)(in + base);
  short4 h, l;
  h.x = f2bf(v.x); l.x = f2bf(v.x - bf2f(h.x));
  h.y = f2bf(v.y); l.y = f2bf(v.y - bf2f(h.y));
  h.z = f2bf(v.z); l.z = f2bf(v.z - bf2f(h.z));
  h.w = f2bf(v.w); l.w = f2bf(v.w - bf2f(h.w));
  *(short4*)(oh + base) = h;
  *(short4*)(ol + base) = l;
}

// in  f32 [batch][R][C]  ->  out bf16 [batch][C][R]
__global__ void k_transpose_bf16(const float* __restrict__ in, short* __restrict__ out,
                                 int R, int C, long inBS, long outBS) {
  __shared__ float tile[32][33];
  const float* src = in + (size_t)blockIdx.z * inBS;
  short* dst = out + (size_t)blockIdx.z * outBS;
  int r0 = blockIdx.y * 32, c0 = blockIdx.x * 32;
  int tx = threadIdx.x, ty = threadIdx.y;
#pragma unroll
  for (int i = 0; i < 32; i += 8) {
    int r = r0 + ty + i, c = c0 + tx;
    if (r < R && c < C) tile[ty + i][tx] = src[(size_t)r * C + c];
  }
  __syncthreads();
#pragma unroll
  for (int i = 0; i < 32; i += 8) {
    int c = c0 + ty + i, r = r0 + tx;
    if (r < R && c < C) dst[(size_t)c * R + r] = f2bf(tile[tx][ty + i]);
  }
}

// in f32 [batch][R][C] -> hi/lo bf16 [batch][C][R]
__global__ void k_transpose_split(const float* __restrict__ in, short* __restrict__ oh,
                                  short* __restrict__ ol, int R, int C, long inBS,
                                  long outBS) {
  __shared__ float tile[32][33];
  const float* src = in + (size_t)blockIdx.z * inBS;
  short* dh = oh + (size_t)blockIdx.z * outBS;
  short* dl = ol + (size_t)blockIdx.z * outBS;
  int r0 = blockIdx.y * 32, c0 = blockIdx.x * 32;
  int tx = threadIdx.x, ty = threadIdx.y;
#pragma unroll
  for (int i = 0; i < 32; i += 8) {
    int r = r0 + ty + i, c = c0 + tx;
    if (r < R && c < C) tile[ty + i][tx] = src[(size_t)r * C + c];
  }
  __syncthreads();
#pragma unroll
  for (int i = 0; i < 32; i += 8) {
    int c = c0 + ty + i, r = r0 + tx;
    if (r < R && c < C) {
      float v = tile[tx][ty + i];
      short hi = f2bf(v);
      short lo = f2bf(v - bf2f(hi));
      dh[(size_t)c * R + r] = hi;
      dl[(size_t)c * R + r] = lo;
    }
  }
}

__global__ void k_bqkv(const float* __restrict__ bq, const float* __restrict__ bk,
                       const float* __restrict__ bv, float* __restrict__ bqkv) {
  int i = blockIdx.x * blockDim.x + threadIdx.x;
  if (i >= L * 3 * H) return;
  int l = i / (3 * H), j = i % (3 * H);
  float v = (j < H) ? bq[l * H + j] : (j < 2 * H) ? bk[l * H + j - H] : bv[l * H + j - 2 * H];
  bqkv[i] = v;
}

// concat Wq|Wk|Wv of layer l into [768][2304] ([k][n])
__global__ void k_wcat(const float* __restrict__ Wq, const float* __restrict__ Wk,
                       const float* __restrict__ Wv, float* __restrict__ out) {
  int i = blockIdx.x * blockDim.x + threadIdx.x;  // H*H
  if (i >= H * H) return;
  int k = i / H, n = i % H;
  out[(size_t)k * 3 * H + n] = Wq[i];
  out[(size_t)k * 3 * H + H + n] = Wk[i];
  out[(size_t)k * 3 * H + 2 * H + n] = Wv[i];
}

__global__ void k_ropetab(float* __restrict__ cosT, float* __restrict__ sinT) {
  int i = blockIdx.x * blockDim.x + threadIdx.x;
  if (i >= S * (HD / 2)) return;
  int s = i / 32, d = i % 32;
  float invf = powf(10000.f, -(2.f * d) / (float)HD);
  float ang = (float)s * invf;
  cosT[i] = cosf(ang);
  sinT[i] = sinf(ang);
}

__global__ void k_embed(const int* __restrict__ ids, const float* __restrict__ emb,
                        float* __restrict__ x) {
  int idx = blockIdx.x * blockDim.x + threadIdx.x;  // NTOK*(H/4)
  int row = idx / (H / 4), c4 = idx % (H / 4);
  if (row >= NTOK) return;
  int t = ids[row];
  ((f32x4*)(x + (size_t)row * H))[c4] = ((const f32x4*)(emb + (size_t)t * H))[c4];
}

// ---------------- layernorm (f32 in, f32 or bf16 out) ----------------
template <bool BF>
__global__ void k_layernorm(const float* __restrict__ x, const float* __restrict__ w,
                            const float* __restrict__ b, void* __restrict__ outp) {
  int row = blockIdx.x * (blockDim.x >> 6) + (threadIdx.x >> 6);
  int lane = threadIdx.x & 63;
  if (row >= NTOK) return;
  const float* xr = x + (size_t)row * H;
  float v[12], s = 0.f, s2 = 0.f;
#pragma unroll
  for (int j = 0; j < 12; j++) { float t = xr[lane + j * 64]; v[j] = t; s += t; s2 += t * t; }
#pragma unroll
  for (int off = 32; off; off >>= 1) { s += __shfl_xor(s, off); s2 += __shfl_xor(s2, off); }
  float m = s / (float)H;
  float var = s2 / (float)H - m * m;
  float rs = 1.f / sqrtf(var + EPSLN);
#pragma unroll
  for (int j = 0; j < 12; j++) {
    int c = lane + j * 64;
    float val = (v[j] - m) * rs * w[c] + b[c];
    if (BF) ((short*)outp)[(size_t)row * H + c] = f2bf(val);
    else    ((float*)outp)[(size_t)row * H + c] = val;
  }
}

// ---------------- rope (all f32; adds QKV bias pre-rotation) ----------------
__global__ void k_rope(const float* __restrict__ qkv, const float* __restrict__ bqkv,
                       const float* __restrict__ cosT, const float* __restrict__ sinT,
                       float* __restrict__ qf, float* __restrict__ kT,
                       float* __restrict__ vf) {
  int idx = blockIdx.x * blockDim.x + threadIdx.x;  // B*S*NH*32
  if (idx >= Bb * S * NHd * 32) return;
  int d = idx & 31;
  int h = (idx >> 5) % NHd;
  int t = idx / (32 * NHd);  // token = b*S+s
  int s = t % S, b = t / S;
  const float* base = qkv + (size_t)t * (3 * H) + h * HD;
  const float* bb = bqkv + h * HD;
  float c = cosT[s * 32 + d], sn = sinT[s * 32 + d];
  float q1 = base[d] + bb[d],               q2 = base[d + 32] + bb[d + 32];
  float k1 = base[H + d] + bb[H + d],       k2 = base[H + d + 32] + bb[H + d + 32];
  float v1 = base[2 * H + d] + bb[2 * H + d], v2 = base[2 * H + d + 32] + bb[2 * H + d + 32];
  size_t z = (size_t)(b * NHd + h);
  size_t qk = (z * S + s) * HD;
  qf[qk + d]      = q1 * c - q2 * sn;
  qf[qk + d + 32] = q2 * c + q1 * sn;
  kT[z * HD * S + (size_t)d * S + s]        = k1 * c - k2 * sn;
  kT[z * HD * S + (size_t)(d + 32) * S + s] = k2 * c + k1 * sn;
  vf[qk + d]      = v1;
  vf[qk + d + 32] = v2;
}

// ---------------- softmax (f32 in place) ----------------
__global__ void k_softmax(float* __restrict__ att) {
  int row = blockIdx.x * (blockDim.x >> 6) + (threadIdx.x >> 6);  // B*NH*S rows
  int lane = threadIdx.x & 63;
  if (row >= Bb * NHd * S) return;
  float* pr = att + (size_t)row * S;
  float v[16], mx = -3e38f;
#pragma unroll
  for (int j = 0; j < 16; j++) { v[j] = pr[lane + j * 64]; mx = fmaxf(mx, v[j]); }
#pragma unroll
  for (int off = 32; off; off >>= 1) mx = fmaxf(mx, __shfl_xor(mx, off));
  float sum = 0.f;
#pragma unroll
  for (int j = 0; j < 16; j++) { v[j] = expf(v[j] - mx); sum += v[j]; }
#pragma unroll
  for (int off = 32; off; off >>= 1) sum += __shfl_xor(sum, off);
  float inv = 1.f / sum;
#pragma unroll
  for (int j = 0; j < 16; j++) pr[lane + j * 64] = v[j] * inv;
}

// x += tmp + bias(col)
__global__ void k_addres(float* __restrict__ x, const float* __restrict__ tmp,
                         const float* __restrict__ bo) {
  int idx = blockIdx.x * blockDim.x + threadIdx.x;  // NTOK*(H/4)
  if (idx >= NTOK * (H / 4)) return;
  int c4 = idx % (H / 4);
  f32x4 t = ((const f32x4*)tmp)[idx];
  f32x4 b = *(const f32x4*)(bo + c4 * 4);
  f32x4* xp = (f32x4*)x + idx;
  *xp = *xp + t + b;
}

// ---------------- router (f32 h input -> exact top-2) ----------------
__global__ void k_router(const float* __restrict__ h, const float* __restrict__ Wr,
                         const float* __restrict__ br, float* __restrict__ sel_w,
                         int* __restrict__ sel_e, int* __restrict__ counts) {
  int tok = blockIdx.x * (blockDim.x >> 6) + (threadIdx.x >> 6);
  int lane = threadIdx.x & 63;
  if (tok >= NTOK) return;
  const float* hr = h + (size_t)tok * H;
  float acc[8] = {0, 0, 0, 0, 0, 0, 0, 0};
  for (int i = lane; i < H; i += 64) {
    float hv = hr[i];
    const f32x4* w4 = (const f32x4*)(Wr + (size_t)i * E);
    f32x4 a = w4[0], b = w4[1];
    acc[0] += hv * a.x; acc[1] += hv * a.y; acc[2] += hv * a.z; acc[3] += hv * a.w;
    acc[4] += hv * b.x; acc[5] += hv * b.y; acc[6] += hv * b.z; acc[7] += hv * b.w;
  }
#pragma unroll
  for (int off = 32; off; off >>= 1)
#pragma unroll
    for (int e = 0; e < 8; e++) acc[e] += __shfl_xor(acc[e], off);
  if (lane == 0) {
    float lg[8], m = -3e38f;
#pragma unroll
    for (int e = 0; e < 8; e++) { lg[e] = acc[e] + br[e]; m = fmaxf(m, lg[e]); }
    float sum = 0.f;
#pragma unroll
    for (int e = 0; e < 8; e++) { lg[e] = expf(lg[e] - m); sum += lg[e]; }
    float inv = 1.f / sum;
#pragma unroll
    for (int e = 0; e < 8; e++) lg[e] *= inv;
    int i1 = 0;
#pragma unroll
    for (int e = 1; e < 8; e++) if (lg[e] > lg[i1]) i1 = e;
    int i2 = (i1 == 0) ? 1 : 0;
#pragma unroll
    for (int e = 0; e < 8; e++) if (e != i1 && lg[e] > lg[i2]) i2 = e;
    float p1 = lg[i1], p2 = lg[i2];
    float ws = p1 + p2 + 1e-9f;
    sel_e[tok * 2] = i1; sel_e[tok * 2 + 1] = i2;
    sel_w[tok * 2] = p1 / ws; sel_w[tok * 2 + 1] = p2 / ws;
    atomicAdd(counts + i1, 1);
    atomicAdd(counts + i2, 1);
  }
}

__global__ void k_offsets(const int* __restrict__ counts, int* __restrict__ offs) {
  if (threadIdx.x == 0) {
    int a = 0;
    for (int e = 0; e < E; e++) { offs[e] = a; a += counts[e]; }
    offs[E] = a;
  }
}

__global__ void k_scatter(const int* __restrict__ sel_e, const int* __restrict__ offs,
                          int* __restrict__ cursor, int* __restrict__ tok_list,
                          int* __restrict__ slot_of) {
  int tok = blockIdx.x * blockDim.x + threadIdx.x;
  if (tok >= NTOK) return;
  for (int k = 0; k < 2; k++) {
    int e = sel_e[tok * 2 + k];
    int pos = atomicAdd(cursor + e, 1);
    int g = offs[e] + pos;
    tok_list[g] = tok;
    slot_of[tok * 2 + k] = g;
  }
}

// ff = sum_k w_k * (oe[slot_k] + b2[e_k]); x += ff
__global__ void k_combine(const float* __restrict__ oe, const float* __restrict__ sel_w,
                          const int* __restrict__ slot_of, const int* __restrict__ sel_e,
                          const float* __restrict__ b2, float* __restrict__ x) {
  int idx = blockIdx.x * blockDim.x + threadIdx.x;  // NTOK*(H/4)
  if (idx >= NTOK * (H / 4)) return;
  int tok = idx / (H / 4), c4 = idx % (H / 4);
  float w0 = sel_w[tok * 2], w1 = sel_w[tok * 2 + 1];
  int s0 = slot_of[tok * 2], s1 = slot_of[tok * 2 + 1];
  int e0 = sel_e[tok * 2], e1 = sel_e[tok * 2 + 1];
  f32x4 a = ((const f32x4*)(oe + (size_t)s0 * H))[c4];
  f32x4 b = ((const f32x4*)(oe + (size_t)s1 * H))[c4];
  f32x4 ba = ((const f32x4*)(b2 + (size_t)e0 * H))[c4];
  f32x4 bb = ((const f32x4*)(b2 + (size_t)e1 * H))[c4];
  f32x4* xp = (f32x4*)(x + (size_t)tok * H) + c4;
  *xp = *xp + w0 * (a + ba) + w1 * (b + bb);
}

// ---------------- f32 SGEMM, 128x128 tile, 8x8 micro, K-step 8, split-K ------
// (attention only now) MODE 0:+bias  2: acc*alpha+causal  5: atomicAdd
template <int MODE, bool GATHER, int KSPLIT>
__global__ __launch_bounds__(256, 2) void k_sgemm128(
    const float* __restrict__ A, long sAz, int lda,
    const float* __restrict__ B, long sBz, int ldb,
    float* __restrict__ C, int zdiv, long sChi, long sClo, int ldc,
    const float* __restrict__ bias, long sBias,
    int M, int N, int K,
    const int* __restrict__ cnts, const int* __restrict__ offs,
    const int* __restrict__ gidx, float alpha) {
  const int z = blockIdx.z / KSPLIT;
  const int ks = blockIdx.z % KSPLIT;
  const int Kc = K / KSPLIT;
  const int Meff = cnts ? cnts[z] : M;
  const int tm = blockIdx.y;
  if (tm * 128 >= Meff) return;
  const int tn = blockIdx.x;
  const int row_base = offs ? offs[z] : 0;

  __shared__ float As[8][128];
  __shared__ float Bs[8][132];

  const int tid = threadIdx.x;

  int arow = tm * 128 + (tid >> 1);
  if (arow > Meff - 1) arow = Meff - 1;
  int agr = row_base + arow;
  if (GATHER) agr = gidx[agr];
  const int am = tid >> 1, ak = (tid & 1) * 4;
  const float* aP = A + (size_t)z * sAz + (size_t)agr * lda + ks * Kc + ak;

  const int bk = tid >> 5, bn4 = (tid & 31) * 4;
  const float* bP = B + (size_t)z * sBz + (size_t)(ks * Kc + bk) * ldb + tn * 128 + bn4;

  f32x4 accA[8], accB[8];
#pragma unroll
  for (int i = 0; i < 8; ++i) {
    accA[i] = {0.f, 0.f, 0.f, 0.f};
    accB[i] = {0.f, 0.f, 0.f, 0.f};
  }
  const int ty = tid >> 4, tx = tid & 15;

  f32x4 av = *(const f32x4*)aP;
  f32x4 bv = *(const f32x4*)bP;

  for (int k0 = 0; k0 < Kc; k0 += 8) {
    __syncthreads();
    As[ak + 0][am] = av.x; As[ak + 1][am] = av.y;
    As[ak + 2][am] = av.z; As[ak + 3][am] = av.w;
    *(f32x4*)&Bs[bk][bn4] = bv;
    __syncthreads();
    if (k0 + 8 < Kc) {
      aP += 8;
      bP += (size_t)8 * ldb;
      av = *(const f32x4*)aP;
      bv = *(const f32x4*)bP;
    }
#pragma unroll
    for (int kk = 0; kk < 8; ++kk) {
      const f32x4 a0 = *(const f32x4*)&As[kk][ty * 8];
      const f32x4 a1 = *(const f32x4*)&As[kk][ty * 8 + 4];
      const f32x4 b0 = *(const f32x4*)&Bs[kk][tx * 4];
      const f32x4 b1 = *(const f32x4*)&Bs[kk][64 + tx * 4];
      accA[0] += a0.x * b0; accB[0] += a0.x * b1;
      accA[1] += a0.y * b0; accB[1] += a0.y * b1;
      accA[2] += a0.z * b0; accB[2] += a0.z * b1;
      accA[3] += a0.w * b0; accB[3] += a0.w * b1;
      accA[4] += a1.x * b0; accB[4] += a1.x * b1;
      accA[5] += a1.y * b0; accB[5] += a1.y * b1;
      accA[6] += a1.z * b0; accB[6] += a1.z * b1;
      accA[7] += a1.w * b0; accB[7] += a1.w * b1;
    }
  }

  const long out_off = (long)(z / zdiv) * sChi + (long)(z % zdiv) * sClo;
  const float* bz = bias ? bias + (size_t)z * sBias : nullptr;
  const int gc0 = tn * 128 + tx * 4;
  f32x4 bva = {0.f, 0.f, 0.f, 0.f}, bvb = {0.f, 0.f, 0.f, 0.f};
  if (MODE == 0 && bz) {
    bva = *(const f32x4*)&bz[gc0];
    bvb = *(const f32x4*)&bz[gc0 + 64];
  }
#pragma unroll
  for (int i = 0; i < 8; ++i) {
    const int lrow = tm * 128 + ty * 8 + i;
    if (lrow >= Meff) continue;
    const long orow = row_base + lrow;
    const long idx = out_off + orow * (long)ldc + gc0;
    if (MODE == 5) {
      atomicAdd(&C[idx + 0], accA[i].x);
      atomicAdd(&C[idx + 1], accA[i].y);
      atomicAdd(&C[idx + 2], accA[i].z);
      atomicAdd(&C[idx + 3], accA[i].w);
      atomicAdd(&C[idx + 64], accB[i].x);
      atomicAdd(&C[idx + 65], accB[i].y);
      atomicAdd(&C[idx + 66], accB[i].z);
      atomicAdd(&C[idx + 67], accB[i].w);
      continue;
    }
    f32x4 v0, v1;
    if (MODE == 0) {
      v0 = accA[i] + bva;
      v1 = accB[i] + bvb;
    } else if (MODE == 2) {
      v0.x = accA[i].x * alpha + ((gc0 + 0 > lrow) ? -1e9f : 0.f);
      v0.y = accA[i].y * alpha + ((gc0 + 1 > lrow) ? -1e9f : 0.f);
      v0.z = accA[i].z * alpha + ((gc0 + 2 > lrow) ? -1e9f : 0.f);
      v0.w = accA[i].w * alpha + ((gc0 + 3 > lrow) ? -1e9f : 0.f);
      v1.x = accB[i].x * alpha + ((gc0 + 64 > lrow) ? -1e9f : 0.f);
      v1.y = accB[i].y * alpha + ((gc0 + 65 > lrow) ? -1e9f : 0.f);
      v1.z = accB[i].z * alpha + ((gc0 + 66 > lrow) ? -1e9f : 0.f);
      v1.w = accB[i].w * alpha + ((gc0 + 67 > lrow) ? -1e9f : 0.f);
    }
    *(f32x4*)&C[idx] = v0;
    *(f32x4*)&C[idx + 64] = v1;
  }
}

template <int MODE, bool GATHER, int KSPLIT>
static void sgemm128(hipStream_t st, const float* A, long sAz, int lda, const float* B,
                     long sBz, int ldb, float* C, int zdiv, long sChi, long sClo, int ldc,
                     const float* bias, long sBias, int M, int N, int K, int nz,
                     const int* cnts, const int* offs_, const int* gat, float alpha) {
  dim3 g(N / 128, (M + 127) / 128, nz * KSPLIT);
  k_sgemm128<MODE, GATHER, KSPLIT><<<g, 256, 0, st>>>(A, sAz, lda, B, sBz, ldb, C, zdiv, sChi,
                                                      sClo, ldc, bias, sBias, M, N, K, cnts,
                                                      offs_, gat, alpha);
}

// ---------------- f32 SGEMM 64x64 (for PV: N=64), register-prefetch ----------
template <int MODE, bool GATHER, int KSPLIT>
__global__ __launch_bounds__(256, 4) void k_sgemm64(
    const float* __restrict__ A, long sAz, int lda,
    const float* __restrict__ B, long sBz, int ldb,
    float* __restrict__ C, int zdiv, long sChi, long sClo, int ldc,
    int M, int N, int K,
    const int* __restrict__ cnts, const int* __restrict__ offs,
    const int* __restrict__ gidx) {
  const int z = blockIdx.z / KSPLIT;
  const int ks = blockIdx.z % KSPLIT;
  const int Kc = K / KSPLIT;
  const int Meff = cnts ? cnts[z] : M;
  const int tm = blockIdx.y;
  if (tm * 64 >= Meff) return;
  const int tn = blockIdx.x;
  const int row_base = offs ? offs[z] : 0;

  __shared__ float As[16][64];
  __shared__ float Bs[16][68];

  const int tid = threadIdx.x;
  int arow = tm * 64 + (tid >> 2);
  if (arow > Meff - 1) arow = Meff - 1;
  int agr = row_base + arow;
  if (GATHER) agr = gidx[agr];
  const int am = tid >> 2, ak = (tid & 3) * 4;
  const float* aP = A + (size_t)z * sAz + (size_t)agr * lda + ks * Kc + ak;
  const int bk = tid >> 4, bn4 = (tid & 15) * 4;
  const float* bP = B + (size_t)z * sBz + (size_t)(ks * Kc + bk) * ldb + tn * 64 + bn4;

  f32x4 acc4[4];
#pragma unroll
  for (int i = 0; i < 4; ++i) acc4[i] = {0.f, 0.f, 0.f, 0.f};
  const int ty = tid >> 4, tx = tid & 15;

  f32x4 av = *(const f32x4*)aP;
  f32x4 bv = *(const f32x4*)bP;

  for (int k0 = 0; k0 < Kc; k0 += 16) {
    __syncthreads();
    As[ak + 0][am] = av.x; As[ak + 1][am] = av.y;
    As[ak + 2][am] = av.z; As[ak + 3][am] = av.w;
    *(f32x4*)&Bs[bk][bn4] = bv;
    __syncthreads();
    if (k0 + 16 < Kc) {
      aP += 16;
      bP += (size_t)16 * ldb;
      av = *(const f32x4*)aP;
      bv = *(const f32x4*)bP;
    }
#pragma unroll
    for (int kk = 0; kk < 16; ++kk) {
      const f32x4 a4 = *(const f32x4*)&As[kk][ty * 4];
      const f32x4 b4 = *(const f32x4*)&Bs[kk][tx * 4];
      acc4[0] += a4.x * b4;
      acc4[1] += a4.y * b4;
      acc4[2] += a4.z * b4;
      acc4[3] += a4.w * b4;
    }
  }

  const long out_off = (long)(z / zdiv) * sChi + (long)(z % zdiv) * sClo;
  const int gc0 = tn * 64 + tx * 4;
#pragma unroll
  for (int i = 0; i < 4; ++i) {
    const int lrow = tm * 64 + ty * 4 + i;
    if (lrow >= Meff) continue;
    const long orow = row_base + lrow;
    const long idx = out_off + orow * (long)ldc + gc0;
    atomicAdd(&C[idx + 0], acc4[i].x);
    atomicAdd(&C[idx + 1], acc4[i].y);
    atomicAdd(&C[idx + 2], acc4[i].z);
    atomicAdd(&C[idx + 3], acc4[i].w);
  }
}

// ---------------- bf16 MFMA GEMM (plain) ----------------
// MODE 0: f32 out (+bias opt)   4: bf16 out = gelu(acc + bias)
template <int MODE, bool GATHER, bool NSWZ>
__global__ __launch_bounds__(256, 2) void k_bgemm(
    const short* __restrict__ A, long sAz, int lda,
    const short* __restrict__ Bt, long sBz, int ldb,
    void* __restrict__ Cp, int zdiv, long sChi, long sClo, int ldc,
    const float* __restrict__ bias, long sBias,
    int M, int N, int K,
    const int* __restrict__ d_counts, const int* __restrict__ d_offs,
    const int* __restrict__ gidx) {
  const int z = blockIdx.z;
  const int Meff = d_counts ? d_counts[z] : M;
  int tm, tn;
  if (NSWZ) {
    const int bid = blockIdx.y * gridDim.x + blockIdx.x;
    tn = bid / gridDim.y;
    tm = bid % gridDim.y;
  } else {
    tm = blockIdx.y;
    tn = blockIdx.x;
  }
  if (tm * 128 >= Meff) return;
  const int row_base = d_offs ? d_offs[z] : 0;

  __shared__ short Abuf[128 * 32];
  __shared__ short Bbuf[128 * 32];

  const int tid = threadIdx.x;
  const int lane = tid & 63;
  const int w = tid >> 6;

  const short* Az = A + (size_t)z * sAz;
  const short* Bz = Bt + (size_t)z * sBz;

  const short* aSrc[2];
  const short* bSrc[2];
#pragma unroll
  for (int i = 0; i < 2; ++i) {
    const int srow = i * 64 + (tid >> 2);
    const int kb = (tid & 3) ^ (srow & 3);
    int lrow = tm * 128 + srow;
    if (lrow > Meff - 1) lrow = Meff - 1;
    int ar = row_base + lrow;
    if (GATHER) ar = gidx[ar];
    aSrc[i] = Az + (size_t)ar * lda + kb * 8;
    int bcol = tn * 128 + srow;
    if (bcol > N - 1) bcol = N - 1;
    bSrc[i] = Bz + (size_t)bcol * ldb + kb * 8;
  }

  f32x4 acc[4][4];
#pragma unroll
  for (int a = 0; a < 4; ++a)
#pragma unroll
    for (int b = 0; b < 4; ++b) acc[a][b] = {0.f, 0.f, 0.f, 0.f};

  const int wr = (w >> 1) * 64;
  const int wc = (w & 1) * 64;
  const int r16 = lane & 15;
  const int kb4 = lane >> 4;
  const int swz = (kb4 ^ (r16 & 3)) * 8;
  int aoff[4], boff[4];
#pragma unroll
  for (int i = 0; i < 4; ++i) {
    aoff[i] = (wr + i * 16 + r16) * 32 + swz;
    boff[i] = (wc + i * 16 + r16) * 32 + swz;
  }
  char* const ldsA0 = (char*)Abuf + w * 1024;
  char* const ldsA1 = (char*)Abuf + 4096 + w * 1024;
  char* const ldsB0 = (char*)Bbuf + w * 1024;
  char* const ldsB1 = (char*)Bbuf + 4096 + w * 1024;

  for (int k0 = 0; k0 < K; k0 += 32) {
    gload16(aSrc[0], ldsA0);
    gload16(aSrc[1], ldsA1);
    gload16(bSrc[0], ldsB0);
    gload16(bSrc[1], ldsB1);
    aSrc[0] += 32; aSrc[1] += 32; bSrc[0] += 32; bSrc[1] += 32;
    __syncthreads();
    s16x8 af[4], bf[4];
#pragma unroll
    for (int i = 0; i < 4; ++i) {
      af[i] = *(const s16x8*)(Abuf + aoff[i]);
      bf[i] = *(const s16x8*)(Bbuf + boff[i]);
    }
#pragma unroll
    for (int mi = 0; mi < 4; ++mi)
#pragma unroll
      for (int ni = 0; ni < 4; ++ni)
        acc[mi][ni] =
            __builtin_amdgcn_mfma_f32_16x16x32_bf16(af[mi], bf[ni], acc[mi][ni], 0, 0, 0);
    __syncthreads();
  }

  const long out_off = (long)(z / zdiv) * sChi + (long)(z % zdiv) * sClo;
  const float* bz = bias ? (bias + (size_t)z * sBias) : nullptr;
  const int q4 = lane >> 4;
  float bvv[4];
  int gco[4];
#pragma unroll
  for (int ni = 0; ni < 4; ++ni) {
    gco[ni] = tn * 128 + wc + ni * 16 + r16;
    bvv[ni] = (bz && gco[ni] < N) ? bz[gco[ni]] : 0.f;
  }
#pragma unroll
  for (int mi = 0; mi < 4; ++mi) {
#pragma unroll
    for (int j = 0; j < 4; ++j) {
      const int lrow = tm * 128 + wr + mi * 16 + q4 * 4 + j;
      if (lrow >= Meff) continue;
      const long rbase = out_off + (row_base + lrow) * (long)ldc;
#pragma unroll
      for (int ni = 0; ni < 4; ++ni) {
        if (gco[ni] >= N) continue;
        const float v = acc[mi][ni][j];
        if (MODE == 0) {
          ((float*)Cp)[rbase + gco[ni]] = v + bvv[ni];
        } else if (MODE == 4) {
          float g = v + bvv[ni];
          ((short*)Cp)[rbase + gco[ni]] = f2bf(gelu1(g));
        }
      }
    }
  }
}

template <int MODE, bool GATHER, bool NSWZ>
static void bgemm(hipStream_t st, const short* A, long sAz, int lda, const short* Bt, long sBz,
                  int ldb, void* C, int zdiv, long sChi, long sClo, int ldc, const float* bias,
                  long sBias, int M, int N, int K, int nz, const int* cnts, const int* offs_,
                  const int* gat) {
  dim3 g((N + 127) / 128, (M + 127) / 128, nz);
  k_bgemm<MODE, GATHER, NSWZ><<<g, 256, 0, st>>>(A, sAz, lda, Bt, sBz, ldb, C, zdiv, sChi,
                                                 sClo, ldc, bias, sBias, M, N, K, cnts, offs_,
                                                 gat);
}

// ---------------- bf16x3 split MFMA GEMM (f32-accurate, router-safe) --------
// C = (Ah+Al) * (Bh+Bl)^T  ~=  Ah*Bh + Ah*Bl + Al*Bh   (3 MFMAs per frag)
// MODE 0: f32 out (+bias opt)   6: gelu(acc+bias) -> split bf16 hi/lo stores
template <int MODE, bool GATHER>
__global__ __launch_bounds__(256, 2) void k_bgemm3(
    const short* __restrict__ Ah, const short* __restrict__ Al, int lda,
    const short* __restrict__ Bh, const short* __restrict__ Bl, long sBz, int ldb,
    void* __restrict__ Cp, void* __restrict__ Cp2, int ldc,
    const float* __restrict__ bias, long sBias,
    int M, int N, int K,
    const int* __restrict__ d_counts, const int* __restrict__ d_offs,
    const int* __restrict__ gidx) {
  const int z = blockIdx.z;
  const int Meff = d_counts ? d_counts[z] : M;
  const int tm = blockIdx.y;
  if (tm * 128 >= Meff) return;
  const int tn = blockIdx.x;
  const int row_base = d_offs ? d_offs[z] : 0;

  __shared__ short AbH[128 * 32];
  __shared__ short AbL[128 * 32];
  __shared__ short BbH[128 * 32];
  __shared__ short BbL[128 * 32];

  const int tid = threadIdx.x;
  const int lane = tid & 63;
  const int w = tid >> 6;

  const short* BzH = Bh + (size_t)z * sBz;
  const short* BzL = Bl + (size_t)z * sBz;

  size_t aOff[2], bOff[2];
#pragma unroll
  for (int i = 0; i < 2; ++i) {
    const int srow = i * 64 + (tid >> 2);
    const int kb = (tid & 3) ^ (srow & 3);  // pre-swizzled source (involution)
    int lrow = tm * 128 + srow;
    if (lrow > Meff - 1) lrow = Meff - 1;
    int ar = row_base + lrow;
    if (GATHER) ar = gidx[ar];
    aOff[i] = (size_t)ar * lda + kb * 8;
    int bcol = tn * 128 + srow;
    if (bcol > N - 1) bcol = N - 1;
    bOff[i] = (size_t)bcol * ldb + kb * 8;
  }

  f32x4 acc[4][4];
#pragma unroll
  for (int a = 0; a < 4; ++a)
#pragma unroll
    for (int b = 0; b < 4; ++b) acc[a][b] = {0.f, 0.f, 0.f, 0.f};

  const int wr = (w >> 1) * 64;
  const int wc = (w & 1) * 64;
  const int r16 = lane & 15;
  const int kb4 = lane >> 4;
  const int swz = (kb4 ^ (r16 & 3)) * 8;
  int aoff[4], boff[4];
#pragma unroll
  for (int i = 0; i < 4; ++i) {
    aoff[i] = (wr + i * 16 + r16) * 32 + swz;
    boff[i] = (wc + i * 16 + r16) * 32 + swz;
  }
  char* const dAH0 = (char*)AbH + w * 1024;
  char* const dAH1 = (char*)AbH + 4096 + w * 1024;
  char* const dAL0 = (char*)AbL + w * 1024;
  char* const dAL1 = (char*)AbL + 4096 + w * 1024;
  char* const dBH0 = (char*)BbH + w * 1024;
  char* const dBH1 = (char*)BbH + 4096 + w * 1024;
  char* const dBL0 = (char*)BbL + w * 1024;
  char* const dBL1 = (char*)BbL + 4096 + w * 1024;

  for (int k0 = 0; k0 < K; k0 += 32) {
    gload16(Ah + aOff[0], dAH0);
    gload16(Ah + aOff[1], dAH1);
    gload16(Al + aOff[0], dAL0);
    gload16(Al + aOff[1], dAL1);
    gload16(BzH + bOff[0], dBH0);
    gload16(BzH + bOff[1], dBH1);
    gload16(BzL + bOff[0], dBL0);
    gload16(BzL + bOff[1], dBL1);
    aOff[0] += 32; aOff[1] += 32; bOff[0] += 32; bOff[1] += 32;
    __syncthreads();
    s16x8 afh[4], afl[4], bfh[4], bfl[4];
#pragma unroll
    for (int i = 0; i < 4; ++i) {
      afh[i] = *(const s16x8*)(AbH + aoff[i]);
      afl[i] = *(const s16x8*)(AbL + aoff[i]);
      bfh[i] = *(const s16x8*)(BbH + boff[i]);
      bfl[i] = *(const s16x8*)(BbL + boff[i]);
    }
#pragma unroll
    for (int mi = 0; mi < 4; ++mi)
#pragma unroll
      for (int ni = 0; ni < 4; ++ni) {
        f32x4 a = acc[mi][ni];
        a = __builtin_amdgcn_mfma_f32_16x16x32_bf16(afh[mi], bfh[ni], a, 0, 0, 0);
        a = __builtin_amdgcn_mfma_f32_16x16x32_bf16(afh[mi], bfl[ni], a, 0, 0, 0);
        a = __builtin_amdgcn_mfma_f32_16x16x32_bf16(afl[mi], bfh[ni], a, 0, 0, 0);
        acc[mi][ni] = a;
      }
    __syncthreads();
  }

  const float* bz = bias ? (bias + (size_t)z * sBias) : nullptr;
  const int q4 = lane >> 4;
  float bvv[4];
  int gco[4];
#pragma unroll
  for (int ni = 0; ni < 4; ++ni) {
    gco[ni] = tn * 128 + wc + ni * 16 + r16;
    bvv[ni] = (bz && gco[ni] < N) ? bz[gco[ni]] : 0.f;
  }
#pragma unroll
  for (int mi = 0; mi < 4; ++mi) {
#pragma unroll
    for (int j = 0; j < 4; ++j) {
      const int lrow = tm * 128 + wr + mi * 16 + q4 * 4 + j;
      if (lrow >= Meff) continue;
      const long rbase = (long)(row_base + lrow) * ldc;
#pragma unroll
      for (int ni = 0; ni < 4; ++ni) {
        if (gco[ni] >= N) continue;
        const float v = acc[mi][ni][j];
        if (MODE == 0) {
          ((float*)Cp)[rbase + gco[ni]] = v + bvv[ni];
        } else if (MODE == 6) {
          float g = gelu1(v + bvv[ni]);
          short hi = f2bf(g);
          short lo = f2bf(g - bf2f(hi));
          ((short*)Cp)[rbase + gco[ni]] = hi;
          ((short*)Cp2)[rbase + gco[ni]] = lo;
        }
      }
    }
  }
}

template <int MODE, bool GATHER>
static void bgemm3(hipStream_t st, const short* Ah, const short* Al, int lda, const short* Bh,
                   const short* Bl, long sBz, int ldb, void* C, void* C2, int ldc,
                   const float* bias, long sBias, int M, int N, int K, int nz,
                   const int* cnts, const int* offs_, const int* gat) {
  dim3 g(N / 128, (M + 127) / 128, nz);
  k_bgemm3<MODE, GATHER><<<g, 256, 0, st>>>(Ah, Al, lda, Bh, Bl, sBz, ldb, C, C2, ldc, bias,
                                            sBias, M, N, K, cnts, offs_, gat);
}

// ---------------- launch ----------------
extern "C" void kernel_launch(void* const* d_in, const int* in_sizes, int n_in, void* d_out,
                              int out_size, void* d_ws, size_t ws_size, hipStream_t stream) {
  (void)in_sizes; (void)n_in; (void)out_size; (void)ws_size;
  const int*   ids  = (const int*)d_in[0];
  const float* emb  = (const float*)d_in[1];
  const float* ln1w = (const float*)d_in[2];
  const float* ln1b = (const float*)d_in[3];
  const float* ln2w = (const float*)d_in[4];
  const float* ln2b = (const float*)d_in[5];
  const float* lnfw = (const float*)d_in[6];
  const float* lnfb = (const float*)d_in[7];
  const float* Wq = (const float*)d_in[8];
  const float* bq = (const float*)d_in[9];
  const float* Wk = (const float*)d_in[10];
  const float* bk = (const float*)d_in[11];
  const float* Wv = (const float*)d_in[12];
  const float* bv = (const float*)d_in[13];
  const float* Wo = (const float*)d_in[14];
  const float* bo = (const float*)d_in[15];
  const float* Wr = (const float*)d_in[16];
  const float* br = (const float*)d_in[17];
  const float* W1 = (const float*)d_in[18];
  const float* b1 = (const float*)d_in[19];
  const float* W2 = (const float*)d_in[20];
  const float* b2 = (const float*)d_in[21];
  float* out = (float*)d_out;

  char* p = (char*)d_ws;
  auto alloc = [&](size_t bytes) {
    char* r = p;
    p += (bytes + 255) & ~(size_t)255;
    return r;
  };
  short* embB = (short*)alloc((size_t)V * H * 2);          // 77.2 MB
  // R region (75.5 MB), time-shared:
  //   phase l0-W1: [W1l0_hi | W1l0_lo]   phase l0-W2: [W2l0_hi | W2l0_lo]
  //   phase l1:    [W1T | W2T]  (plain bf16 transposed)
  short* Rbuf = (short*)alloc((size_t)2 * E * F * H * 2);
  short* R_hi = Rbuf;
  short* R_lo = Rbuf + (size_t)E * F * H;
  float* bqkv = (float*)alloc((size_t)L * 3 * H * 4);
  float* Wcat = (float*)alloc((size_t)3 * H * H * 4);      // 7.1 MB
  float* cosT = (float*)alloc((size_t)S * 32 * 4);
  float* sinT = (float*)alloc((size_t)S * 32 * 4);
  float* x    = (float*)alloc((size_t)NTOK * H * 4);
  float* hbuf = (float*)alloc((size_t)NTOK * H * 4);
  float* qf   = (float*)alloc((size_t)NTOK * H * 4);       // also Wo split-K tmp
  float* kT   = (float*)alloc((size_t)NTOK * H * 4);
  float* vf   = (float*)alloc((size_t)NTOK * H * 4);
  float* o    = (float*)alloc((size_t)NTOK * H * 4);
  short* xb   = (short*)alloc((size_t)NTOK * H * 2);
  short* xb2  = (short*)alloc((size_t)NTOK * H * 2);
  short* h_hi = (short*)alloc((size_t)NTOK * H * 2);
  short* h_lo = (short*)alloc((size_t)NTOK * H * 2);
  // union region: qkvl (18.9MB) | att f32 (100.7MB) | act_hi+act_lo (50.3) + oe
  char* uni = alloc((size_t)Bb * NHd * S * S * 4);         // 100.7 MB
  float* qkvl   = (float*)uni;
  float* att    = (float*)uni;
  short* act_hi = (short*)uni;
  short* act_lo = (short*)(uni + (size_t)NSLOT * F * 2);
  short* act_b  = (short*)uni;                             // l1 plain bf16 act
  float* oe     = (float*)(uni + (size_t)NSLOT * F * 4);
  int* counts  = (int*)alloc(2 * E * 4);
  int* cursor  = counts + E;
  int* offs    = (int*)alloc((E + 1) * 4);
  int* sel_e   = (int*)alloc((size_t)NTOK * 2 * 4);
  float* sel_w = (float*)alloc((size_t)NTOK * 2 * 4);
  int* slot_of = (int*)alloc((size_t)NTOK * 2 * 4);
  int* tok_lst = (int*)alloc((size_t)NSLOT * 4);

  // ---- prologue ----
  long nEmb4 = (long)V * H / 4;
  k_f32_to_bf16<<<(nEmb4 + 255) / 256, 256, 0, stream>>>(emb, embB, nEmb4);
  k_bqkv<<<(L * 3 * H + 255) / 256, 256, 0, stream>>>(bq, bk, bv, bqkv);
  k_ropetab<<<(S * 32 + 255) / 256, 256, 0, stream>>>(cosT, sinT);
  k_embed<<<(NTOK * (H / 4) + 255) / 256, 256, 0, stream>>>(ids, emb, x);

  dim3 tb(32, 8);
  for (int l = 0; l < L; l++) {
    // --- attention (f32; upstream of routers) ---
    k_layernorm<false><<<NTOK / 4, 256, 0, stream>>>(x, ln1w + l * H, ln1b + l * H, hbuf);
    k_wcat<<<(H * H + 255) / 256, 256, 0, stream>>>(Wq + (size_t)l * H * H,
                                                    Wk + (size_t)l * H * H,
                                                    Wv + (size_t)l * H * H, Wcat);
    hipMemsetAsync(qkvl, 0, (size_t)NTOK * 3 * H * 4, stream);
    sgemm128<5, false, 2>(stream, hbuf, 0, H, Wcat, 0, 3 * H, qkvl, 1, 0, 0, 3 * H, nullptr, 0,
                          NTOK, 3 * H, H, 1, nullptr, nullptr, nullptr, 1.f);
    k_rope<<<(Bb * S * NHd * 32 + 255) / 256, 256, 0, stream>>>(qkvl, bqkv + l * 3 * H, cosT,
                                                                sinT, qf, kT, vf);
    sgemm128<2, false, 1>(stream, qf, (long)S * HD, HD, kT, (long)HD * S, S, att, 1,
                          (long)S * S, 0, S, nullptr, 0, S, S, HD, Bb * NHd, nullptr, nullptr,
                          nullptr, 0.125f);
    k_softmax<<<(Bb * NHd * S) / 4, 256, 0, stream>>>(att);
    hipMemsetAsync(o, 0, (size_t)NTOK * H * 4, stream);
    {
      dim3 g(1, S / 64, Bb * NHd * 4);
      k_sgemm64<5, false, 4><<<g, 256, 0, stream>>>(att, (long)S * S, S, vf, (long)S * HD, HD,
                                                    o, NHd, (long)S * H, HD, H, S, HD, S,
                                                    nullptr, nullptr, nullptr);
    }
    hipMemsetAsync(qf, 0, (size_t)NTOK * H * 4, stream);
    sgemm128<5, false, 8>(stream, o, 0, H, Wo + (size_t)l * H * H, 0, H, qf, 1, 0, 0, H,
                          nullptr, 0, NTOK, H, H, 1, nullptr, nullptr, nullptr, 1.f);
    k_addres<<<(NTOK * (H / 4) + 255) / 256, 256, 0, stream>>>(x, qf, bo + l * H);

    // --- MoE ---
    k_layernorm<false><<<NTOK / 4, 256, 0, stream>>>(x, ln2w + l * H, ln2b + l * H, hbuf);
    hipMemsetAsync(counts, 0, 2 * E * sizeof(int), stream);
    k_router<<<NTOK / 4, 256, 0, stream>>>(hbuf, Wr + (size_t)l * H * E, br + l * E, sel_w,
                                           sel_e, counts);
    k_offsets<<<1, 64, 0, stream>>>(counts, offs);
    k_scatter<<<(NTOK + 255) / 256, 256, 0, stream>>>(sel_e, offs, cursor, tok_lst, slot_of);
    if (l == 0) {
      // bf16x3 split MFMA experts (upstream of router 1; error ~2e-6 rel)
      k_split<<<(NTOK * H / 4 + 255) / 256, 256, 0, stream>>>(hbuf, h_hi, h_lo,
                                                              (long)NTOK * H / 4);
      // W1-l0: [E][H][F] -> transposed split [E][F][H]
      k_transpose_split<<<dim3(F / 32, H / 32, E), tb, 0, stream>>>(
          W1, R_hi, R_lo, H, F, (long)H * F, (long)F * H);
      bgemm3<6, true>(stream, h_hi, h_lo, H, R_hi, R_lo, (long)F * H, H, act_hi, act_lo, F,
                      b1, F, NSLOT, F, H, E, counts, offs, tok_lst);
      // W2-l0: [E][F][H] -> transposed split [E][H][F]   (reuses R; stream-ordered)
      k_transpose_split<<<dim3(H / 32, F / 32, E), tb, 0, stream>>>(
          W2, R_hi, R_lo, F, H, (long)F * H, (long)H * F);
      bgemm3<0, false>(stream, act_hi, act_lo, F, R_hi, R_lo, (long)H * F, F, oe, nullptr, H,
                       nullptr, 0, NSLOT, H, F, E, counts, offs, nullptr);
      k_combine<<<(NTOK * (H / 4) + 255) / 256, 256, 0, stream>>>(oe, sel_w, slot_of, sel_e,
                                                                  b2, x);
      // R now free: stage layer-1 expert weights (plain bf16 transposed)
      k_transpose_bf16<<<dim3(F / 32, H / 32, E), tb, 0, stream>>>(
          W1 + (size_t)1 * E * H * F, R_hi, H, F, (long)H * F, (long)F * H);
      k_transpose_bf16<<<dim3(H / 32, F / 32, E), tb, 0, stream>>>(
          W2 + (size_t)1 * E * F * H, R_lo, F, H, (long)F * H, (long)H * F);
    } else {
      // downstream of all routers: plain bf16 MFMA experts (W1T=R_hi, W2T=R_lo)
      k_f32_to_bf16<<<(NTOK * H / 4 + 255) / 256, 256, 0, stream>>>(hbuf, xb2,
                                                                    (long)NTOK * H / 4);
      bgemm<4, true, false>(stream, xb2, 0, H, R_hi, (long)F * H, H, act_b, 1, 0, 0, F,
                            b1 + (size_t)l * E * F, F, NSLOT, F, H, E, counts, offs, tok_lst);
      bgemm<0, false, false>(stream, act_b, 0, F, R_lo, (long)H * F, F, oe, 1, 0, 0, H,
                             nullptr, 0, NSLOT, H, F, E, counts, offs, nullptr);
      k_combine<<<(NTOK * (H / 4) + 255) / 256, 256, 0, stream>>>(oe, sel_w, slot_of, sel_e,
                                                                  b2 + (size_t)l * E * H, x);
    }
  }

  // --- final LN + tied logits (bf16 MFMA, N-major swizzle for B-locality) ---
  k_layernorm<true><<<NTOK / 4, 256, 0, stream>>>(x, lnfw, lnfb, xb);
  bgemm<0, false, true>(stream, xb, 0, H, embB, 0, H, out, 1, 0, 0, V, nullptr, 0, NTOK, V, H,
                        1, nullptr, nullptr, nullptr);
}

// Round 9
// 1792.316 us; speedup vs baseline: 1.5687x; 1.3317x over previous
//
#include <hip/hip_runtime.h>
#include <stdint.h>

// ---------------- dims ----------------
constexpr int L = 2, Bb = 2, S = 1024, H = 768, NHd = 12, HD = 64;
constexpr int E = 8, F = 3072, V = 50257;
constexpr int NTOK = Bb * S;        // 2048
constexpr int NSLOT = NTOK * 2;     // 4096 (top-2)
constexpr float EPSLN = 1e-5f;

typedef __attribute__((ext_vector_type(4))) float f32x4;
typedef __attribute__((ext_vector_type(8))) short s16x8;

#define DEVI __device__ __forceinline__

DEVI float bf2f(short u) {
  union { float f; uint32_t i; } c; c.i = ((uint32_t)(uint16_t)u) << 16; return c.f;
}
DEVI short f2bf(float f) {
  union { float f; uint32_t i; } c; c.f = f;
  uint32_t x = c.i;
  uint32_t r = (x + 0x7fffu + ((x >> 16) & 1u)) >> 16;  // RNE
  return (short)r;
}

DEVI void gload16(const void* g, void* l) {
  __builtin_amdgcn_global_load_lds(g, l, 16, 0, 0);
}

DEVI float gelu1(float g) { return 0.5f * g * (1.f + erff(g * 0.70710678118f)); }

// ---------------- small kernels ----------------
__global__ void k_f32_to_bf16(const float* __restrict__ in, short* __restrict__ out, long n4) {
  long i = (long)blockIdx.x * blockDim.x + threadIdx.x;
  if (i >= n4) return;
  long base = i * 4;
  f32x4 v = *(const f32x4*)(in + base);
  short4 o;
  o.x = f2bf(v.x); o.y = f2bf(v.y); o.z = f2bf(v.z); o.w = f2bf(v.w);
  *(short4*)(out + base) = o;
}

// f32 -> (hi, lo) double-bf16 split
__global__ void k_split(const float* __restrict__ in, short* __restrict__ oh,
                        short* __restrict__ ol, long n4) {
  long i = (long)blockIdx.x * blockDim.x + threadIdx.x;
  if (i >= n4) return;
  long base = i * 4;
  f32x4 v = *(const f32x4*)(in + base);
  short4 h, l;
  h.x = f2bf(v.x); l.x = f2bf(v.x - bf2f(h.x));
  h.y = f2bf(v.y); l.y = f2bf(v.y - bf2f(h.y));
  h.z = f2bf(v.z); l.z = f2bf(v.z - bf2f(h.z));
  h.w = f2bf(v.w); l.w = f2bf(v.w - bf2f(h.w));
  *(short4*)(oh + base) = h;
  *(short4*)(ol + base) = l;
}

// f32 -> 3-term bf16 split (t0+t1+t2, residual ~2^-27)
__global__ void k_split3(const float* __restrict__ in, short* __restrict__ o0,
                         short* __restrict__ o1, short* __restrict__ o2, long n4) {
  long i = (long)blockIdx.x * blockDim.x + threadIdx.x;
  if (i >= n4) return;
  long base = i * 4;
  f32x4 v = *(const f32x4*)(in + base);
  short4 a, b, c;
#define SP3(comp)                                    \
  {                                                  \
    float x = v.comp;                                \
    short t0 = f2bf(x);                              \
    float r = x - bf2f(t0);                          \
    short t1 = f2bf(r);                              \
    short t2 = f2bf(r - bf2f(t1));                   \
    a.comp = t0; b.comp = t1; c.comp = t2;           \
  }
  SP3(x) SP3(y) SP3(z) SP3(w)
#undef SP3
  *(short4*)(o0 + base) = a;
  *(short4*)(o1 + base) = b;
  *(short4*)(o2 + base) = c;
}

// in  f32 [batch][R][C]  ->  out bf16 [batch][C][R]
__global__ void k_transpose_bf16(const float* __restrict__ in, short* __restrict__ out,
                                 int R, int C, long inBS, long outBS) {
  __shared__ float tile[32][33];
  const float* src = in + (size_t)blockIdx.z * inBS;
  short* dst = out + (size_t)blockIdx.z * outBS;
  int r0 = blockIdx.y * 32, c0 = blockIdx.x * 32;
  int tx = threadIdx.x, ty = threadIdx.y;
#pragma unroll
  for (int i = 0; i < 32; i += 8) {
    int r = r0 + ty + i, c = c0 + tx;
    if (r < R && c < C) tile[ty + i][tx] = src[(size_t)r * C + c];
  }
  __syncthreads();
#pragma unroll
  for (int i = 0; i < 32; i += 8) {
    int c = c0 + ty + i, r = r0 + tx;
    if (r < R && c < C) dst[(size_t)c * R + r] = f2bf(tile[tx][ty + i]);
  }
}

// in f32 [batch][R][C] -> hi/lo bf16 [batch][C][R]
__global__ void k_transpose_split(const float* __restrict__ in, short* __restrict__ oh,
                                  short* __restrict__ ol, int R, int C, long inBS,
                                  long outBS) {
  __shared__ float tile[32][33];
  const float* src = in + (size_t)blockIdx.z * inBS;
  short* dh = oh + (size_t)blockIdx.z * outBS;
  short* dl = ol + (size_t)blockIdx.z * outBS;
  int r0 = blockIdx.y * 32, c0 = blockIdx.x * 32;
  int tx = threadIdx.x, ty = threadIdx.y;
#pragma unroll
  for (int i = 0; i < 32; i += 8) {
    int r = r0 + ty + i, c = c0 + tx;
    if (r < R && c < C) tile[ty + i][tx] = src[(size_t)r * C + c];
  }
  __syncthreads();
#pragma unroll
  for (int i = 0; i < 32; i += 8) {
    int c = c0 + ty + i, r = r0 + tx;
    if (r < R && c < C) {
      float v = tile[tx][ty + i];
      short hi = f2bf(v);
      short lo = f2bf(v - bf2f(hi));
      dh[(size_t)c * R + r] = hi;
      dl[(size_t)c * R + r] = lo;
    }
  }
}

// in f32 [R][C] -> 3-split bf16 [C][R]
__global__ void k_transpose_split3(const float* __restrict__ in, short* __restrict__ o0,
                                   short* __restrict__ o1, short* __restrict__ o2,
                                   int R, int C) {
  __shared__ float tile[32][33];
  int r0 = blockIdx.y * 32, c0 = blockIdx.x * 32;
  int tx = threadIdx.x, ty = threadIdx.y;
#pragma unroll
  for (int i = 0; i < 32; i += 8) {
    int r = r0 + ty + i, c = c0 + tx;
    if (r < R && c < C) tile[ty + i][tx] = in[(size_t)r * C + c];
  }
  __syncthreads();
#pragma unroll
  for (int i = 0; i < 32; i += 8) {
    int c = c0 + ty + i, r = r0 + tx;
    if (r < R && c < C) {
      float v = tile[tx][ty + i];
      short t0 = f2bf(v);
      float rr = v - bf2f(t0);
      short t1 = f2bf(rr);
      short t2 = f2bf(rr - bf2f(t1));
      o0[(size_t)c * R + r] = t0;
      o1[(size_t)c * R + r] = t1;
      o2[(size_t)c * R + r] = t2;
    }
  }
}

__global__ void k_bqkv(const float* __restrict__ bq, const float* __restrict__ bk,
                       const float* __restrict__ bv, float* __restrict__ bqkv) {
  int i = blockIdx.x * blockDim.x + threadIdx.x;
  if (i >= L * 3 * H) return;
  int l = i / (3 * H), j = i % (3 * H);
  float v = (j < H) ? bq[l * H + j] : (j < 2 * H) ? bk[l * H + j - H] : bv[l * H + j - 2 * H];
  bqkv[i] = v;
}

__global__ void k_ropetab(float* __restrict__ cosT, float* __restrict__ sinT) {
  int i = blockIdx.x * blockDim.x + threadIdx.x;
  if (i >= S * (HD / 2)) return;
  int s = i / 32, d = i % 32;
  float invf = powf(10000.f, -(2.f * d) / (float)HD);
  float ang = (float)s * invf;
  cosT[i] = cosf(ang);
  sinT[i] = sinf(ang);
}

__global__ void k_embed(const int* __restrict__ ids, const float* __restrict__ emb,
                        float* __restrict__ x) {
  int idx = blockIdx.x * blockDim.x + threadIdx.x;  // NTOK*(H/4)
  int row = idx / (H / 4), c4 = idx % (H / 4);
  if (row >= NTOK) return;
  int t = ids[row];
  ((f32x4*)(x + (size_t)row * H))[c4] = ((const f32x4*)(emb + (size_t)t * H))[c4];
}

// ---------------- layernorm (f32 in, f32 or bf16 out) ----------------
template <bool BF>
__global__ void k_layernorm(const float* __restrict__ x, const float* __restrict__ w,
                            const float* __restrict__ b, void* __restrict__ outp) {
  int row = blockIdx.x * (blockDim.x >> 6) + (threadIdx.x >> 6);
  int lane = threadIdx.x & 63;
  if (row >= NTOK) return;
  const float* xr = x + (size_t)row * H;
  float v[12], s = 0.f, s2 = 0.f;
#pragma unroll
  for (int j = 0; j < 12; j++) { float t = xr[lane + j * 64]; v[j] = t; s += t; s2 += t * t; }
#pragma unroll
  for (int off = 32; off; off >>= 1) { s += __shfl_xor(s, off); s2 += __shfl_xor(s2, off); }
  float m = s / (float)H;
  float var = s2 / (float)H - m * m;
  float rs = 1.f / sqrtf(var + EPSLN);
#pragma unroll
  for (int j = 0; j < 12; j++) {
    int c = lane + j * 64;
    float val = (v[j] - m) * rs * w[c] + b[c];
    if (BF) ((short*)outp)[(size_t)row * H + c] = f2bf(val);
    else    ((float*)outp)[(size_t)row * H + c] = val;
  }
}

// ---------------- rope: qf/kf in [z][s][d], vT in [z][d][s] (f32) ------------
__global__ void k_rope(const float* __restrict__ qkv, const float* __restrict__ bqkv,
                       const float* __restrict__ cosT, const float* __restrict__ sinT,
                       float* __restrict__ qf, float* __restrict__ kf,
                       float* __restrict__ vT) {
  int idx = blockIdx.x * blockDim.x + threadIdx.x;  // B*S*NH*32
  if (idx >= Bb * S * NHd * 32) return;
  int d = idx & 31;
  int h = (idx >> 5) % NHd;
  int t = idx / (32 * NHd);  // token = b*S+s
  int s = t % S, b = t / S;
  const float* base = qkv + (size_t)t * (3 * H) + h * HD;
  const float* bb = bqkv + h * HD;
  float c = cosT[s * 32 + d], sn = sinT[s * 32 + d];
  float q1 = base[d] + bb[d],               q2 = base[d + 32] + bb[d + 32];
  float k1 = base[H + d] + bb[H + d],       k2 = base[H + d + 32] + bb[H + d + 32];
  float v1 = base[2 * H + d] + bb[2 * H + d], v2 = base[2 * H + d + 32] + bb[2 * H + d + 32];
  size_t z = (size_t)(b * NHd + h);
  size_t qk = (z * S + s) * HD;
  qf[qk + d]      = q1 * c - q2 * sn;
  qf[qk + d + 32] = q2 * c + q1 * sn;
  kf[qk + d]      = k1 * c - k2 * sn;
  kf[qk + d + 32] = k2 * c + k1 * sn;
  size_t vb = z * HD * S + s;
  vT[vb + (size_t)d * S]        = v1;
  vT[vb + (size_t)(d + 32) * S] = v2;
}

// ---------------- softmax over hi/lo bf16 scores, in place -------------------
__global__ void k_softmax2(short* __restrict__ p0, short* __restrict__ p1) {
  int row = blockIdx.x * 4 + (threadIdx.x >> 6);  // B*NH*S rows
  int lane = threadIdx.x & 63;
  s16x8* r0 = (s16x8*)(p0 + (size_t)row * S + lane * 16);
  s16x8* r1 = (s16x8*)(p1 + (size_t)row * S + lane * 16);
  s16x8 h0 = r0[0], h1 = r0[1];
  s16x8 l0 = r1[0], l1 = r1[1];
  float v[16];
#pragma unroll
  for (int j = 0; j < 8; j++) {
    v[j] = bf2f(h0[j]) + bf2f(l0[j]);
    v[8 + j] = bf2f(h1[j]) + bf2f(l1[j]);
  }
  float mx = -3e38f;
#pragma unroll
  for (int j = 0; j < 16; j++) mx = fmaxf(mx, v[j]);
#pragma unroll
  for (int off = 32; off; off >>= 1) mx = fmaxf(mx, __shfl_xor(mx, off));
  float sum = 0.f;
#pragma unroll
  for (int j = 0; j < 16; j++) { v[j] = expf(v[j] - mx); sum += v[j]; }
#pragma unroll
  for (int off = 32; off; off >>= 1) sum += __shfl_xor(sum, off);
  float inv = 1.f / sum;
#pragma unroll
  for (int j = 0; j < 16; j++) v[j] *= inv;
  s16x8 oh0, oh1, ol0, ol1;
#pragma unroll
  for (int j = 0; j < 8; j++) {
    short hi = f2bf(v[j]);
    oh0[j] = hi; ol0[j] = f2bf(v[j] - bf2f(hi));
    short hi2 = f2bf(v[8 + j]);
    oh1[j] = hi2; ol1[j] = f2bf(v[8 + j] - bf2f(hi2));
  }
  r0[0] = oh0; r0[1] = oh1;
  r1[0] = ol0; r1[1] = ol1;
}

// ---------------- router (f32 h input -> exact top-2) ----------------
__global__ void k_router(const float* __restrict__ h, const float* __restrict__ Wr,
                         const float* __restrict__ br, float* __restrict__ sel_w,
                         int* __restrict__ sel_e, int* __restrict__ counts) {
  int tok = blockIdx.x * (blockDim.x >> 6) + (threadIdx.x >> 6);
  int lane = threadIdx.x & 63;
  if (tok >= NTOK) return;
  const float* hr = h + (size_t)tok * H;
  float acc[8] = {0, 0, 0, 0, 0, 0, 0, 0};
  for (int i = lane; i < H; i += 64) {
    float hv = hr[i];
    const f32x4* w4 = (const f32x4*)(Wr + (size_t)i * E);
    f32x4 a = w4[0], b = w4[1];
    acc[0] += hv * a.x; acc[1] += hv * a.y; acc[2] += hv * a.z; acc[3] += hv * a.w;
    acc[4] += hv * b.x; acc[5] += hv * b.y; acc[6] += hv * b.z; acc[7] += hv * b.w;
  }
#pragma unroll
  for (int off = 32; off; off >>= 1)
#pragma unroll
    for (int e = 0; e < 8; e++) acc[e] += __shfl_xor(acc[e], off);
  if (lane == 0) {
    float lg[8], m = -3e38f;
#pragma unroll
    for (int e = 0; e < 8; e++) { lg[e] = acc[e] + br[e]; m = fmaxf(m, lg[e]); }
    float sum = 0.f;
#pragma unroll
    for (int e = 0; e < 8; e++) { lg[e] = expf(lg[e] - m); sum += lg[e]; }
    float inv = 1.f / sum;
#pragma unroll
    for (int e = 0; e < 8; e++) lg[e] *= inv;
    int i1 = 0;
#pragma unroll
    for (int e = 1; e < 8; e++) if (lg[e] > lg[i1]) i1 = e;
    int i2 = (i1 == 0) ? 1 : 0;
#pragma unroll
    for (int e = 0; e < 8; e++) if (e != i1 && lg[e] > lg[i2]) i2 = e;
    float p1 = lg[i1], p2 = lg[i2];
    float ws = p1 + p2 + 1e-9f;
    sel_e[tok * 2] = i1; sel_e[tok * 2 + 1] = i2;
    sel_w[tok * 2] = p1 / ws; sel_w[tok * 2 + 1] = p2 / ws;
    atomicAdd(counts + i1, 1);
    atomicAdd(counts + i2, 1);
  }
}

__global__ void k_offsets(const int* __restrict__ counts, int* __restrict__ offs) {
  if (threadIdx.x == 0) {
    int a = 0;
    for (int e = 0; e < E; e++) { offs[e] = a; a += counts[e]; }
    offs[E] = a;
  }
}

__global__ void k_scatter(const int* __restrict__ sel_e, const int* __restrict__ offs,
                          int* __restrict__ cursor, int* __restrict__ tok_list,
                          int* __restrict__ slot_of) {
  int tok = blockIdx.x * blockDim.x + threadIdx.x;
  if (tok >= NTOK) return;
  for (int k = 0; k < 2; k++) {
    int e = sel_e[tok * 2 + k];
    int pos = atomicAdd(cursor + e, 1);
    int g = offs[e] + pos;
    tok_list[g] = tok;
    slot_of[tok * 2 + k] = g;
  }
}

// ff = sum_k w_k * (oe[slot_k] + b2[e_k]); x += ff
__global__ void k_combine(const float* __restrict__ oe, const float* __restrict__ sel_w,
                          const int* __restrict__ slot_of, const int* __restrict__ sel_e,
                          const float* __restrict__ b2, float* __restrict__ x) {
  int idx = blockIdx.x * blockDim.x + threadIdx.x;  // NTOK*(H/4)
  if (idx >= NTOK * (H / 4)) return;
  int tok = idx / (H / 4), c4 = idx % (H / 4);
  float w0 = sel_w[tok * 2], w1 = sel_w[tok * 2 + 1];
  int s0 = slot_of[tok * 2], s1 = slot_of[tok * 2 + 1];
  int e0 = sel_e[tok * 2], e1 = sel_e[tok * 2 + 1];
  f32x4 a = ((const f32x4*)(oe + (size_t)s0 * H))[c4];
  f32x4 b = ((const f32x4*)(oe + (size_t)s1 * H))[c4];
  f32x4 ba = ((const f32x4*)(b2 + (size_t)e0 * H))[c4];
  f32x4 bb = ((const f32x4*)(b2 + (size_t)e1 * H))[c4];
  f32x4* xp = (f32x4*)(x + (size_t)tok * H) + c4;
  *xp = *xp + w0 * (a + ba) + w1 * (b + bb);
}

// ---------------- split-MFMA GEMM: C = (ΣA_s)·(ΣB_s)^T, products i+j<SP -----
// SP=2: 3 MFMAs/frag (bf16x3, ~2^-18); SP=3: 6 MFMAs/frag (bf16x6, ~2^-26).
// MODE 0: f32 out (+bias opt)         1: f32 out = res + acc + bias
// MODE 6: gelu(acc+bias) -> split2 bf16 (Cp,Cp2)
// MODE 7: acc*alpha + causal -> split2 bf16 (Cp,Cp2)
template <int SP, int MODE, bool GATHER>
__global__ __launch_bounds__(256, 2) void k_bgemmS(
    const short* __restrict__ A0, const short* __restrict__ A1, const short* __restrict__ A2,
    long sAz, int lda,
    const short* __restrict__ B0, const short* __restrict__ B1, const short* __restrict__ B2,
    long sBz, int ldb,
    void* __restrict__ Cp, void* __restrict__ Cp2, int zdiv, long sChi, long sClo, int ldc,
    const float* __restrict__ res, const float* __restrict__ bias, long sBias,
    int M, int N, int K,
    const int* __restrict__ d_counts, const int* __restrict__ d_offs,
    const int* __restrict__ gidx, float alpha) {
  const int z = blockIdx.z;
  const int Meff = d_counts ? d_counts[z] : M;
  const int tm = blockIdx.y;
  if (tm * 128 >= Meff) return;
  const int tn = blockIdx.x;
  const int row_base = d_offs ? d_offs[z] : 0;

  __shared__ short Ab[SP][128 * 32];
  __shared__ short Bb2[SP][128 * 32];

  const int tid = threadIdx.x;
  const int lane = tid & 63;
  const int w = tid >> 6;

  const short* APz[3];
  const short* BPz[3];
  APz[0] = A0 + (size_t)z * sAz;
  APz[1] = A1 + (size_t)z * sAz;
  APz[2] = (SP > 2) ? (A2 + (size_t)z * sAz) : APz[0];
  BPz[0] = B0 + (size_t)z * sBz;
  BPz[1] = B1 + (size_t)z * sBz;
  BPz[2] = (SP > 2) ? (B2 + (size_t)z * sBz) : BPz[0];

  size_t aOff[2], bOff[2];
#pragma unroll
  for (int i = 0; i < 2; ++i) {
    const int srow = i * 64 + (tid >> 2);
    const int kb = (tid & 3) ^ (srow & 3);  // pre-swizzled source (involution)
    int lrow = tm * 128 + srow;
    if (lrow > Meff - 1) lrow = Meff - 1;
    int ar = row_base + lrow;
    if (GATHER) ar = gidx[ar];
    aOff[i] = (size_t)ar * lda + kb * 8;
    int bcol = tn * 128 + srow;
    if (bcol > N - 1) bcol = N - 1;
    bOff[i] = (size_t)bcol * ldb + kb * 8;
  }

  f32x4 acc[4][4];
#pragma unroll
  for (int a = 0; a < 4; ++a)
#pragma unroll
    for (int b = 0; b < 4; ++b) acc[a][b] = {0.f, 0.f, 0.f, 0.f};

  const int wr = (w >> 1) * 64;
  const int wc = (w & 1) * 64;
  const int r16 = lane & 15;
  const int kb4 = lane >> 4;
  const int swz = (kb4 ^ (r16 & 3)) * 8;
  int aoff[4], boff[4];
#pragma unroll
  for (int i = 0; i < 4; ++i) {
    aoff[i] = (wr + i * 16 + r16) * 32 + swz;
    boff[i] = (wc + i * 16 + r16) * 32 + swz;
  }

  for (int k0 = 0; k0 < K; k0 += 32) {
#pragma unroll
    for (int s = 0; s < SP; ++s) {
      gload16(APz[s] + aOff[0], (char*)(&Ab[s][0]) + w * 1024);
      gload16(APz[s] + aOff[1], (char*)(&Ab[s][0]) + 4096 + w * 1024);
      gload16(BPz[s] + bOff[0], (char*)(&Bb2[s][0]) + w * 1024);
      gload16(BPz[s] + bOff[1], (char*)(&Bb2[s][0]) + 4096 + w * 1024);
    }
    aOff[0] += 32; aOff[1] += 32; bOff[0] += 32; bOff[1] += 32;
    __syncthreads();
    s16x8 af[SP][4], bf[SP][4];
#pragma unroll
    for (int s = 0; s < SP; ++s)
#pragma unroll
      for (int i = 0; i < 4; ++i) {
        af[s][i] = *(const s16x8*)(&Ab[s][aoff[i]]);
        bf[s][i] = *(const s16x8*)(&Bb2[s][boff[i]]);
      }
#pragma unroll
    for (int mi = 0; mi < 4; ++mi)
#pragma unroll
      for (int ni = 0; ni < 4; ++ni) {
        f32x4 a = acc[mi][ni];
#pragma unroll
        for (int si = 0; si < SP; ++si)
#pragma unroll
          for (int sj = 0; sj < SP - si; ++sj)
            a = __builtin_amdgcn_mfma_f32_16x16x32_bf16(af[si][mi], bf[sj][ni], a, 0, 0, 0);
        acc[mi][ni] = a;
      }
    __syncthreads();
  }

  const long out_off = (long)(z / zdiv) * sChi + (long)(z % zdiv) * sClo;
  const float* bz = bias ? (bias + (size_t)z * sBias) : nullptr;
  const int q4 = lane >> 4;
  float bvv[4];
  int gco[4];
#pragma unroll
  for (int ni = 0; ni < 4; ++ni) {
    gco[ni] = tn * 128 + wc + ni * 16 + r16;
    bvv[ni] = (bz && gco[ni] < N) ? bz[gco[ni]] : 0.f;
  }
#pragma unroll
  for (int mi = 0; mi < 4; ++mi) {
#pragma unroll
    for (int j = 0; j < 4; ++j) {
      const int lrow = tm * 128 + wr + mi * 16 + q4 * 4 + j;
      if (lrow >= Meff) continue;
      const long rbase = out_off + (long)(row_base + lrow) * ldc;
#pragma unroll
      for (int ni = 0; ni < 4; ++ni) {
        if (gco[ni] >= N) continue;
        const float v = acc[mi][ni][j];
        const long idx = rbase + gco[ni];
        if (MODE == 0) {
          ((float*)Cp)[idx] = v + bvv[ni];
        } else if (MODE == 1) {
          ((float*)Cp)[idx] = res[idx] + v + bvv[ni];
        } else if (MODE == 6) {
          float g = gelu1(v + bvv[ni]);
          short hi = f2bf(g);
          ((short*)Cp)[idx] = hi;
          ((short*)Cp2)[idx] = f2bf(g - bf2f(hi));
        } else if (MODE == 7) {
          float g = v * alpha + ((gco[ni] > lrow) ? -1e9f : 0.f);
          short hi = f2bf(g);
          ((short*)Cp)[idx] = hi;
          ((short*)Cp2)[idx] = f2bf(g - bf2f(hi));
        }
      }
    }
  }
}

template <int SP, int MODE, bool GATHER>
static void bgemmS(hipStream_t st, const short* A0, const short* A1, const short* A2, long sAz,
                   int lda, const short* B0, const short* B1, const short* B2, long sBz,
                   int ldb, void* C, void* C2, int zdiv, long sChi, long sClo, int ldc,
                   const float* res, const float* bias, long sBias, int M, int N, int K,
                   int nz, const int* cnts, const int* offs_, const int* gat, float alpha) {
  dim3 g((N + 127) / 128, (M + 127) / 128, nz);
  k_bgemmS<SP, MODE, GATHER><<<g, 256, 0, st>>>(A0, A1, A2, sAz, lda, B0, B1, B2, sBz, ldb, C,
                                                C2, zdiv, sChi, sClo, ldc, res, bias, sBias, M,
                                                N, K, cnts, offs_, gat, alpha);
}

// ---------------- plain bf16 MFMA GEMM (l1 MoE + logits) ----------------
// MODE 0: f32 out (+bias opt)   4: bf16 out = gelu(acc + bias)
// NSWZ: N-major + bijective XCD-chunk swizzle (B-tile L2 locality).
template <int MODE, bool GATHER, bool NSWZ>
__global__ __launch_bounds__(256, 2) void k_bgemm(
    const short* __restrict__ A, long sAz, int lda,
    const short* __restrict__ Bt, long sBz, int ldb,
    void* __restrict__ Cp, int zdiv, long sChi, long sClo, int ldc,
    const float* __restrict__ bias, long sBias,
    int M, int N, int K,
    const int* __restrict__ d_counts, const int* __restrict__ d_offs,
    const int* __restrict__ gidx) {
  const int z = blockIdx.z;
  const int Meff = d_counts ? d_counts[z] : M;
  int tm, tn;
  if (NSWZ) {
    const int bid = blockIdx.y * gridDim.x + blockIdx.x;
    const int nwg = gridDim.x * gridDim.y;
    const int q = nwg >> 3, r = nwg & 7;
    const int xcd = bid & 7, ix = bid >> 3;
    const int wg = (xcd < r) ? (xcd * (q + 1) + ix) : (r * (q + 1) + (xcd - r) * q + ix);
    tn = wg / gridDim.y;   // N-major: consecutive wg share tn
    tm = wg % gridDim.y;
  } else {
    tm = blockIdx.y;
    tn = blockIdx.x;
  }
  if (tm * 128 >= Meff) return;
  const int row_base = d_offs ? d_offs[z] : 0;

  __shared__ short Abuf[128 * 32];
  __shared__ short Bbuf[128 * 32];

  const int tid = threadIdx.x;
  const int lane = tid & 63;
  const int w = tid >> 6;

  const short* Az = A + (size_t)z * sAz;
  const short* Bz = Bt + (size_t)z * sBz;

  const short* aSrc[2];
  const short* bSrc[2];
#pragma unroll
  for (int i = 0; i < 2; ++i) {
    const int srow = i * 64 + (tid >> 2);
    const int kb = (tid & 3) ^ (srow & 3);
    int lrow = tm * 128 + srow;
    if (lrow > Meff - 1) lrow = Meff - 1;
    int ar = row_base + lrow;
    if (GATHER) ar = gidx[ar];
    aSrc[i] = Az + (size_t)ar * lda + kb * 8;
    int bcol = tn * 128 + srow;
    if (bcol > N - 1) bcol = N - 1;
    bSrc[i] = Bz + (size_t)bcol * ldb + kb * 8;
  }

  f32x4 acc[4][4];
#pragma unroll
  for (int a = 0; a < 4; ++a)
#pragma unroll
    for (int b = 0; b < 4; ++b) acc[a][b] = {0.f, 0.f, 0.f, 0.f};

  const int wr = (w >> 1) * 64;
  const int wc = (w & 1) * 64;
  const int r16 = lane & 15;
  const int kb4 = lane >> 4;
  const int swz = (kb4 ^ (r16 & 3)) * 8;
  int aoff[4], boff[4];
#pragma unroll
  for (int i = 0; i < 4; ++i) {
    aoff[i] = (wr + i * 16 + r16) * 32 + swz;
    boff[i] = (wc + i * 16 + r16) * 32 + swz;
  }
  char* const ldsA0 = (char*)Abuf + w * 1024;
  char* const ldsA1 = (char*)Abuf + 4096 + w * 1024;
  char* const ldsB0 = (char*)Bbuf + w * 1024;
  char* const ldsB1 = (char*)Bbuf + 4096 + w * 1024;

  for (int k0 = 0; k0 < K; k0 += 32) {
    gload16(aSrc[0], ldsA0);
    gload16(aSrc[1], ldsA1);
    gload16(bSrc[0], ldsB0);
    gload16(bSrc[1], ldsB1);
    aSrc[0] += 32; aSrc[1] += 32; bSrc[0] += 32; bSrc[1] += 32;
    __syncthreads();
    s16x8 af[4], bf[4];
#pragma unroll
    for (int i = 0; i < 4; ++i) {
      af[i] = *(const s16x8*)(Abuf + aoff[i]);
      bf[i] = *(const s16x8*)(Bbuf + boff[i]);
    }
#pragma unroll
    for (int mi = 0; mi < 4; ++mi)
#pragma unroll
      for (int ni = 0; ni < 4; ++ni)
        acc[mi][ni] =
            __builtin_amdgcn_mfma_f32_16x16x32_bf16(af[mi], bf[ni], acc[mi][ni], 0, 0, 0);
    __syncthreads();
  }

  const long out_off = (long)(z / zdiv) * sChi + (long)(z % zdiv) * sClo;
  const float* bz = bias ? (bias + (size_t)z * sBias) : nullptr;
  const int q4 = lane >> 4;
  float bvv[4];
  int gco[4];
#pragma unroll
  for (int ni = 0; ni < 4; ++ni) {
    gco[ni] = tn * 128 + wc + ni * 16 + r16;
    bvv[ni] = (bz && gco[ni] < N) ? bz[gco[ni]] : 0.f;
  }
#pragma unroll
  for (int mi = 0; mi < 4; ++mi) {
#pragma unroll
    for (int j = 0; j < 4; ++j) {
      const int lrow = tm * 128 + wr + mi * 16 + q4 * 4 + j;
      if (lrow >= Meff) continue;
      const long rbase = out_off + (row_base + lrow) * (long)ldc;
#pragma unroll
      for (int ni = 0; ni < 4; ++ni) {
        if (gco[ni] >= N) continue;
        const float v = acc[mi][ni][j];
        if (MODE == 0) {
          ((float*)Cp)[rbase + gco[ni]] = v + bvv[ni];
        } else if (MODE == 4) {
          float g = v + bvv[ni];
          ((short*)Cp)[rbase + gco[ni]] = f2bf(gelu1(g));
        }
      }
    }
  }
}

template <int MODE, bool GATHER, bool NSWZ>
static void bgemm(hipStream_t st, const short* A, long sAz, int lda, const short* Bt, long sBz,
                  int ldb, void* C, int zdiv, long sChi, long sClo, int ldc, const float* bias,
                  long sBias, int M, int N, int K, int nz, const int* cnts, const int* offs_,
                  const int* gat) {
  dim3 g((N + 127) / 128, (M + 127) / 128, nz);
  k_bgemm<MODE, GATHER, NSWZ><<<g, 256, 0, st>>>(A, sAz, lda, Bt, sBz, ldb, C, zdiv, sChi,
                                                 sClo, ldc, bias, sBias, M, N, K, cnts, offs_,
                                                 gat);
}

// ---------------- launch ----------------
extern "C" void kernel_launch(void* const* d_in, const int* in_sizes, int n_in, void* d_out,
                              int out_size, void* d_ws, size_t ws_size, hipStream_t stream) {
  (void)in_sizes; (void)n_in; (void)out_size; (void)ws_size;
  const int*   ids  = (const int*)d_in[0];
  const float* emb  = (const float*)d_in[1];
  const float* ln1w = (const float*)d_in[2];
  const float* ln1b = (const float*)d_in[3];
  const float* ln2w = (const float*)d_in[4];
  const float* ln2b = (const float*)d_in[5];
  const float* lnfw = (const float*)d_in[6];
  const float* lnfb = (const float*)d_in[7];
  const float* Wq = (const float*)d_in[8];
  const float* bq = (const float*)d_in[9];
  const float* Wk = (const float*)d_in[10];
  const float* bk = (const float*)d_in[11];
  const float* Wv = (const float*)d_in[12];
  const float* bv = (const float*)d_in[13];
  const float* Wo = (const float*)d_in[14];
  const float* bo = (const float*)d_in[15];
  const float* Wr = (const float*)d_in[16];
  const float* br = (const float*)d_in[17];
  const float* W1 = (const float*)d_in[18];
  const float* b1 = (const float*)d_in[19];
  const float* W2 = (const float*)d_in[20];
  const float* b2 = (const float*)d_in[21];
  float* out = (float*)d_out;

  char* p = (char*)d_ws;
  auto alloc = [&](size_t bytes) {
    char* r = p;
    p += (bytes + 255) & ~(size_t)255;
    return r;
  };
  short* embB = (short*)alloc((size_t)V * H * 2);               // 77.2 MB
  // big region (100.7 MB), time-shared:
  //   attention: [p0 | p1] score/prob splits (2 x 50.3)
  //   MoE:       [R_hi | R_lo] expert weight region (2 x 37.7)
  char* big = alloc((size_t)Bb * NHd * S * S * 2 * 2);
  short* p0   = (short*)big;
  short* p1   = p0 + (size_t)Bb * NHd * S * S;
  short* R_hi = (short*)big;
  short* R_lo = R_hi + (size_t)E * F * H;
  short* Wb0 = (short*)alloc((size_t)3 * H * H * 2);            // QKV B splits [2304][768]
  short* Wb1 = (short*)alloc((size_t)3 * H * H * 2);
  short* Wb2 = (short*)alloc((size_t)3 * H * H * 2);
  short* Wo0 = (short*)alloc((size_t)H * H * 2);                // Wo^T splits [768][768]
  short* Wo1 = (short*)alloc((size_t)H * H * 2);
  short* Wo2 = (short*)alloc((size_t)H * H * 2);
  float* bqkv = (float*)alloc((size_t)L * 3 * H * 4);
  float* cosT = (float*)alloc((size_t)S * 32 * 4);
  float* sinT = (float*)alloc((size_t)S * 32 * 4);
  float* x    = (float*)alloc((size_t)NTOK * H * 4);
  float* hbuf = (float*)alloc((size_t)NTOK * H * 4);
  float* qf   = (float*)alloc((size_t)NTOK * H * 4);
  float* kf   = (float*)alloc((size_t)NTOK * H * 4);
  float* vT   = (float*)alloc((size_t)NTOK * H * 4);
  float* o    = (float*)alloc((size_t)NTOK * H * 4);
  short* xb   = (short*)alloc((size_t)NTOK * H * 2);
  short* xb2  = (short*)alloc((size_t)NTOK * H * 2);
  short* h_hi = (short*)alloc((size_t)NTOK * H * 2);            // MoE l0 (2-split)
  short* h_lo = (short*)alloc((size_t)NTOK * H * 2);
  short* h30  = (short*)alloc((size_t)NTOK * H * 2);            // attention 3-splits
  short* h31  = (short*)alloc((size_t)NTOK * H * 2);
  short* h32  = (short*)alloc((size_t)NTOK * H * 2);
  short* q30  = (short*)alloc((size_t)NTOK * H * 2);
  short* q31  = (short*)alloc((size_t)NTOK * H * 2);
  short* q32  = (short*)alloc((size_t)NTOK * H * 2);
  short* k30  = (short*)alloc((size_t)NTOK * H * 2);
  short* k31  = (short*)alloc((size_t)NTOK * H * 2);
  short* k32  = (short*)alloc((size_t)NTOK * H * 2);
  short* v20  = (short*)alloc((size_t)NTOK * H * 2);
  short* v21  = (short*)alloc((size_t)NTOK * H * 2);
  short* o30  = (short*)alloc((size_t)NTOK * H * 2);
  short* o31  = (short*)alloc((size_t)NTOK * H * 2);
  short* o32  = (short*)alloc((size_t)NTOK * H * 2);
  // union region (63.1 MB): qkvl f32 | act_hi+act_lo (l0) / act_b (l1) + oe
  char* uni = alloc((size_t)NSLOT * F * 4 + (size_t)NSLOT * H * 4);
  float* qkvl   = (float*)uni;
  short* act_hi = (short*)uni;
  short* act_lo = (short*)(uni + (size_t)NSLOT * F * 2);
  short* act_b  = (short*)uni;
  float* oe     = (float*)(uni + (size_t)NSLOT * F * 4);
  int* counts  = (int*)alloc(2 * E * 4);
  int* cursor  = counts + E;
  int* offs    = (int*)alloc((E + 1) * 4);
  int* sel_e   = (int*)alloc((size_t)NTOK * 2 * 4);
  float* sel_w = (float*)alloc((size_t)NTOK * 2 * 4);
  int* slot_of = (int*)alloc((size_t)NTOK * 2 * 4);
  int* tok_lst = (int*)alloc((size_t)NSLOT * 4);

  // ---- prologue ----
  long nEmb4 = (long)V * H / 4;
  k_f32_to_bf16<<<(nEmb4 + 255) / 256, 256, 0, stream>>>(emb, embB, nEmb4);
  k_bqkv<<<(L * 3 * H + 255) / 256, 256, 0, stream>>>(bq, bk, bv, bqkv);
  k_ropetab<<<(S * 32 + 255) / 256, 256, 0, stream>>>(cosT, sinT);
  k_embed<<<(NTOK * (H / 4) + 255) / 256, 256, 0, stream>>>(ids, emb, x);

  dim3 tb(32, 8);
  const dim3 tHH(H / 32, H / 32, 1);
  const long n4tok = (long)NTOK * H / 4;
  const int nb4 = (NTOK * (H / 4) + 255) / 256;

  for (int l = 0; l < L; l++) {
    // --- attention (bf16x6 / split-MFMA; upstream of routers) ---
    k_layernorm<false><<<NTOK / 4, 256, 0, stream>>>(x, ln1w + l * H, ln1b + l * H, hbuf);
    k_split3<<<(n4tok + 255) / 256, 256, 0, stream>>>(hbuf, h30, h31, h32, n4tok);
    // W_{q,k,v}^T 3-splits into [2304][768]
    k_transpose_split3<<<tHH, tb, 0, stream>>>(Wq + (size_t)l * H * H, Wb0, Wb1, Wb2, H, H);
    k_transpose_split3<<<tHH, tb, 0, stream>>>(Wk + (size_t)l * H * H, Wb0 + H * H,
                                               Wb1 + H * H, Wb2 + H * H, H, H);
    k_transpose_split3<<<tHH, tb, 0, stream>>>(Wv + (size_t)l * H * H, Wb0 + 2 * H * H,
                                               Wb1 + 2 * H * H, Wb2 + 2 * H * H, H, H);
    // QKV: [2048 x 2304 x 768], f32 out (bias added in rope)
    bgemmS<3, 0, false>(stream, h30, h31, h32, 0, H, Wb0, Wb1, Wb2, 0, H, qkvl, nullptr, 1, 0,
                        0, 3 * H, nullptr, nullptr, 0, NTOK, 3 * H, H, 1, nullptr, nullptr,
                        nullptr, 1.f);
    k_rope<<<(Bb * S * NHd * 32 + 255) / 256, 256, 0, stream>>>(qkvl, bqkv + l * 3 * H, cosT,
                                                                sinT, qf, kf, vT);
    k_split3<<<(n4tok + 255) / 256, 256, 0, stream>>>(qf, q30, q31, q32, n4tok);
    k_split3<<<(n4tok + 255) / 256, 256, 0, stream>>>(kf, k30, k31, k32, n4tok);
    k_split<<<(n4tok + 255) / 256, 256, 0, stream>>>(vT, v20, v21, n4tok);
    // QK^T: per-head [1024 x 1024 x 64], scale+causal -> hi/lo bf16 scores
    bgemmS<3, 7, false>(stream, q30, q31, q32, (long)S * HD, HD, k30, k31, k32, (long)S * HD,
                        HD, p0, p1, 1, (long)S * S, 0, S, nullptr, nullptr, 0, S, S, HD,
                        Bb * NHd, nullptr, nullptr, nullptr, 0.125f);
    k_softmax2<<<(Bb * NHd * S) / 4, 256, 0, stream>>>(p0, p1);
    // PV: per-head [1024 x 64 x 1024], p(2-split) x v(2-split) -> o f32
    bgemmS<2, 0, false>(stream, p0, p1, nullptr, (long)S * S, S, v20, v21, nullptr,
                        (long)HD * S, S, o, nullptr, NHd, (long)S * H, HD, H, nullptr, nullptr,
                        0, S, HD, S, Bb * NHd, nullptr, nullptr, nullptr, 1.f);
    // Wo: x += o @ Wo + bo
    k_split3<<<(n4tok + 255) / 256, 256, 0, stream>>>(o, o30, o31, o32, n4tok);
    k_transpose_split3<<<tHH, tb, 0, stream>>>(Wo + (size_t)l * H * H, Wo0, Wo1, Wo2, H, H);
    bgemmS<3, 1, false>(stream, o30, o31, o32, 0, H, Wo0, Wo1, Wo2, 0, H, x, nullptr, 1, 0, 0,
                        H, x, bo + l * H, 0, NTOK, H, H, 1, nullptr, nullptr, nullptr, 1.f);

    // --- MoE ---
    k_layernorm<false><<<NTOK / 4, 256, 0, stream>>>(x, ln2w + l * H, ln2b + l * H, hbuf);
    hipMemsetAsync(counts, 0, 2 * E * sizeof(int), stream);
    k_router<<<NTOK / 4, 256, 0, stream>>>(hbuf, Wr + (size_t)l * H * E, br + l * E, sel_w,
                                           sel_e, counts);
    k_offsets<<<1, 64, 0, stream>>>(counts, offs);
    k_scatter<<<(NTOK + 255) / 256, 256, 0, stream>>>(sel_e, offs, cursor, tok_lst, slot_of);
    if (l == 0) {
      // bf16x3 split MFMA experts (proven path; p0/p1 dead -> R region free)
      k_split<<<(n4tok + 255) / 256, 256, 0, stream>>>(hbuf, h_hi, h_lo, n4tok);
      k_transpose_split<<<dim3(F / 32, H / 32, E), tb, 0, stream>>>(
          W1, R_hi, R_lo, H, F, (long)H * F, (long)F * H);
      bgemmS<2, 6, true>(stream, h_hi, h_lo, nullptr, 0, H, R_hi, R_lo, nullptr, (long)F * H,
                         H, act_hi, act_lo, 1, 0, 0, F, nullptr, b1, F, NSLOT, F, H, E, counts,
                         offs, tok_lst, 1.f);
      k_transpose_split<<<dim3(H / 32, F / 32, E), tb, 0, stream>>>(
          W2, R_hi, R_lo, F, H, (long)F * H, (long)H * F);
      bgemmS<2, 0, false>(stream, act_hi, act_lo, nullptr, 0, F, R_hi, R_lo, nullptr,
                          (long)H * F, F, oe, nullptr, 1, 0, 0, H, nullptr, nullptr, 0, NSLOT,
                          H, F, E, counts, offs, nullptr, 1.f);
      k_combine<<<nb4, 256, 0, stream>>>(oe, sel_w, slot_of, sel_e, b2, x);
    } else {
      // plain bf16 MFMA experts; stage l1 weights now (R free since l1-attn done)
      k_transpose_bf16<<<dim3(F / 32, H / 32, E), tb, 0, stream>>>(
          W1 + (size_t)1 * E * H * F, R_hi, H, F, (long)H * F, (long)F * H);
      k_transpose_bf16<<<dim3(H / 32, F / 32, E), tb, 0, stream>>>(
          W2 + (size_t)1 * E * F * H, R_lo, F, H, (long)F * H, (long)H * F);
      k_f32_to_bf16<<<(n4tok + 255) / 256, 256, 0, stream>>>(hbuf, xb2, n4tok);
      bgemm<4, true, false>(stream, xb2, 0, H, R_hi, (long)F * H, H, act_b, 1, 0, 0, F,
                            b1 + (size_t)l * E * F, F, NSLOT, F, H, E, counts, offs, tok_lst);
      bgemm<0, false, false>(stream, act_b, 0, F, R_lo, (long)H * F, F, oe, 1, 0, 0, H,
                             nullptr, 0, NSLOT, H, F, E, counts, offs, nullptr);
      k_combine<<<nb4, 256, 0, stream>>>(oe, sel_w, slot_of, sel_e, b2 + (size_t)l * E * H, x);
    }
  }

  // --- final LN + tied logits (bf16 MFMA, XCD-chunked N-major swizzle) ---
  k_layernorm<true><<<NTOK / 4, 256, 0, stream>>>(x, lnfw, lnfb, xb);
  bgemm<0, false, true>(stream, xb, 0, H, embB, 0, H, out, 1, 0, 0, V, nullptr, 0, NTOK, V, H,
                        1, nullptr, nullptr, nullptr);
}

// Round 10
// 1699.876 us; speedup vs baseline: 1.6540x; 1.0544x over previous
//
#include <hip/hip_runtime.h>
#include <stdint.h>

// ---------------- dims ----------------
constexpr int L = 2, Bb = 2, S = 1024, H = 768, NHd = 12, HD = 64;
constexpr int E = 8, F = 3072, V = 50257;
constexpr int NTOK = Bb * S;        // 2048
constexpr int NSLOT = NTOK * 2;     // 4096 (top-2)
constexpr float EPSLN = 1e-5f;

typedef __attribute__((ext_vector_type(4))) float f32x4;
typedef __attribute__((ext_vector_type(8))) short s16x8;

#define DEVI __device__ __forceinline__

DEVI float bf2f(short u) {
  union { float f; uint32_t i; } c; c.i = ((uint32_t)(uint16_t)u) << 16; return c.f;
}
DEVI short f2bf(float f) {
  union { float f; uint32_t i; } c; c.f = f;
  uint32_t x = c.i;
  uint32_t r = (x + 0x7fffu + ((x >> 16) & 1u)) >> 16;  // RNE
  return (short)r;
}

DEVI void gload16(const void* g, void* l) {
  __builtin_amdgcn_global_load_lds(g, l, 16, 0, 0);
}

DEVI float gelu1(float g) { return 0.5f * g * (1.f + erff(g * 0.70710678118f)); }

// ---------------- small kernels ----------------
__global__ void k_f32_to_bf16(const float* __restrict__ in, short* __restrict__ out, long n4) {
  long i = (long)blockIdx.x * blockDim.x + threadIdx.x;
  if (i >= n4) return;
  long base = i * 4;
  f32x4 v = *(const f32x4*)(in + base);
  short4 o;
  o.x = f2bf(v.x); o.y = f2bf(v.y); o.z = f2bf(v.z); o.w = f2bf(v.w);
  *(short4*)(out + base) = o;
}

// in  f32 [batch][R][C]  ->  out bf16 [batch][C][R]
__global__ void k_transpose_bf16(const float* __restrict__ in, short* __restrict__ out,
                                 int R, int C, long inBS, long outBS) {
  __shared__ float tile[32][33];
  const float* src = in + (size_t)blockIdx.z * inBS;
  short* dst = out + (size_t)blockIdx.z * outBS;
  int r0 = blockIdx.y * 32, c0 = blockIdx.x * 32;
  int tx = threadIdx.x, ty = threadIdx.y;
#pragma unroll
  for (int i = 0; i < 32; i += 8) {
    int r = r0 + ty + i, c = c0 + tx;
    if (r < R && c < C) tile[ty + i][tx] = src[(size_t)r * C + c];
  }
  __syncthreads();
#pragma unroll
  for (int i = 0; i < 32; i += 8) {
    int c = c0 + ty + i, r = r0 + tx;
    if (r < R && c < C) dst[(size_t)c * R + r] = f2bf(tile[tx][ty + i]);
  }
}

// in f32 [batch][R][C] -> hi/lo bf16 [batch][C][R]
__global__ void k_transpose_split(const float* __restrict__ in, short* __restrict__ oh,
                                  short* __restrict__ ol, int R, int C, long inBS,
                                  long outBS) {
  __shared__ float tile[32][33];
  const float* src = in + (size_t)blockIdx.z * inBS;
  short* dh = oh + (size_t)blockIdx.z * outBS;
  short* dl = ol + (size_t)blockIdx.z * outBS;
  int r0 = blockIdx.y * 32, c0 = blockIdx.x * 32;
  int tx = threadIdx.x, ty = threadIdx.y;
#pragma unroll
  for (int i = 0; i < 32; i += 8) {
    int r = r0 + ty + i, c = c0 + tx;
    if (r < R && c < C) tile[ty + i][tx] = src[(size_t)r * C + c];
  }
  __syncthreads();
#pragma unroll
  for (int i = 0; i < 32; i += 8) {
    int c = c0 + ty + i, r = r0 + tx;
    if (r < R && c < C) {
      float v = tile[tx][ty + i];
      short hi = f2bf(v);
      short lo = f2bf(v - bf2f(hi));
      dh[(size_t)c * R + r] = hi;
      dl[(size_t)c * R + r] = lo;
    }
  }
}

// in f32 [R][C] -> 3-split bf16 [C][R]   (single matrix)
__global__ void k_transpose_split3(const float* __restrict__ in, short* __restrict__ o0,
                                   short* __restrict__ o1, short* __restrict__ o2,
                                   int R, int C) {
  __shared__ float tile[32][33];
  int r0 = blockIdx.y * 32, c0 = blockIdx.x * 32;
  int tx = threadIdx.x, ty = threadIdx.y;
#pragma unroll
  for (int i = 0; i < 32; i += 8) {
    int r = r0 + ty + i, c = c0 + tx;
    if (r < R && c < C) tile[ty + i][tx] = in[(size_t)r * C + c];
  }
  __syncthreads();
#pragma unroll
  for (int i = 0; i < 32; i += 8) {
    int c = c0 + ty + i, r = r0 + tx;
    if (r < R && c < C) {
      float v = tile[tx][ty + i];
      short t0 = f2bf(v);
      float rr = v - bf2f(t0);
      short t1 = f2bf(rr);
      short t2 = f2bf(rr - bf2f(t1));
      o0[(size_t)c * R + r] = t0;
      o1[(size_t)c * R + r] = t1;
      o2[(size_t)c * R + r] = t2;
    }
  }
}

// batched QKV weight transpose+split3: z=0,1,2 selects Wq/Wk/Wv (HxH each)
__global__ void k_wqkv_t3(const float* __restrict__ Wq, const float* __restrict__ Wk,
                          const float* __restrict__ Wv, short* __restrict__ o0,
                          short* __restrict__ o1, short* __restrict__ o2) {
  __shared__ float tile[32][33];
  const int zz = blockIdx.z;
  const float* in = (zz == 0) ? Wq : (zz == 1) ? Wk : Wv;
  const size_t doff = (size_t)zz * H * H;
  int r0 = blockIdx.y * 32, c0 = blockIdx.x * 32;
  int tx = threadIdx.x, ty = threadIdx.y;
#pragma unroll
  for (int i = 0; i < 32; i += 8) {
    int r = r0 + ty + i, c = c0 + tx;
    tile[ty + i][tx] = in[(size_t)r * H + c];
  }
  __syncthreads();
#pragma unroll
  for (int i = 0; i < 32; i += 8) {
    int c = c0 + ty + i, r = r0 + tx;
    float v = tile[tx][ty + i];
    short t0 = f2bf(v);
    float rr = v - bf2f(t0);
    short t1 = f2bf(rr);
    short t2 = f2bf(rr - bf2f(t1));
    o0[doff + (size_t)c * H + r] = t0;
    o1[doff + (size_t)c * H + r] = t1;
    o2[doff + (size_t)c * H + r] = t2;
  }
}

__global__ void k_bqkv(const float* __restrict__ bq, const float* __restrict__ bk,
                       const float* __restrict__ bv, float* __restrict__ bqkv) {
  int i = blockIdx.x * blockDim.x + threadIdx.x;
  if (i >= L * 3 * H) return;
  int l = i / (3 * H), j = i % (3 * H);
  float v = (j < H) ? bq[l * H + j] : (j < 2 * H) ? bk[l * H + j - H] : bv[l * H + j - 2 * H];
  bqkv[i] = v;
}

__global__ void k_ropetab(float* __restrict__ cosT, float* __restrict__ sinT) {
  int i = blockIdx.x * blockDim.x + threadIdx.x;
  if (i >= S * (HD / 2)) return;
  int s = i / 32, d = i % 32;
  float invf = powf(10000.f, -(2.f * d) / (float)HD);
  float ang = (float)s * invf;
  cosT[i] = cosf(ang);
  sinT[i] = sinf(ang);
}

__global__ void k_embed(const int* __restrict__ ids, const float* __restrict__ emb,
                        float* __restrict__ x) {
  int idx = blockIdx.x * blockDim.x + threadIdx.x;  // NTOK*(H/4)
  int row = idx / (H / 4), c4 = idx % (H / 4);
  if (row >= NTOK) return;
  int t = ids[row];
  ((f32x4*)(x + (size_t)row * H))[c4] = ((const f32x4*)(emb + (size_t)t * H))[c4];
}

// ---------------- layernorm with fused output formats ----------------
// OUT 1: split3 -> s0,s1,s2        OUT 2: f32 of + split2 -> s0,s1
// OUT 3: f32 of + bf16 -> s0       OUT 4: bf16 -> s0
template <int OUT>
__global__ void k_layernorm(const float* __restrict__ x, const float* __restrict__ w,
                            const float* __restrict__ b, float* __restrict__ of,
                            short* __restrict__ s0, short* __restrict__ s1,
                            short* __restrict__ s2) {
  int row = blockIdx.x * (blockDim.x >> 6) + (threadIdx.x >> 6);
  int lane = threadIdx.x & 63;
  if (row >= NTOK) return;
  const float* xr = x + (size_t)row * H;
  float v[12], s = 0.f, s2s = 0.f;
#pragma unroll
  for (int j = 0; j < 12; j++) { float t = xr[lane + j * 64]; v[j] = t; s += t; s2s += t * t; }
#pragma unroll
  for (int off = 32; off; off >>= 1) { s += __shfl_xor(s, off); s2s += __shfl_xor(s2s, off); }
  float m = s / (float)H;
  float var = s2s / (float)H - m * m;
  float rs = 1.f / sqrtf(var + EPSLN);
#pragma unroll
  for (int j = 0; j < 12; j++) {
    int c = lane + j * 64;
    float val = (v[j] - m) * rs * w[c] + b[c];
    size_t idx = (size_t)row * H + c;
    if (OUT == 1) {
      short t0 = f2bf(val);
      float rr = val - bf2f(t0);
      short t1 = f2bf(rr);
      short t2 = f2bf(rr - bf2f(t1));
      s0[idx] = t0; s1[idx] = t1; s2[idx] = t2;
    } else if (OUT == 2) {
      of[idx] = val;
      short hi = f2bf(val);
      s0[idx] = hi; s1[idx] = f2bf(val - bf2f(hi));
    } else if (OUT == 3) {
      of[idx] = val;
      s0[idx] = f2bf(val);
    } else {
      s0[idx] = f2bf(val);
    }
  }
}

// ---------------- softmax over hi/lo bf16 scores, in place -------------------
__global__ void k_softmax2(short* __restrict__ p0, short* __restrict__ p1) {
  int row = blockIdx.x * 4 + (threadIdx.x >> 6);  // B*NH*S rows
  int lane = threadIdx.x & 63;
  s16x8* r0 = (s16x8*)(p0 + (size_t)row * S + lane * 16);
  s16x8* r1 = (s16x8*)(p1 + (size_t)row * S + lane * 16);
  s16x8 h0 = r0[0], h1 = r0[1];
  s16x8 l0 = r1[0], l1 = r1[1];
  float v[16];
#pragma unroll
  for (int j = 0; j < 8; j++) {
    v[j] = bf2f(h0[j]) + bf2f(l0[j]);
    v[8 + j] = bf2f(h1[j]) + bf2f(l1[j]);
  }
  float mx = -3e38f;
#pragma unroll
  for (int j = 0; j < 16; j++) mx = fmaxf(mx, v[j]);
#pragma unroll
  for (int off = 32; off; off >>= 1) mx = fmaxf(mx, __shfl_xor(mx, off));
  float sum = 0.f;
#pragma unroll
  for (int j = 0; j < 16; j++) { v[j] = expf(v[j] - mx); sum += v[j]; }
#pragma unroll
  for (int off = 32; off; off >>= 1) sum += __shfl_xor(sum, off);
  float inv = 1.f / sum;
#pragma unroll
  for (int j = 0; j < 16; j++) v[j] *= inv;
  s16x8 oh0, oh1, ol0, ol1;
#pragma unroll
  for (int j = 0; j < 8; j++) {
    short hi = f2bf(v[j]);
    oh0[j] = hi; ol0[j] = f2bf(v[j] - bf2f(hi));
    short hi2 = f2bf(v[8 + j]);
    oh1[j] = hi2; ol1[j] = f2bf(v[8 + j] - bf2f(hi2));
  }
  r0[0] = oh0; r0[1] = oh1;
  r1[0] = ol0; r1[1] = ol1;
}

// ---------------- router (f32 h input -> exact top-2) ----------------
__global__ void k_router(const float* __restrict__ h, const float* __restrict__ Wr,
                         const float* __restrict__ br, float* __restrict__ sel_w,
                         int* __restrict__ sel_e, int* __restrict__ counts) {
  int tok = blockIdx.x * (blockDim.x >> 6) + (threadIdx.x >> 6);
  int lane = threadIdx.x & 63;
  if (tok >= NTOK) return;
  const float* hr = h + (size_t)tok * H;
  float acc[8] = {0, 0, 0, 0, 0, 0, 0, 0};
  for (int i = lane; i < H; i += 64) {
    float hv = hr[i];
    const f32x4* w4 = (const f32x4*)(Wr + (size_t)i * E);
    f32x4 a = w4[0], b = w4[1];
    acc[0] += hv * a.x; acc[1] += hv * a.y; acc[2] += hv * a.z; acc[3] += hv * a.w;
    acc[4] += hv * b.x; acc[5] += hv * b.y; acc[6] += hv * b.z; acc[7] += hv * b.w;
  }
#pragma unroll
  for (int off = 32; off; off >>= 1)
#pragma unroll
    for (int e = 0; e < 8; e++) acc[e] += __shfl_xor(acc[e], off);
  if (lane == 0) {
    float lg[8], m = -3e38f;
#pragma unroll
    for (int e = 0; e < 8; e++) { lg[e] = acc[e] + br[e]; m = fmaxf(m, lg[e]); }
    float sum = 0.f;
#pragma unroll
    for (int e = 0; e < 8; e++) { lg[e] = expf(lg[e] - m); sum += lg[e]; }
    float inv = 1.f / sum;
#pragma unroll
    for (int e = 0; e < 8; e++) lg[e] *= inv;
    int i1 = 0;
#pragma unroll
    for (int e = 1; e < 8; e++) if (lg[e] > lg[i1]) i1 = e;
    int i2 = (i1 == 0) ? 1 : 0;
#pragma unroll
    for (int e = 0; e < 8; e++) if (e != i1 && lg[e] > lg[i2]) i2 = e;
    float p1 = lg[i1], p2 = lg[i2];
    float ws = p1 + p2 + 1e-9f;
    sel_e[tok * 2] = i1; sel_e[tok * 2 + 1] = i2;
    sel_w[tok * 2] = p1 / ws; sel_w[tok * 2 + 1] = p2 / ws;
    atomicAdd(counts + i1, 1);
    atomicAdd(counts + i2, 1);
  }
}

__global__ void k_offsets(const int* __restrict__ counts, int* __restrict__ offs) {
  if (threadIdx.x == 0) {
    int a = 0;
    for (int e = 0; e < E; e++) { offs[e] = a; a += counts[e]; }
    offs[E] = a;
  }
}

__global__ void k_scatter(const int* __restrict__ sel_e, const int* __restrict__ offs,
                          int* __restrict__ cursor, int* __restrict__ tok_list,
                          int* __restrict__ slot_of) {
  int tok = blockIdx.x * blockDim.x + threadIdx.x;
  if (tok >= NTOK) return;
  for (int k = 0; k < 2; k++) {
    int e = sel_e[tok * 2 + k];
    int pos = atomicAdd(cursor + e, 1);
    int g = offs[e] + pos;
    tok_list[g] = tok;
    slot_of[tok * 2 + k] = g;
  }
}

// ff = sum_k w_k * (oe[slot_k] + b2[e_k]); x += ff
__global__ void k_combine(const float* __restrict__ oe, const float* __restrict__ sel_w,
                          const int* __restrict__ slot_of, const int* __restrict__ sel_e,
                          const float* __restrict__ b2, float* __restrict__ x) {
  int idx = blockIdx.x * blockDim.x + threadIdx.x;  // NTOK*(H/4)
  if (idx >= NTOK * (H / 4)) return;
  int tok = idx / (H / 4), c4 = idx % (H / 4);
  float w0 = sel_w[tok * 2], w1 = sel_w[tok * 2 + 1];
  int s0 = slot_of[tok * 2], s1 = slot_of[tok * 2 + 1];
  int e0 = sel_e[tok * 2], e1 = sel_e[tok * 2 + 1];
  f32x4 a = ((const f32x4*)(oe + (size_t)s0 * H))[c4];
  f32x4 b = ((const f32x4*)(oe + (size_t)s1 * H))[c4];
  f32x4 ba = ((const f32x4*)(b2 + (size_t)e0 * H))[c4];
  f32x4 bb = ((const f32x4*)(b2 + (size_t)e1 * H))[c4];
  f32x4* xp = (f32x4*)(x + (size_t)tok * H) + c4;
  *xp = *xp + w0 * (a + ba) + w1 * (b + bb);
}

// ---------------- split-MFMA GEMM: C = (ΣA_s)·(ΣB_s)^T, products i+j<SP -----
// SP=2: 3 MFMAs/frag; SP=3: 6 MFMAs/frag.
// MODE 0: f32 out (+bias opt)   1: f32 out = res + acc + bias
// MODE 6: gelu(acc+bias) -> split2 bf16 (Cp,Cp2)
// MODE 7: acc*alpha + causal -> split2 bf16 (Cp,Cp2)
// MODE 8: acc -> split3 bf16 (Cp,Cp2,Cp3)
// MODE 9: QKV fused: bias + RoPE + split3(q->Cp..3, k->K0..2) / split2(v->V0,V1)
template <int SP, int MODE, bool GATHER>
__global__ __launch_bounds__(256, 2) void k_bgemmS(
    const short* __restrict__ A0, const short* __restrict__ A1, const short* __restrict__ A2,
    long sAz, int lda,
    const short* __restrict__ B0, const short* __restrict__ B1, const short* __restrict__ B2,
    long sBz, int ldb,
    void* __restrict__ Cp, void* __restrict__ Cp2, void* __restrict__ Cp3,
    short* __restrict__ K0, short* __restrict__ K1, short* __restrict__ K2,
    short* __restrict__ V0, short* __restrict__ V1,
    const float* __restrict__ cT, const float* __restrict__ sT,
    int zdiv, long sChi, long sClo, int ldc,
    const float* __restrict__ res, const float* __restrict__ bias, long sBias,
    int M, int N, int K,
    const int* __restrict__ d_counts, const int* __restrict__ d_offs,
    const int* __restrict__ gidx, float alpha) {
  const int z = blockIdx.z;
  const int Meff = d_counts ? d_counts[z] : M;
  const int tm = blockIdx.y;
  if (tm * 128 >= Meff) return;
  const int tn = blockIdx.x;
  const int row_base = d_offs ? d_offs[z] : 0;

  __shared__ short Ab[SP][128 * 32];
  __shared__ short Bb2[SP][128 * 32];

  const int tid = threadIdx.x;
  const int lane = tid & 63;
  const int w = tid >> 6;

  const short* APz[3];
  const short* BPz[3];
  APz[0] = A0 + (size_t)z * sAz;
  APz[1] = A1 + (size_t)z * sAz;
  APz[2] = (SP > 2) ? (A2 + (size_t)z * sAz) : APz[0];
  BPz[0] = B0 + (size_t)z * sBz;
  BPz[1] = B1 + (size_t)z * sBz;
  BPz[2] = (SP > 2) ? (B2 + (size_t)z * sBz) : BPz[0];

  size_t aOff[2], bOff[2];
#pragma unroll
  for (int i = 0; i < 2; ++i) {
    const int srow = i * 64 + (tid >> 2);
    const int kb = (tid & 3) ^ (srow & 3);  // pre-swizzled source (involution)
    int lrow = tm * 128 + srow;
    if (lrow > Meff - 1) lrow = Meff - 1;
    int ar = row_base + lrow;
    if (GATHER) ar = gidx[ar];
    aOff[i] = (size_t)ar * lda + kb * 8;
    int bcol = tn * 128 + srow;
    if (bcol > N - 1) bcol = N - 1;
    bOff[i] = (size_t)bcol * ldb + kb * 8;
  }

  f32x4 acc[4][4];
#pragma unroll
  for (int a = 0; a < 4; ++a)
#pragma unroll
    for (int b = 0; b < 4; ++b) acc[a][b] = {0.f, 0.f, 0.f, 0.f};

  const int wr = (w >> 1) * 64;
  const int wc = (w & 1) * 64;
  const int r16 = lane & 15;
  const int kb4 = lane >> 4;
  const int swz = (kb4 ^ (r16 & 3)) * 8;
  int aoff[4], boff[4];
#pragma unroll
  for (int i = 0; i < 4; ++i) {
    aoff[i] = (wr + i * 16 + r16) * 32 + swz;
    boff[i] = (wc + i * 16 + r16) * 32 + swz;
  }

  for (int k0 = 0; k0 < K; k0 += 32) {
#pragma unroll
    for (int s = 0; s < SP; ++s) {
      gload16(APz[s] + aOff[0], (char*)(&Ab[s][0]) + w * 1024);
      gload16(APz[s] + aOff[1], (char*)(&Ab[s][0]) + 4096 + w * 1024);
      gload16(BPz[s] + bOff[0], (char*)(&Bb2[s][0]) + w * 1024);
      gload16(BPz[s] + bOff[1], (char*)(&Bb2[s][0]) + 4096 + w * 1024);
    }
    aOff[0] += 32; aOff[1] += 32; bOff[0] += 32; bOff[1] += 32;
    __syncthreads();
    s16x8 af[SP][4], bf[SP][4];
#pragma unroll
    for (int s = 0; s < SP; ++s)
#pragma unroll
      for (int i = 0; i < 4; ++i) {
        af[s][i] = *(const s16x8*)(&Ab[s][aoff[i]]);
        bf[s][i] = *(const s16x8*)(&Bb2[s][boff[i]]);
      }
#pragma unroll
    for (int mi = 0; mi < 4; ++mi)
#pragma unroll
      for (int ni = 0; ni < 4; ++ni) {
        f32x4 a = acc[mi][ni];
#pragma unroll
        for (int si = 0; si < SP; ++si)
#pragma unroll
          for (int sj = 0; sj < SP - si; ++sj)
            a = __builtin_amdgcn_mfma_f32_16x16x32_bf16(af[si][mi], bf[sj][ni], a, 0, 0, 0);
        acc[mi][ni] = a;
      }
    __syncthreads();
  }

  const float* bz = bias ? (bias + (size_t)z * sBias) : nullptr;
  const int q4 = lane >> 4;
  float bvv[4];
  int gco[4];
#pragma unroll
  for (int ni = 0; ni < 4; ++ni) {
    gco[ni] = tn * 128 + wc + ni * 16 + r16;
    bvv[ni] = (bz && gco[ni] < N) ? bz[gco[ni]] : 0.f;
  }

  if (MODE == 9) {
    // QKV fused epilogue: cols = [q(768) | k(768) | v(768)], heads of 64.
    const int sec_base = tn * 128 + wc;     // multiple of 64, aligned to sections
    const int sec = sec_base / H;           // 0=q, 1=k, 2=v
    const int hh = (sec_base % H) / HD;
#pragma unroll
    for (int mi = 0; mi < 4; ++mi) {
#pragma unroll
      for (int j = 0; j < 4; ++j) {
        const int row = tm * 128 + wr + mi * 16 + q4 * 4 + j;   // token
        const int ss = row & (S - 1);
        const long zz = (long)((row >> 10) * NHd + hh);
#pragma unroll
        for (int ni = 0; ni < 2; ++ni) {
          const int d = ni * 16 + r16;                          // 0..31
          float a1 = acc[mi][ni][j] + bvv[ni];
          float a2 = acc[mi][ni + 2][j] + bvv[ni + 2];
          if (sec < 2) {
            float cc = cT[ss * 32 + d], sn = sT[ss * 32 + d];
            float r1 = a1 * cc - a2 * sn;
            float r2 = a2 * cc + a1 * sn;
            const long bi = (zz * S + ss) * HD + d;
            short* d0 = (sec == 0) ? (short*)Cp : K0;
            short* d1 = (sec == 0) ? (short*)Cp2 : K1;
            short* d2 = (sec == 0) ? (short*)Cp3 : K2;
            short t0 = f2bf(r1); float rr = r1 - bf2f(t0);
            short t1 = f2bf(rr); short t2 = f2bf(rr - bf2f(t1));
            d0[bi] = t0; d1[bi] = t1; d2[bi] = t2;
            t0 = f2bf(r2); rr = r2 - bf2f(t0);
            t1 = f2bf(rr); t2 = f2bf(rr - bf2f(t1));
            d0[bi + 32] = t0; d1[bi + 32] = t1; d2[bi + 32] = t2;
          } else {
            const long vb1 = zz * HD * S + (long)d * S + ss;
            short hv = f2bf(a1);
            V0[vb1] = hv; V1[vb1] = f2bf(a1 - bf2f(hv));
            const long vb2 = vb1 + 32L * S;
            hv = f2bf(a2);
            V0[vb2] = hv; V1[vb2] = f2bf(a2 - bf2f(hv));
          }
        }
      }
    }
    return;
  }

  const long out_off = (long)(z / zdiv) * sChi + (long)(z % zdiv) * sClo;
#pragma unroll
  for (int mi = 0; mi < 4; ++mi) {
#pragma unroll
    for (int j = 0; j < 4; ++j) {
      const int lrow = tm * 128 + wr + mi * 16 + q4 * 4 + j;
      if (lrow >= Meff) continue;
      const long rbase = out_off + (long)(row_base + lrow) * ldc;
#pragma unroll
      for (int ni = 0; ni < 4; ++ni) {
        if (gco[ni] >= N) continue;
        const float v = acc[mi][ni][j];
        const long idx = rbase + gco[ni];
        if (MODE == 0) {
          ((float*)Cp)[idx] = v + bvv[ni];
        } else if (MODE == 1) {
          ((float*)Cp)[idx] = res[idx] + v + bvv[ni];
        } else if (MODE == 6) {
          float g = gelu1(v + bvv[ni]);
          short hi = f2bf(g);
          ((short*)Cp)[idx] = hi;
          ((short*)Cp2)[idx] = f2bf(g - bf2f(hi));
        } else if (MODE == 7) {
          float g = v * alpha + ((gco[ni] > lrow) ? -1e9f : 0.f);
          short hi = f2bf(g);
          ((short*)Cp)[idx] = hi;
          ((short*)Cp2)[idx] = f2bf(g - bf2f(hi));
        } else if (MODE == 8) {
          float g = v + bvv[ni];
          short t0 = f2bf(g); float rr = g - bf2f(t0);
          short t1 = f2bf(rr); short t2 = f2bf(rr - bf2f(t1));
          ((short*)Cp)[idx] = t0;
          ((short*)Cp2)[idx] = t1;
          ((short*)Cp3)[idx] = t2;
        }
      }
    }
  }
}

template <int SP, int MODE, bool GATHER>
static void bgemmS(hipStream_t st, const short* A0, const short* A1, const short* A2, long sAz,
                   int lda, const short* B0, const short* B1, const short* B2, long sBz,
                   int ldb, void* C, void* C2, void* C3, int zdiv, long sChi, long sClo,
                   int ldc, const float* res, const float* bias, long sBias, int M, int N,
                   int K, int nz, const int* cnts, const int* offs_, const int* gat,
                   float alpha, short* K0 = nullptr, short* K1 = nullptr, short* K2 = nullptr,
                   short* V0 = nullptr, short* V1 = nullptr, const float* cT = nullptr,
                   const float* sT = nullptr) {
  dim3 g((N + 127) / 128, (M + 127) / 128, nz);
  k_bgemmS<SP, MODE, GATHER><<<g, 256, 0, st>>>(A0, A1, A2, sAz, lda, B0, B1, B2, sBz, ldb, C,
                                                C2, C3, K0, K1, K2, V0, V1, cT, sT, zdiv, sChi,
                                                sClo, ldc, res, bias, sBias, M, N, K, cnts,
                                                offs_, gat, alpha);
}

// ---------------- plain bf16 MFMA GEMM, BK=64 (l1 MoE + logits) --------------
// MODE 0: f32 out (+bias opt)   4: bf16 out = gelu(acc + bias)
// NSWZ: N-major + bijective XCD-chunk swizzle (B-tile L2 locality).
template <int MODE, bool GATHER, bool NSWZ>
__global__ __launch_bounds__(256, 2) void k_bgemm(
    const short* __restrict__ A, long sAz, int lda,
    const short* __restrict__ Bt, long sBz, int ldb,
    void* __restrict__ Cp, int zdiv, long sChi, long sClo, int ldc,
    const float* __restrict__ bias, long sBias,
    int M, int N, int K,
    const int* __restrict__ d_counts, const int* __restrict__ d_offs,
    const int* __restrict__ gidx) {
  const int z = blockIdx.z;
  const int Meff = d_counts ? d_counts[z] : M;
  int tm, tn;
  if (NSWZ) {
    const int bid = blockIdx.y * gridDim.x + blockIdx.x;
    const int nwg = gridDim.x * gridDim.y;
    const int q = nwg >> 3, r = nwg & 7;
    const int xcd = bid & 7, ix = bid >> 3;
    const int wg = (xcd < r) ? (xcd * (q + 1) + ix) : (r * (q + 1) + (xcd - r) * q + ix);
    tn = wg / gridDim.y;   // N-major: consecutive wg share tn
    tm = wg % gridDim.y;
  } else {
    tm = blockIdx.y;
    tn = blockIdx.x;
  }
  if (tm * 128 >= Meff) return;
  const int row_base = d_offs ? d_offs[z] : 0;

  __shared__ short Abuf[128 * 64];   // 16 KB
  __shared__ short Bbuf[128 * 64];   // 16 KB

  const int tid = threadIdx.x;
  const int lane = tid & 63;
  const int w = tid >> 6;

  const short* Az = A + (size_t)z * sAz;
  const short* Bz = Bt + (size_t)z * sBz;

  // staging: chunk c = w*4+i covers LDS rows c*8..c*8+7; lane -> row c*8+(lane>>3),
  // k-unit lane&7; source k pre-swizzled by (row&7)^unit (involution, rule #21).
  const int swzS = ((lane >> 3) ^ (lane & 7)) * 8;
  const short* aSrc[4];
  const short* bSrc[4];
#pragma unroll
  for (int i = 0; i < 4; ++i) {
    const int rin = (w * 4 + i) * 8 + (lane >> 3);  // 0..127
    int lrow = tm * 128 + rin;
    if (lrow > Meff - 1) lrow = Meff - 1;
    int ar = row_base + lrow;
    if (GATHER) ar = gidx[ar];
    aSrc[i] = Az + (size_t)ar * lda + swzS;
    int bcol = tn * 128 + rin;
    if (bcol > N - 1) bcol = N - 1;
    bSrc[i] = Bz + (size_t)bcol * ldb + swzS;
  }

  f32x4 acc[4][4];
#pragma unroll
  for (int a = 0; a < 4; ++a)
#pragma unroll
    for (int b = 0; b < 4; ++b) acc[a][b] = {0.f, 0.f, 0.f, 0.f};

  const int wr = (w >> 1) * 64;
  const int wc = (w & 1) * 64;
  const int r16 = lane & 15;
  const int kb4 = lane >> 4;
  int aoff[4][2], boff[4][2];
#pragma unroll
  for (int i = 0; i < 4; ++i) {
#pragma unroll
    for (int kw = 0; kw < 2; ++kw) {
      const int sw = ((r16 & 7) ^ (kw * 4 + kb4)) * 8;
      aoff[i][kw] = (wr + i * 16 + r16) * 64 + sw;
      boff[i][kw] = (wc + i * 16 + r16) * 64 + sw;
    }
  }

  for (int k0 = 0; k0 < K; k0 += 64) {
#pragma unroll
    for (int i = 0; i < 4; ++i) gload16(aSrc[i], (char*)Abuf + (w * 4 + i) * 1024);
#pragma unroll
    for (int i = 0; i < 4; ++i) gload16(bSrc[i], (char*)Bbuf + (w * 4 + i) * 1024);
#pragma unroll
    for (int i = 0; i < 4; ++i) { aSrc[i] += 64; bSrc[i] += 64; }
    __syncthreads();
#pragma unroll
    for (int kw = 0; kw < 2; ++kw) {
      s16x8 af[4], bf[4];
#pragma unroll
      for (int i = 0; i < 4; ++i) {
        af[i] = *(const s16x8*)(Abuf + aoff[i][kw]);
        bf[i] = *(const s16x8*)(Bbuf + boff[i][kw]);
      }
#pragma unroll
      for (int mi = 0; mi < 4; ++mi)
#pragma unroll
        for (int ni = 0; ni < 4; ++ni)
          acc[mi][ni] =
              __builtin_amdgcn_mfma_f32_16x16x32_bf16(af[mi], bf[ni], acc[mi][ni], 0, 0, 0);
    }
    __syncthreads();
  }

  const long out_off = (long)(z / zdiv) * sChi + (long)(z % zdiv) * sClo;
  const float* bz = bias ? (bias + (size_t)z * sBias) : nullptr;
  const int q4 = lane >> 4;
  float bvv[4];
  int gco[4];
#pragma unroll
  for (int ni = 0; ni < 4; ++ni) {
    gco[ni] = tn * 128 + wc + ni * 16 + r16;
    bvv[ni] = (bz && gco[ni] < N) ? bz[gco[ni]] : 0.f;
  }
#pragma unroll
  for (int mi = 0; mi < 4; ++mi) {
#pragma unroll
    for (int j = 0; j < 4; ++j) {
      const int lrow = tm * 128 + wr + mi * 16 + q4 * 4 + j;
      if (lrow >= Meff) continue;
      const long rbase = out_off + (row_base + lrow) * (long)ldc;
#pragma unroll
      for (int ni = 0; ni < 4; ++ni) {
        if (gco[ni] >= N) continue;
        const float v = acc[mi][ni][j];
        if (MODE == 0) {
          ((float*)Cp)[rbase + gco[ni]] = v + bvv[ni];
        } else if (MODE == 4) {
          float g = v + bvv[ni];
          ((short*)Cp)[rbase + gco[ni]] = f2bf(gelu1(g));
        }
      }
    }
  }
}

template <int MODE, bool GATHER, bool NSWZ>
static void bgemm(hipStream_t st, const short* A, long sAz, int lda, const short* Bt, long sBz,
                  int ldb, void* C, int zdiv, long sChi, long sClo, int ldc, const float* bias,
                  long sBias, int M, int N, int K, int nz, const int* cnts, const int* offs_,
                  const int* gat) {
  dim3 g((N + 127) / 128, (M + 127) / 128, nz);
  k_bgemm<MODE, GATHER, NSWZ><<<g, 256, 0, st>>>(A, sAz, lda, Bt, sBz, ldb, C, zdiv, sChi,
                                                 sClo, ldc, bias, sBias, M, N, K, cnts, offs_,
                                                 gat);
}

// ---------------- launch ----------------
extern "C" void kernel_launch(void* const* d_in, const int* in_sizes, int n_in, void* d_out,
                              int out_size, void* d_ws, size_t ws_size, hipStream_t stream) {
  (void)in_sizes; (void)n_in; (void)out_size; (void)ws_size;
  const int*   ids  = (const int*)d_in[0];
  const float* emb  = (const float*)d_in[1];
  const float* ln1w = (const float*)d_in[2];
  const float* ln1b = (const float*)d_in[3];
  const float* ln2w = (const float*)d_in[4];
  const float* ln2b = (const float*)d_in[5];
  const float* lnfw = (const float*)d_in[6];
  const float* lnfb = (const float*)d_in[7];
  const float* Wq = (const float*)d_in[8];
  const float* bq = (const float*)d_in[9];
  const float* Wk = (const float*)d_in[10];
  const float* bk = (const float*)d_in[11];
  const float* Wv = (const float*)d_in[12];
  const float* bv = (const float*)d_in[13];
  const float* Wo = (const float*)d_in[14];
  const float* bo = (const float*)d_in[15];
  const float* Wr = (const float*)d_in[16];
  const float* br = (const float*)d_in[17];
  const float* W1 = (const float*)d_in[18];
  const float* b1 = (const float*)d_in[19];
  const float* W2 = (const float*)d_in[20];
  const float* b2 = (const float*)d_in[21];
  float* out = (float*)d_out;

  char* p = (char*)d_ws;
  auto alloc = [&](size_t bytes) {
    char* r = p;
    p += (bytes + 255) & ~(size_t)255;
    return r;
  };
  short* embB = (short*)alloc((size_t)V * H * 2);               // 77.2 MB
  // big region (100.7 MB), time-shared: attention [p0|p1] vs MoE [R_hi|R_lo]
  char* big = alloc((size_t)Bb * NHd * S * S * 2 * 2);
  short* p0   = (short*)big;
  short* p1   = p0 + (size_t)Bb * NHd * S * S;
  short* R_hi = (short*)big;
  short* R_lo = R_hi + (size_t)E * F * H;
  short* Wb0 = (short*)alloc((size_t)3 * H * H * 2);            // QKV W^T 3-splits
  short* Wb1 = (short*)alloc((size_t)3 * H * H * 2);
  short* Wb2 = (short*)alloc((size_t)3 * H * H * 2);
  short* Wo0 = (short*)alloc((size_t)H * H * 2);                // Wo^T 3-splits
  short* Wo1 = (short*)alloc((size_t)H * H * 2);
  short* Wo2 = (short*)alloc((size_t)H * H * 2);
  float* bqkv = (float*)alloc((size_t)L * 3 * H * 4);
  float* cosT = (float*)alloc((size_t)S * 32 * 4);
  float* sinT = (float*)alloc((size_t)S * 32 * 4);
  float* x    = (float*)alloc((size_t)NTOK * H * 4);
  float* hbuf = (float*)alloc((size_t)NTOK * H * 4);
  short* xb   = (short*)alloc((size_t)NTOK * H * 2);
  short* xb2  = (short*)alloc((size_t)NTOK * H * 2);
  short* h_hi = (short*)alloc((size_t)NTOK * H * 2);
  short* h_lo = (short*)alloc((size_t)NTOK * H * 2);
  short* h30  = (short*)alloc((size_t)NTOK * H * 2);
  short* h31  = (short*)alloc((size_t)NTOK * H * 2);
  short* h32  = (short*)alloc((size_t)NTOK * H * 2);
  short* q30  = (short*)alloc((size_t)NTOK * H * 2);
  short* q31  = (short*)alloc((size_t)NTOK * H * 2);
  short* q32  = (short*)alloc((size_t)NTOK * H * 2);
  short* k30  = (short*)alloc((size_t)NTOK * H * 2);
  short* k31  = (short*)alloc((size_t)NTOK * H * 2);
  short* k32  = (short*)alloc((size_t)NTOK * H * 2);
  short* v20  = (short*)alloc((size_t)NTOK * H * 2);
  short* v21  = (short*)alloc((size_t)NTOK * H * 2);
  short* o30  = (short*)alloc((size_t)NTOK * H * 2);
  short* o31  = (short*)alloc((size_t)NTOK * H * 2);
  short* o32  = (short*)alloc((size_t)NTOK * H * 2);
  // union region (63.1 MB): act_hi+act_lo (l0) / act_b (l1) + oe
  char* uni = alloc((size_t)NSLOT * F * 4 + (size_t)NSLOT * H * 4);
  short* act_hi = (short*)uni;
  short* act_lo = (short*)(uni + (size_t)NSLOT * F * 2);
  short* act_b  = (short*)uni;
  float* oe     = (float*)(uni + (size_t)NSLOT * F * 4);
  int* counts  = (int*)alloc(2 * E * 4);
  int* cursor  = counts + E;
  int* offs    = (int*)alloc((E + 1) * 4);
  int* sel_e   = (int*)alloc((size_t)NTOK * 2 * 4);
  float* sel_w = (float*)alloc((size_t)NTOK * 2 * 4);
  int* slot_of = (int*)alloc((size_t)NTOK * 2 * 4);
  int* tok_lst = (int*)alloc((size_t)NSLOT * 4);

  // ---- prologue ----
  long nEmb4 = (long)V * H / 4;
  k_f32_to_bf16<<<(nEmb4 + 255) / 256, 256, 0, stream>>>(emb, embB, nEmb4);
  k_bqkv<<<(L * 3 * H + 255) / 256, 256, 0, stream>>>(bq, bk, bv, bqkv);
  k_ropetab<<<(S * 32 + 255) / 256, 256, 0, stream>>>(cosT, sinT);
  k_embed<<<(NTOK * (H / 4) + 255) / 256, 256, 0, stream>>>(ids, emb, x);

  dim3 tb(32, 8);
  const dim3 tHH(H / 32, H / 32, 1);

  for (int l = 0; l < L; l++) {
    // --- attention (bf16x6 split-MFMA; upstream of routers) ---
    k_layernorm<1><<<NTOK / 4, 256, 0, stream>>>(x, ln1w + l * H, ln1b + l * H, nullptr, h30,
                                                 h31, h32);
    k_wqkv_t3<<<dim3(H / 32, H / 32, 3), tb, 0, stream>>>(
        Wq + (size_t)l * H * H, Wk + (size_t)l * H * H, Wv + (size_t)l * H * H, Wb0, Wb1, Wb2);
    // QKV fused with bias+RoPE+splits (MODE 9)
    bgemmS<3, 9, false>(stream, h30, h31, h32, 0, H, Wb0, Wb1, Wb2, 0, H, q30, q31, q32, 1, 0,
                        0, 0, nullptr, bqkv + l * 3 * H, 0, NTOK, 3 * H, H, 1, nullptr,
                        nullptr, nullptr, 1.f, k30, k31, k32, v20, v21, cosT, sinT);
    // QK^T: scale+causal -> hi/lo bf16 scores
    bgemmS<3, 7, false>(stream, q30, q31, q32, (long)S * HD, HD, k30, k31, k32, (long)S * HD,
                        HD, p0, p1, nullptr, 1, (long)S * S, 0, S, nullptr, nullptr, 0, S, S,
                        HD, Bb * NHd, nullptr, nullptr, nullptr, 0.125f);
    k_softmax2<<<(Bb * NHd * S) / 4, 256, 0, stream>>>(p0, p1);
    // PV -> o split3 (MODE 8)
    bgemmS<2, 8, false>(stream, p0, p1, nullptr, (long)S * S, S, v20, v21, nullptr,
                        (long)HD * S, S, o30, o31, o32, NHd, (long)S * H, HD, H, nullptr,
                        nullptr, 0, S, HD, S, Bb * NHd, nullptr, nullptr, nullptr, 1.f);
    // Wo: x += o @ Wo + bo
    k_transpose_split3<<<tHH, tb, 0, stream>>>(Wo + (size_t)l * H * H, Wo0, Wo1, Wo2, H, H);
    bgemmS<3, 1, false>(stream, o30, o31, o32, 0, H, Wo0, Wo1, Wo2, 0, H, x, nullptr, nullptr,
                        1, 0, 0, H, x, bo + l * H, 0, NTOK, H, H, 1, nullptr, nullptr, nullptr,
                        1.f);

    // --- MoE ---
    if (l == 0)
      k_layernorm<2><<<NTOK / 4, 256, 0, stream>>>(x, ln2w + l * H, ln2b + l * H, hbuf, h_hi,
                                                   h_lo, nullptr);
    else
      k_layernorm<3><<<NTOK / 4, 256, 0, stream>>>(x, ln2w + l * H, ln2b + l * H, hbuf, xb2,
                                                   nullptr, nullptr);
    hipMemsetAsync(counts, 0, 2 * E * sizeof(int), stream);
    k_router<<<NTOK / 4, 256, 0, stream>>>(hbuf, Wr + (size_t)l * H * E, br + l * E, sel_w,
                                           sel_e, counts);
    k_offsets<<<1, 64, 0, stream>>>(counts, offs);
    k_scatter<<<(NTOK + 255) / 256, 256, 0, stream>>>(sel_e, offs, cursor, tok_lst, slot_of);
    if (l == 0) {
      // bf16x3 split MFMA experts (proven path; p0/p1 dead -> R region free)
      k_transpose_split<<<dim3(F / 32, H / 32, E), tb, 0, stream>>>(
          W1, R_hi, R_lo, H, F, (long)H * F, (long)F * H);
      bgemmS<2, 6, true>(stream, h_hi, h_lo, nullptr, 0, H, R_hi, R_lo, nullptr, (long)F * H,
                         H, act_hi, act_lo, nullptr, 1, 0, 0, F, nullptr, b1, F, NSLOT, F, H,
                         E, counts, offs, tok_lst, 1.f);
      k_transpose_split<<<dim3(H / 32, F / 32, E), tb, 0, stream>>>(
          W2, R_hi, R_lo, F, H, (long)F * H, (long)H * F);
      bgemmS<2, 0, false>(stream, act_hi, act_lo, nullptr, 0, F, R_hi, R_lo, nullptr,
                          (long)H * F, F, oe, nullptr, nullptr, 1, 0, 0, H, nullptr, nullptr,
                          0, NSLOT, H, F, E, counts, offs, nullptr, 1.f);
      k_combine<<<(NTOK * (H / 4) + 255) / 256, 256, 0, stream>>>(oe, sel_w, slot_of, sel_e,
                                                                  b2, x);
    } else {
      // plain bf16 MFMA experts (BK=64); stage l1 weights (R free after l1-attn)
      k_transpose_bf16<<<dim3(F / 32, H / 32, E), tb, 0, stream>>>(
          W1 + (size_t)1 * E * H * F, R_hi, H, F, (long)H * F, (long)F * H);
      k_transpose_bf16<<<dim3(H / 32, F / 32, E), tb, 0, stream>>>(
          W2 + (size_t)1 * E * F * H, R_lo, F, H, (long)F * H, (long)H * F);
      bgemm<4, true, false>(stream, xb2, 0, H, R_hi, (long)F * H, H, act_b, 1, 0, 0, F,
                            b1 + (size_t)l * E * F, F, NSLOT, F, H, E, counts, offs, tok_lst);
      bgemm<0, false, false>(stream, act_b, 0, F, R_lo, (long)H * F, F, oe, 1, 0, 0, H,
                             nullptr, 0, NSLOT, H, F, E, counts, offs, nullptr);
      k_combine<<<(NTOK * (H / 4) + 255) / 256, 256, 0, stream>>>(oe, sel_w, slot_of, sel_e,
                                                                  b2 + (size_t)l * E * H, x);
    }
  }

  // --- final LN + tied logits (bf16 MFMA BK=64, XCD-chunked N-major swizzle) ---
  k_layernorm<4><<<NTOK / 4, 256, 0, stream>>>(x, lnfw, lnfb, nullptr, xb, nullptr, nullptr);
  bgemm<0, false, true>(stream, xb, 0, H, embB, 0, H, out, 1, 0, 0, V, nullptr, 0, NTOK, V, H,
                        1, nullptr, nullptr, nullptr);
}